// Round 1
// baseline (17191.078 us; speedup 1.0000x reference)
//
#include <hip/hip_runtime.h>

#define FDIM 128
#define RDIM 20

constexpr int TE   = 32;   // edges per block (message kernel)
constexpr int TH   = 256;
constexpr int TN_U = 16;   // nodes per block (update kernel)
constexpr int TN_E = 32;   // nodes per block (energy kernel)

__device__ __forceinline__ float siluf(float x) { return x / (1.f + __expf(-x)); }

// ---------------------------------------------------------------- init: s = emb[z], v = 0
__global__ void k_init(const int* __restrict__ z, const float* __restrict__ emb,
                       float* __restrict__ s, float* __restrict__ v, int N) {
    int i = blockIdx.x * blockDim.x + threadIdx.x;
    if (i >= N * FDIM) return;
    int n = i >> 7, f = i & 127;
    s[i] = emb[z[n] * FDIM + f];
    v[i * 3 + 0] = 0.f; v[i * 3 + 1] = 0.f; v[i * 3 + 2] = 0.f;
}

// ---------------------------------------------------------------- message kernel (one layer)
// Per block: TE edges. Computes rbf+filter-MLP on the fly, scatters m_s/m_v via atomics.
__global__ __launch_bounds__(TH) void k_msg(
    const float* __restrict__ pos, const int* __restrict__ erow, const int* __restrict__ ecol,
    const float* __restrict__ centers, const float* __restrict__ gamma,
    const float* __restrict__ fw1, const float* __restrict__ fb1,
    const float* __restrict__ fw2, const float* __restrict__ fb2,
    const float* __restrict__ s, const float* __restrict__ v,
    float* __restrict__ m_s, float* __restrict__ m_v, int E)
{
    __shared__ int   sh_row[TE], sh_col[TE];
    __shared__ float sh_dist[TE];
    __shared__ float sh_dir[TE][4];
    __shared__ float sh_rbf[TE][RDIM];
    __shared__ float sh_h[TE][FDIM + 2];   // stride 130
    __shared__ float sh_w[64][FDIM];       // fw2 chunk: [g within chunk][f]

    const int tid = threadIdx.x;
    const int e0  = blockIdx.x * TE;

    // A1: edge geometry
    if (tid < TE) {
        int e = e0 + tid;
        if (e < E) {
            int rw = erow[e], cl = ecol[e];
            sh_row[tid] = rw; sh_col[tid] = cl;
            float dx = pos[cl*3+0] - pos[rw*3+0];
            float dy = pos[cl*3+1] - pos[rw*3+1];
            float dz = pos[cl*3+2] - pos[rw*3+2];
            float dist = sqrtf(dx*dx + dy*dy + dz*dz + 1e-12f);
            sh_dist[tid] = dist;
            float inv = 1.f / (dist + 1e-8f);
            sh_dir[tid][0] = dx*inv; sh_dir[tid][1] = dy*inv; sh_dir[tid][2] = dz*inv;
        } else {
            sh_row[tid] = 0; sh_col[tid] = 0; sh_dist[tid] = 0.f;
            sh_dir[tid][0] = sh_dir[tid][1] = sh_dir[tid][2] = 0.f;
        }
    }
    __syncthreads();
    // A2: rbf
    for (int i = tid; i < TE * RDIM; i += TH) {
        int e = i / RDIM, r = i % RDIM;
        float d = sh_dist[e] - centers[r];
        sh_rbf[e][r] = __expf(-gamma[r] * d * d);
    }
    __syncthreads();
    // A3: h = silu(rbf @ fw1 + fb1)
    for (int i = tid; i < TE * FDIM; i += TH) {
        int e = i >> 7, f = i & 127;
        float acc = fb1[f];
        #pragma unroll
        for (int r = 0; r < RDIM; ++r) acc += sh_rbf[e][r] * fw1[r * FDIM + f];
        sh_h[e][f] = siluf(acc);
    }
    // (sync before first sh_h read happens inside the gc loop below)

    // B: phi gates = h @ fw2 + fb2, 4x4 register tiles
    const int eq = tid & 7;        // edge quad -> edges 4eq..4eq+3
    const int fq = tid >> 3;       // 0..31 -> feats 4fq..4fq+3
    const int f0 = fq * 4;

    float pg[3][4][4];
    #pragma unroll
    for (int g3 = 0; g3 < 3; ++g3) {
        #pragma unroll
        for (int ee = 0; ee < 4; ++ee)
            #pragma unroll
            for (int i = 0; i < 4; ++i) pg[g3][ee][i] = fb2[g3 * FDIM + f0 + i];
        for (int gc = 0; gc < 2; ++gc) {
            __syncthreads();
            for (int i2 = tid; i2 < 64 * FDIM; i2 += TH) {
                int gg = i2 >> 7, f = i2 & 127;
                sh_w[gg][f] = fw2[(gc * 64 + gg) * (3 * FDIM) + g3 * FDIM + f];
            }
            __syncthreads();
            #pragma unroll 2
            for (int gg = 0; gg < 64; ++gg) {
                float4 w4 = *(const float4*)(&sh_w[gg][f0]);
                #pragma unroll
                for (int ee = 0; ee < 4; ++ee) {
                    float hv = sh_h[4*eq + ee][gc * 64 + gg];
                    pg[g3][ee][0] += hv * w4.x; pg[g3][ee][1] += hv * w4.y;
                    pg[g3][ee][2] += hv * w4.z; pg[g3][ee][3] += hv * w4.w;
                }
            }
        }
    }

    // C: scatter (atomics)
    #pragma unroll
    for (int ee = 0; ee < 4; ++ee) {
        int el = 4*eq + ee;
        int e  = e0 + el;
        if (e >= E) continue;
        int rw = sh_row[el], cl = sh_col[el];
        float d0 = sh_dir[el][0], d1 = sh_dir[el][1], d2 = sh_dir[el][2];
        #pragma unroll
        for (int i = 0; i < 4; ++i) {
            int f = f0 + i;
            float sc = s[cl * FDIM + f];
            atomicAdd(&m_s[rw * FDIM + f], pg[0][ee][i] * sc);
            int vi = (cl * FDIM + f) * 3;
            int mi = (rw * FDIM + f) * 3;
            float pvv = pg[1][ee][i];
            float svs = pg[2][ee][i] * sc;
            atomicAdd(&m_v[mi + 0], pvv * v[vi + 0] + svs * d0);
            atomicAdd(&m_v[mi + 1], pvv * v[vi + 1] + svs * d1);
            atomicAdd(&m_v[mi + 2], pvv * v[vi + 2] + svs * d2);
        }
    }
}

// ---------------------------------------------------------------- update kernel (one layer)
__global__ __launch_bounds__(TH) void k_update(
    const float* __restrict__ uw1, const float* __restrict__ ub1,
    const float* __restrict__ uw2, const float* __restrict__ ub2,
    float* __restrict__ s, float* __restrict__ v,
    const float* __restrict__ m_s, const float* __restrict__ m_v, int N)
{
    __shared__ float sh_x[TN_U][3 * FDIM + 10];  // stride 394
    __shared__ float sh_w[32][FDIM];
    __shared__ float sh_u1[TN_U][FDIM + 2];      // stride 130

    const int tid = threadIdx.x;
    const int n0  = blockIdx.x * TN_U;

    // A: x = [s, m_s, v_norm]
    for (int i = tid; i < TN_U * FDIM; i += TH) {
        int n = i >> 7, f = i & 127;
        int ng = n0 + n;
        if (ng < N) {
            sh_x[n][f]          = s[ng * FDIM + f];
            sh_x[n][FDIM + f]   = m_s[ng * FDIM + f];
            int vi = (ng * FDIM + f) * 3;
            float a = m_v[vi], b = m_v[vi+1], c = m_v[vi+2];
            sh_x[n][2*FDIM + f] = sqrtf(a*a + b*b + c*c + 1e-12f);
        } else {
            sh_x[n][f] = sh_x[n][FDIM+f] = sh_x[n][2*FDIM+f] = 0.f;
        }
    }

    const int eq = tid & 7;     // node pair: nodes 2eq, 2eq+1
    const int fq = tid >> 3;    // 0..31
    const int f0 = fq * 4;

    // B: u1 = silu(x @ uw1 + ub1)
    float accB[2][4];
    #pragma unroll
    for (int j = 0; j < 2; ++j)
        #pragma unroll
        for (int i = 0; i < 4; ++i) accB[j][i] = ub1[f0 + i];
    for (int kc = 0; kc < 12; ++kc) {
        __syncthreads();
        for (int i2 = tid; i2 < 32 * FDIM; i2 += TH) {
            int kk = i2 >> 7, f = i2 & 127;
            sh_w[kk][f] = uw1[(kc * 32 + kk) * FDIM + f];
        }
        __syncthreads();
        #pragma unroll 2
        for (int kk = 0; kk < 32; ++kk) {
            float4 w4 = *(const float4*)(&sh_w[kk][f0]);
            #pragma unroll
            for (int j = 0; j < 2; ++j) {
                float xv = sh_x[2*eq + j][kc * 32 + kk];
                accB[j][0] += xv * w4.x; accB[j][1] += xv * w4.y;
                accB[j][2] += xv * w4.z; accB[j][3] += xv * w4.w;
            }
        }
    }
    __syncthreads();
    #pragma unroll
    for (int j = 0; j < 2; ++j)
        #pragma unroll
        for (int i = 0; i < 4; ++i) sh_u1[2*eq + j][f0 + i] = siluf(accB[j][i]);

    // C: upd = u1 @ uw2 + ub2 ; apply delta_s / alpha / beta
    float alpha[2][4];
    #pragma unroll
    for (int g3 = 0; g3 < 3; ++g3) {
        float a2[2][4];
        #pragma unroll
        for (int j = 0; j < 2; ++j)
            #pragma unroll
            for (int i = 0; i < 4; ++i) a2[j][i] = ub2[g3 * FDIM + f0 + i];
        for (int kc = 0; kc < 4; ++kc) {
            __syncthreads();
            for (int i2 = tid; i2 < 32 * FDIM; i2 += TH) {
                int kk = i2 >> 7, f = i2 & 127;
                sh_w[kk][f] = uw2[(kc * 32 + kk) * (3 * FDIM) + g3 * FDIM + f];
            }
            __syncthreads();
            #pragma unroll 2
            for (int kk = 0; kk < 32; ++kk) {
                float4 w4 = *(const float4*)(&sh_w[kk][f0]);
                #pragma unroll
                for (int j = 0; j < 2; ++j) {
                    float uv = sh_u1[2*eq + j][kc * 32 + kk];
                    a2[j][0] += uv * w4.x; a2[j][1] += uv * w4.y;
                    a2[j][2] += uv * w4.z; a2[j][3] += uv * w4.w;
                }
            }
        }
        #pragma unroll
        for (int j = 0; j < 2; ++j) {
            int ng = n0 + 2*eq + j;
            if (ng >= N) continue;
            if (g3 == 0) {
                #pragma unroll
                for (int i = 0; i < 4; ++i) s[ng * FDIM + f0 + i] += a2[j][i];
            } else if (g3 == 1) {
                #pragma unroll
                for (int i = 0; i < 4; ++i) alpha[j][i] = a2[j][i];
            } else {
                #pragma unroll
                for (int i = 0; i < 4; ++i) {
                    int vi = (ng * FDIM + f0 + i) * 3;
                    #pragma unroll
                    for (int k = 0; k < 3; ++k)
                        v[vi + k] = alpha[j][i] * v[vi + k] + a2[j][i] * m_v[vi + k];
                }
            }
        }
    }
}

// ---------------------------------------------------------------- energy head
__global__ __launch_bounds__(TH) void k_energy(
    const float* __restrict__ ew1, const float* __restrict__ eb1,
    const float* __restrict__ ew2, const float* __restrict__ eb2,
    const float* __restrict__ s, const int* __restrict__ batch,
    float* __restrict__ energies, int N, int S)
{
    __shared__ float sh_s[TN_E][FDIM + 2];   // stride 130
    __shared__ float sh_w[64][FDIM];
    __shared__ float sh_e[TN_E];

    const int tid = threadIdx.x;
    const int n0  = blockIdx.x * TN_E;

    for (int i = tid; i < TN_E * FDIM; i += TH) {
        int n = i >> 7, f = i & 127;
        int ng = n0 + n;
        sh_s[n][f] = (ng < N) ? s[ng * FDIM + f] : 0.f;
    }

    const int eq = tid & 7;      // node quad
    const int gq = tid >> 3;     // 0..31
    const int g0 = gq * 4;

    for (int st = 0; st < S; ++st) {
        __syncthreads();
        if (tid < TN_E) sh_e[tid] = 0.f;
        float acc[4][4];
        #pragma unroll
        for (int ee = 0; ee < 4; ++ee)
            #pragma unroll
            for (int i = 0; i < 4; ++i) acc[ee][i] = eb1[st * FDIM + g0 + i];
        for (int fc = 0; fc < 2; ++fc) {
            __syncthreads();
            for (int i2 = tid; i2 < 64 * FDIM; i2 += TH) {
                int ff = i2 >> 7, g = i2 & 127;
                sh_w[ff][g] = ew1[(st * FDIM + fc * 64 + ff) * FDIM + g];
            }
            __syncthreads();
            #pragma unroll 2
            for (int ff = 0; ff < 64; ++ff) {
                float4 w4 = *(const float4*)(&sh_w[ff][g0]);
                #pragma unroll
                for (int ee = 0; ee < 4; ++ee) {
                    float sv = sh_s[4*eq + ee][fc * 64 + ff];
                    acc[ee][0] += sv * w4.x; acc[ee][1] += sv * w4.y;
                    acc[ee][2] += sv * w4.z; acc[ee][3] += sv * w4.w;
                }
            }
        }
        __syncthreads();
        #pragma unroll
        for (int ee = 0; ee < 4; ++ee) {
            float p = 0.f;
            #pragma unroll
            for (int i = 0; i < 4; ++i) p += siluf(acc[ee][i]) * ew2[st * FDIM + g0 + i];
            atomicAdd(&sh_e[4*eq + ee], p);
        }
        __syncthreads();
        if (tid < TN_E) {
            int ng = n0 + tid;
            if (ng < N) atomicAdd(&energies[batch[ng] * S + st], sh_e[tid] + eb2[st]);
        }
    }
}

// ---------------------------------------------------------------- dipole / nac heads
__global__ void k_vec(const float* __restrict__ v, const float* __restrict__ dipole_w,
                      const float* __restrict__ nac_w, const int* __restrict__ batch,
                      float* __restrict__ dipoles, float* __restrict__ nac, int N)
{
    int n = blockIdx.x * 4 + (threadIdx.x >> 6);
    int lane = threadIdx.x & 63;
    if (n >= N) return;
    float pd[3] = {0.f, 0.f, 0.f};
    float pn[3][3] = {{0.f}};
    for (int f = lane; f < FDIM; f += 64) {
        int vi = (n * FDIM + f) * 3;
        float v0 = v[vi], v1 = v[vi+1], v2 = v[vi+2];
        float wd = dipole_w[f];
        pd[0] += wd * v0; pd[1] += wd * v1; pd[2] += wd * v2;
        #pragma unroll
        for (int p = 0; p < 3; ++p) {
            float wn = nac_w[p * FDIM + f];
            pn[p][0] += wn * v0; pn[p][1] += wn * v1; pn[p][2] += wn * v2;
        }
    }
    #pragma unroll
    for (int d = 32; d > 0; d >>= 1) {
        #pragma unroll
        for (int k = 0; k < 3; ++k) pd[k] += __shfl_down(pd[k], d, 64);
        #pragma unroll
        for (int p = 0; p < 3; ++p)
            #pragma unroll
            for (int k = 0; k < 3; ++k) pn[p][k] += __shfl_down(pn[p][k], d, 64);
    }
    if (lane == 0) {
        int m = batch[n];
        #pragma unroll
        for (int k = 0; k < 3; ++k) atomicAdd(&dipoles[m * 3 + k], pd[k]);
        #pragma unroll
        for (int p = 0; p < 3; ++p)
            #pragma unroll
            for (int k = 0; k < 3; ++k) atomicAdd(&nac[(m * 3 + p) * 3 + k], pn[p][k]);
    }
}

// ---------------------------------------------------------------- per-molecule heads
__global__ __launch_bounds__(128) void k_heads(
    const float* __restrict__ aw1, const float* __restrict__ ab1,
    const float* __restrict__ aw2, const float* __restrict__ ab2,
    const float* __restrict__ yw1, const float* __restrict__ yb1,
    const float* __restrict__ yw2, const float* __restrict__ yb2,
    const float* __restrict__ energies, const float* __restrict__ nac,
    float* __restrict__ lam, float* __restrict__ phi_y, int M, int S)
{
    __shared__ float sh_in[8];
    __shared__ float sh_red[2];
    int m = blockIdx.x;
    if (m >= M) return;
    int tid = threadIdx.x;
    if (tid == 0) {
        float e0 = energies[m * S];
        for (int j = 0; j < 3; ++j) sh_in[j] = energies[m * S + 1 + j] - e0;
        for (int p = 0; p < 3; ++p) {
            float a = nac[(m * 3 + p) * 3 + 0];
            float b = nac[(m * 3 + p) * 3 + 1];
            float c = nac[(m * 3 + p) * 3 + 2];
            sh_in[3 + p] = sqrtf(a*a + b*b + c*c + 1e-12f);
        }
    }
    __syncthreads();
    float pa = 0.f;
    if (tid < 64) {
        float h = ab1[tid];
        #pragma unroll
        for (int j = 0; j < 3; ++j) h += sh_in[j] * aw1[j * 64 + tid];
        pa = siluf(h) * aw2[tid];
    }
    float h2 = yb1[tid];
    #pragma unroll
    for (int j = 0; j < 6; ++j) h2 += sh_in[j] * yw1[j * 128 + tid];
    float py = siluf(h2) * yw2[tid];
    #pragma unroll
    for (int d = 32; d > 0; d >>= 1) {
        pa += __shfl_down(pa, d, 64);
        py += __shfl_down(py, d, 64);
    }
    int wid = tid >> 6, lane = tid & 63;
    if (lane == 0) sh_red[wid] = py;
    __syncthreads();
    if (tid == 0) {
        lam[m] = pa + ab2[0];
        float yt = sh_red[0] + sh_red[1] + yb2[0];
        phi_y[m] = 1.f / (1.f + __expf(-yt));
    }
}

// ---------------------------------------------------------------- launch
extern "C" void kernel_launch(void* const* d_in, const int* in_sizes, int n_in,
                              void* d_out, int out_size, void* d_ws, size_t ws_size,
                              hipStream_t stream)
{
    const int*   z        = (const int*)  d_in[0];
    const float* pos      = (const float*)d_in[1];
    const int*   eidx     = (const int*)  d_in[2];
    const int*   batch    = (const int*)  d_in[3];
    const float* emb      = (const float*)d_in[5];
    const float* centers  = (const float*)d_in[6];
    const float* gamma    = (const float*)d_in[7];
    const float* fw1      = (const float*)d_in[8];
    const float* fb1      = (const float*)d_in[9];
    const float* fw2      = (const float*)d_in[10];
    const float* fb2      = (const float*)d_in[11];
    const float* uw1      = (const float*)d_in[12];
    const float* ub1      = (const float*)d_in[13];
    const float* uw2      = (const float*)d_in[14];
    const float* ub2      = (const float*)d_in[15];
    const float* ew1      = (const float*)d_in[16];
    const float* eb1      = (const float*)d_in[17];
    const float* ew2      = (const float*)d_in[18];
    const float* eb2      = (const float*)d_in[19];
    const float* dipole_w = (const float*)d_in[20];
    const float* nac_w    = (const float*)d_in[21];
    const float* aw1      = (const float*)d_in[22];
    const float* ab1      = (const float*)d_in[23];
    const float* aw2      = (const float*)d_in[24];
    const float* ab2      = (const float*)d_in[25];
    const float* yw1      = (const float*)d_in[26];
    const float* yb1      = (const float*)d_in[27];
    const float* yw2      = (const float*)d_in[28];
    const float* yb2      = (const float*)d_in[29];

    const int N = in_sizes[0];
    const int E = in_sizes[2] / 2;
    const int S = in_sizes[19];            // eb2 is (S,1)
    const int P = in_sizes[21] / FDIM;     // nac_w is (P,F)
    const int L = in_sizes[9] / FDIM;      // fb1 is (L,F)
    const int M = out_size / (S + 3 + P * 3 + 2);

    float* s   = (float*)d_ws;
    float* v   = s   + (size_t)N * FDIM;
    float* m_s = v   + (size_t)N * FDIM * 3;
    float* m_v = m_s + (size_t)N * FDIM;

    float* out      = (float*)d_out;
    float* energies = out;
    float* dipoles  = energies + (size_t)M * S;
    float* nac      = dipoles  + (size_t)M * 3;
    float* lam      = nac      + (size_t)M * P * 3;
    float* phi_y    = lam      + M;

    hipMemsetAsync(d_out, 0, (size_t)out_size * sizeof(float), stream);
    k_init<<<(N * FDIM + 255) / 256, 256, 0, stream>>>(z, emb, s, v, N);

    for (int l = 0; l < L; ++l) {
        hipMemsetAsync(m_s, 0, (size_t)N * FDIM * 4 * sizeof(float), stream);
        k_msg<<<(E + TE - 1) / TE, TH, 0, stream>>>(
            pos, eidx, eidx + E, centers, gamma,
            fw1 + (size_t)l * RDIM * FDIM, fb1 + (size_t)l * FDIM,
            fw2 + (size_t)l * FDIM * 3 * FDIM, fb2 + (size_t)l * 3 * FDIM,
            s, v, m_s, m_v, E);
        k_update<<<(N + TN_U - 1) / TN_U, TH, 0, stream>>>(
            uw1 + (size_t)l * 3 * FDIM * FDIM, ub1 + (size_t)l * FDIM,
            uw2 + (size_t)l * FDIM * 3 * FDIM, ub2 + (size_t)l * 3 * FDIM,
            s, v, m_s, m_v, N);
    }

    k_energy<<<(N + TN_E - 1) / TN_E, TH, 0, stream>>>(ew1, eb1, ew2, eb2, s, batch, energies, N, S);
    k_vec<<<(N + 3) / 4, 256, 0, stream>>>(v, dipole_w, nac_w, batch, dipoles, nac, N);
    k_heads<<<M, 128, 0, stream>>>(aw1, ab1, aw2, ab2, yw1, yb1, yw2, yb2,
                                   energies, nac, lam, phi_y, M, S);
}

// Round 2
// 8144.308 us; speedup vs baseline: 2.1108x; 2.1108x over previous
//
#include <hip/hip_runtime.h>

#define FDIM 128
#define RDIM 20

constexpr int TE_G = 32;   // edges per chunk (gather message kernel)
constexpr int TH   = 256;
constexpr int TN_U = 16;   // nodes per block (update kernel)
constexpr int TN_E = 32;   // nodes per block (energy kernel)

__device__ __forceinline__ float siluf(float x) { return x / (1.f + __expf(-x)); }

// ---------------------------------------------------------------- init: s = emb[z], v = 0
__global__ void k_init(const int* __restrict__ z, const float* __restrict__ emb,
                       float* __restrict__ s, float* __restrict__ v, int N) {
    int i = blockIdx.x * blockDim.x + threadIdx.x;
    if (i >= N * FDIM) return;
    int n = i >> 7, f = i & 127;
    s[i] = emb[z[n] * FDIM + f];
    v[i * 3 + 0] = 0.f; v[i * 3 + 1] = 0.f; v[i * 3 + 2] = 0.f;
}

// ---------------------------------------------------------------- CSR build
__global__ void k_hist(const int* __restrict__ erow, int* __restrict__ cursor, int E) {
    int e = blockIdx.x * blockDim.x + threadIdx.x;
    if (e < E) atomicAdd(&cursor[erow[e]], 1);
}

__global__ __launch_bounds__(256) void k_scan(int* __restrict__ cursor,
                                              int* __restrict__ rowstart, int N) {
    __shared__ int sh[256];
    __shared__ int carry;
    int tid = threadIdx.x;
    if (tid == 0) carry = 0;
    __syncthreads();
    for (int base = 0; base < N; base += 256) {
        int idx = base + tid;
        int x = (idx < N) ? cursor[idx] : 0;
        sh[tid] = x;
        __syncthreads();
        for (int off = 1; off < 256; off <<= 1) {
            int t = (tid >= off) ? sh[tid - off] : 0;
            __syncthreads();
            sh[tid] += t;
            __syncthreads();
        }
        int excl = carry + sh[tid] - x;
        if (idx < N) { rowstart[idx] = excl; cursor[idx] = excl; }
        __syncthreads();
        if (tid == 0) carry += sh[255];
        __syncthreads();
    }
    if (tid == 0) rowstart[N] = carry;
}

__global__ void k_fill(const int* __restrict__ erow, int* __restrict__ cursor,
                       int* __restrict__ esort, int E) {
    int e = blockIdx.x * blockDim.x + threadIdx.x;
    if (e < E) {
        int p = atomicAdd(&cursor[erow[e]], 1);
        esort[p] = e;
    }
}

// ---------------------------------------------------------------- message kernel (gather, one layer)
// One block per destination node. Zero global atomics.
__global__ __launch_bounds__(TH) void k_msg2(
    const float* __restrict__ pos, const int* __restrict__ ecol,
    const int* __restrict__ rowstart, const int* __restrict__ esort,
    const float* __restrict__ centers, const float* __restrict__ gamma,
    const float* __restrict__ fw1, const float* __restrict__ fb1,
    const float* __restrict__ fw2, const float* __restrict__ fb2,
    const float* __restrict__ s, const float* __restrict__ v,
    float* __restrict__ m_s, float* __restrict__ m_v, int N)
{
    __shared__ int   sh_col[TE_G];
    __shared__ float sh_dir[TE_G][4];          // [0..2]=dir, [3]=dist
    __shared__ float sh_rbf[TE_G][RDIM];
    __shared__ float sh_ht[FDIM][TE_G + 1];    // h transposed: [k][edge], stride 33
    __shared__ float sh_w[32][3 * FDIM + 4];   // fw2 chunk [k-in-chunk][384], stride 388

    const int n   = blockIdx.x;
    const int tid = threadIdx.x;
    const int lo  = rowstart[n], hi = rowstart[n + 1];

    const int eq = tid & 7;      // edge quad: edges 4eq..4eq+3 of chunk
    const int fq = tid >> 3;     // 0..31
    const int f0 = fq * 4;

    float racc_s[4] = {0.f, 0.f, 0.f, 0.f};
    float racc_v[4][3] = {{0.f,0.f,0.f},{0.f,0.f,0.f},{0.f,0.f,0.f},{0.f,0.f,0.f}};

    const float px = pos[n * 3 + 0], py = pos[n * 3 + 1], pz = pos[n * 3 + 2];

    for (int base = lo; base < hi; base += TE_G) {
        const int ne = min(TE_G, hi - base);
        __syncthreads();   // protect previous iteration's LDS reads
        // A1: edge geometry
        if (tid < TE_G) {
            if (tid < ne) {
                int e  = esort[base + tid];
                int cl = ecol[e];
                sh_col[tid] = cl;
                float dx = pos[cl*3+0] - px;
                float dy = pos[cl*3+1] - py;
                float dz = pos[cl*3+2] - pz;
                float dist = sqrtf(dx*dx + dy*dy + dz*dz + 1e-12f);
                float inv = 1.f / (dist + 1e-8f);
                sh_dir[tid][0] = dx*inv; sh_dir[tid][1] = dy*inv; sh_dir[tid][2] = dz*inv;
                sh_dir[tid][3] = dist;
            } else {
                sh_col[tid] = 0;
                sh_dir[tid][0] = sh_dir[tid][1] = sh_dir[tid][2] = 0.f;
                sh_dir[tid][3] = 0.f;
            }
        }
        __syncthreads();
        // A2: rbf
        for (int i = tid; i < TE_G * RDIM; i += TH) {
            int e = i / RDIM, r = i - e * RDIM;
            float d = sh_dir[e][3] - centers[r];
            sh_rbf[e][r] = __expf(-gamma[r] * d * d);
        }
        __syncthreads();
        // A3: h = silu(rbf @ fw1 + fb1), stored transposed
        for (int i = tid; i < TE_G * FDIM; i += TH) {
            int e = i >> 7, f = i & 127;
            float acc = fb1[f];
            #pragma unroll
            for (int r = 0; r < RDIM; ++r) acc += sh_rbf[e][r] * fw1[r * FDIM + f];
            sh_ht[f][e] = siluf(acc);
        }

        // B: phi = h @ fw2 + fb2  (3 gates x 4 feats x 4 edges per thread)
        float pg[3][4][4];
        #pragma unroll
        for (int g3 = 0; g3 < 3; ++g3)
            #pragma unroll
            for (int ee = 0; ee < 4; ++ee)
                #pragma unroll
                for (int i = 0; i < 4; ++i) pg[g3][ee][i] = fb2[g3 * FDIM + f0 + i];

        const int kkr = tid >> 3;   // 0..31: row for staging
        const int t8  = tid & 7;
        for (int kc = 0; kc < 4; ++kc) {
            __syncthreads();
            // stage fw2 rows [kc*32, kc*32+32) x 384
            #pragma unroll
            for (int j = 0; j < 12; ++j) {
                int g = (t8 * 12 + j) * 4;
                float4 w4 = *(const float4*)&fw2[(size_t)(kc * 32 + kkr) * (3 * FDIM) + g];
                *(float4*)&sh_w[kkr][g] = w4;
            }
            __syncthreads();
            #pragma unroll 4
            for (int kk = 0; kk < 32; ++kk) {
                float hv[4];
                #pragma unroll
                for (int ee = 0; ee < 4; ++ee) hv[ee] = sh_ht[kc * 32 + kk][4 * eq + ee];
                #pragma unroll
                for (int g3 = 0; g3 < 3; ++g3) {
                    float4 w4 = *(const float4*)&sh_w[kk][g3 * FDIM + f0];
                    #pragma unroll
                    for (int ee = 0; ee < 4; ++ee) {
                        pg[g3][ee][0] += hv[ee] * w4.x;
                        pg[g3][ee][1] += hv[ee] * w4.y;
                        pg[g3][ee][2] += hv[ee] * w4.z;
                        pg[g3][ee][3] += hv[ee] * w4.w;
                    }
                }
            }
        }

        // C: accumulate this chunk's contributions into registers
        #pragma unroll
        for (int ee = 0; ee < 4; ++ee) {
            int el = 4 * eq + ee;
            if (base + el < hi) {
                int cl = sh_col[el];
                float d0 = sh_dir[el][0], d1 = sh_dir[el][1], d2 = sh_dir[el][2];
                #pragma unroll
                for (int i = 0; i < 4; ++i) {
                    int f = f0 + i;
                    float sc = s[(size_t)cl * FDIM + f];
                    racc_s[i] += pg[0][ee][i] * sc;
                    size_t vi = ((size_t)cl * FDIM + f) * 3;
                    float pvv = pg[1][ee][i];
                    float svs = pg[2][ee][i] * sc;
                    racc_v[i][0] += pvv * v[vi + 0] + svs * d0;
                    racc_v[i][1] += pvv * v[vi + 1] + svs * d1;
                    racc_v[i][2] += pvv * v[vi + 2] + svs * d2;
                }
            }
        }
    }

    // reduce across the 8 edge-groups (lane bits 0..2)
    #pragma unroll
    for (int m = 1; m <= 4; m <<= 1) {
        #pragma unroll
        for (int i = 0; i < 4; ++i) {
            racc_s[i] += __shfl_xor(racc_s[i], m, 64);
            #pragma unroll
            for (int k = 0; k < 3; ++k) racc_v[i][k] += __shfl_xor(racc_v[i][k], m, 64);
        }
    }
    if (eq == 0) {
        float4 ms4 = make_float4(racc_s[0], racc_s[1], racc_s[2], racc_s[3]);
        *(float4*)&m_s[(size_t)n * FDIM + f0] = ms4;
        float* mv = &m_v[((size_t)n * FDIM + f0) * 3];
        float4 a = make_float4(racc_v[0][0], racc_v[0][1], racc_v[0][2], racc_v[1][0]);
        float4 b = make_float4(racc_v[1][1], racc_v[1][2], racc_v[2][0], racc_v[2][1]);
        float4 c = make_float4(racc_v[2][2], racc_v[3][0], racc_v[3][1], racc_v[3][2]);
        *(float4*)&mv[0] = a; *(float4*)&mv[4] = b; *(float4*)&mv[8] = c;
    }
}

// ---------------------------------------------------------------- update kernel (one layer)
__global__ __launch_bounds__(TH) void k_update(
    const float* __restrict__ uw1, const float* __restrict__ ub1,
    const float* __restrict__ uw2, const float* __restrict__ ub2,
    float* __restrict__ s, float* __restrict__ v,
    const float* __restrict__ m_s, const float* __restrict__ m_v, int N)
{
    __shared__ float sh_x[TN_U][3 * FDIM + 10];  // stride 394
    __shared__ float sh_w[32][FDIM];
    __shared__ float sh_u1[TN_U][FDIM + 2];      // stride 130

    const int tid = threadIdx.x;
    const int n0  = blockIdx.x * TN_U;

    // A: x = [s, m_s, v_norm]
    for (int i = tid; i < TN_U * FDIM; i += TH) {
        int n = i >> 7, f = i & 127;
        int ng = n0 + n;
        if (ng < N) {
            sh_x[n][f]          = s[ng * FDIM + f];
            sh_x[n][FDIM + f]   = m_s[ng * FDIM + f];
            int vi = (ng * FDIM + f) * 3;
            float a = m_v[vi], b = m_v[vi+1], c = m_v[vi+2];
            sh_x[n][2*FDIM + f] = sqrtf(a*a + b*b + c*c + 1e-12f);
        } else {
            sh_x[n][f] = sh_x[n][FDIM+f] = sh_x[n][2*FDIM+f] = 0.f;
        }
    }

    const int eq = tid & 7;     // node pair: nodes 2eq, 2eq+1
    const int fq = tid >> 3;    // 0..31
    const int f0 = fq * 4;

    // B: u1 = silu(x @ uw1 + ub1)
    float accB[2][4];
    #pragma unroll
    for (int j = 0; j < 2; ++j)
        #pragma unroll
        for (int i = 0; i < 4; ++i) accB[j][i] = ub1[f0 + i];
    for (int kc = 0; kc < 12; ++kc) {
        __syncthreads();
        for (int i2 = tid; i2 < 32 * FDIM; i2 += TH) {
            int kk = i2 >> 7, f = i2 & 127;
            sh_w[kk][f] = uw1[(kc * 32 + kk) * FDIM + f];
        }
        __syncthreads();
        #pragma unroll 2
        for (int kk = 0; kk < 32; ++kk) {
            float4 w4 = *(const float4*)(&sh_w[kk][f0]);
            #pragma unroll
            for (int j = 0; j < 2; ++j) {
                float xv = sh_x[2*eq + j][kc * 32 + kk];
                accB[j][0] += xv * w4.x; accB[j][1] += xv * w4.y;
                accB[j][2] += xv * w4.z; accB[j][3] += xv * w4.w;
            }
        }
    }
    __syncthreads();
    #pragma unroll
    for (int j = 0; j < 2; ++j)
        #pragma unroll
        for (int i = 0; i < 4; ++i) sh_u1[2*eq + j][f0 + i] = siluf(accB[j][i]);

    // C: upd = u1 @ uw2 + ub2 ; apply delta_s / alpha / beta
    float alpha[2][4];
    #pragma unroll
    for (int g3 = 0; g3 < 3; ++g3) {
        float a2[2][4];
        #pragma unroll
        for (int j = 0; j < 2; ++j)
            #pragma unroll
            for (int i = 0; i < 4; ++i) a2[j][i] = ub2[g3 * FDIM + f0 + i];
        for (int kc = 0; kc < 4; ++kc) {
            __syncthreads();
            for (int i2 = tid; i2 < 32 * FDIM; i2 += TH) {
                int kk = i2 >> 7, f = i2 & 127;
                sh_w[kk][f] = uw2[(kc * 32 + kk) * (3 * FDIM) + g3 * FDIM + f];
            }
            __syncthreads();
            #pragma unroll 2
            for (int kk = 0; kk < 32; ++kk) {
                float4 w4 = *(const float4*)(&sh_w[kk][f0]);
                #pragma unroll
                for (int j = 0; j < 2; ++j) {
                    float uv = sh_u1[2*eq + j][kc * 32 + kk];
                    a2[j][0] += uv * w4.x; a2[j][1] += uv * w4.y;
                    a2[j][2] += uv * w4.z; a2[j][3] += uv * w4.w;
                }
            }
        }
        #pragma unroll
        for (int j = 0; j < 2; ++j) {
            int ng = n0 + 2*eq + j;
            if (ng >= N) continue;
            if (g3 == 0) {
                #pragma unroll
                for (int i = 0; i < 4; ++i) s[ng * FDIM + f0 + i] += a2[j][i];
            } else if (g3 == 1) {
                #pragma unroll
                for (int i = 0; i < 4; ++i) alpha[j][i] = a2[j][i];
            } else {
                #pragma unroll
                for (int i = 0; i < 4; ++i) {
                    int vi = (ng * FDIM + f0 + i) * 3;
                    #pragma unroll
                    for (int k = 0; k < 3; ++k)
                        v[vi + k] = alpha[j][i] * v[vi + k] + a2[j][i] * m_v[vi + k];
                }
            }
        }
    }
}

// ---------------------------------------------------------------- energy head
__global__ __launch_bounds__(TH) void k_energy(
    const float* __restrict__ ew1, const float* __restrict__ eb1,
    const float* __restrict__ ew2, const float* __restrict__ eb2,
    const float* __restrict__ s, const int* __restrict__ batch,
    float* __restrict__ energies, int N, int S)
{
    __shared__ float sh_s[TN_E][FDIM + 2];   // stride 130
    __shared__ float sh_w[64][FDIM];
    __shared__ float sh_e[TN_E];

    const int tid = threadIdx.x;
    const int n0  = blockIdx.x * TN_E;

    for (int i = tid; i < TN_E * FDIM; i += TH) {
        int n = i >> 7, f = i & 127;
        int ng = n0 + n;
        sh_s[n][f] = (ng < N) ? s[ng * FDIM + f] : 0.f;
    }

    const int eq = tid & 7;      // node quad
    const int gq = tid >> 3;     // 0..31
    const int g0 = gq * 4;

    for (int st = 0; st < S; ++st) {
        __syncthreads();
        if (tid < TN_E) sh_e[tid] = 0.f;
        float acc[4][4];
        #pragma unroll
        for (int ee = 0; ee < 4; ++ee)
            #pragma unroll
            for (int i = 0; i < 4; ++i) acc[ee][i] = eb1[st * FDIM + g0 + i];
        for (int fc = 0; fc < 2; ++fc) {
            __syncthreads();
            for (int i2 = tid; i2 < 64 * FDIM; i2 += TH) {
                int ff = i2 >> 7, g = i2 & 127;
                sh_w[ff][g] = ew1[(st * FDIM + fc * 64 + ff) * FDIM + g];
            }
            __syncthreads();
            #pragma unroll 2
            for (int ff = 0; ff < 64; ++ff) {
                float4 w4 = *(const float4*)(&sh_w[ff][g0]);
                #pragma unroll
                for (int ee = 0; ee < 4; ++ee) {
                    float sv = sh_s[4*eq + ee][fc * 64 + ff];
                    acc[ee][0] += sv * w4.x; acc[ee][1] += sv * w4.y;
                    acc[ee][2] += sv * w4.z; acc[ee][3] += sv * w4.w;
                }
            }
        }
        __syncthreads();
        #pragma unroll
        for (int ee = 0; ee < 4; ++ee) {
            float p = 0.f;
            #pragma unroll
            for (int i = 0; i < 4; ++i) p += siluf(acc[ee][i]) * ew2[st * FDIM + g0 + i];
            atomicAdd(&sh_e[4*eq + ee], p);
        }
        __syncthreads();
        if (tid < TN_E) {
            int ng = n0 + tid;
            if (ng < N) atomicAdd(&energies[batch[ng] * S + st], sh_e[tid] + eb2[st]);
        }
    }
}

// ---------------------------------------------------------------- dipole / nac heads
__global__ void k_vec(const float* __restrict__ v, const float* __restrict__ dipole_w,
                      const float* __restrict__ nac_w, const int* __restrict__ batch,
                      float* __restrict__ dipoles, float* __restrict__ nac, int N)
{
    int n = blockIdx.x * 4 + (threadIdx.x >> 6);
    int lane = threadIdx.x & 63;
    if (n >= N) return;
    float pd[3] = {0.f, 0.f, 0.f};
    float pn[3][3] = {{0.f}};
    for (int f = lane; f < FDIM; f += 64) {
        int vi = (n * FDIM + f) * 3;
        float v0 = v[vi], v1 = v[vi+1], v2 = v[vi+2];
        float wd = dipole_w[f];
        pd[0] += wd * v0; pd[1] += wd * v1; pd[2] += wd * v2;
        #pragma unroll
        for (int p = 0; p < 3; ++p) {
            float wn = nac_w[p * FDIM + f];
            pn[p][0] += wn * v0; pn[p][1] += wn * v1; pn[p][2] += wn * v2;
        }
    }
    #pragma unroll
    for (int d = 32; d > 0; d >>= 1) {
        #pragma unroll
        for (int k = 0; k < 3; ++k) pd[k] += __shfl_down(pd[k], d, 64);
        #pragma unroll
        for (int p = 0; p < 3; ++p)
            #pragma unroll
            for (int k = 0; k < 3; ++k) pn[p][k] += __shfl_down(pn[p][k], d, 64);
    }
    if (lane == 0) {
        int m = batch[n];
        #pragma unroll
        for (int k = 0; k < 3; ++k) atomicAdd(&dipoles[m * 3 + k], pd[k]);
        #pragma unroll
        for (int p = 0; p < 3; ++p)
            #pragma unroll
            for (int k = 0; k < 3; ++k) atomicAdd(&nac[(m * 3 + p) * 3 + k], pn[p][k]);
    }
}

// ---------------------------------------------------------------- per-molecule heads
__global__ __launch_bounds__(128) void k_heads(
    const float* __restrict__ aw1, const float* __restrict__ ab1,
    const float* __restrict__ aw2, const float* __restrict__ ab2,
    const float* __restrict__ yw1, const float* __restrict__ yb1,
    const float* __restrict__ yw2, const float* __restrict__ yb2,
    const float* __restrict__ energies, const float* __restrict__ nac,
    float* __restrict__ lam, float* __restrict__ phi_y, int M, int S)
{
    __shared__ float sh_in[8];
    __shared__ float sh_red[2];
    int m = blockIdx.x;
    if (m >= M) return;
    int tid = threadIdx.x;
    if (tid == 0) {
        float e0 = energies[m * S];
        for (int j = 0; j < 3; ++j) sh_in[j] = energies[m * S + 1 + j] - e0;
        for (int p = 0; p < 3; ++p) {
            float a = nac[(m * 3 + p) * 3 + 0];
            float b = nac[(m * 3 + p) * 3 + 1];
            float c = nac[(m * 3 + p) * 3 + 2];
            sh_in[3 + p] = sqrtf(a*a + b*b + c*c + 1e-12f);
        }
    }
    __syncthreads();
    float pa = 0.f;
    if (tid < 64) {
        float h = ab1[tid];
        #pragma unroll
        for (int j = 0; j < 3; ++j) h += sh_in[j] * aw1[j * 64 + tid];
        pa = siluf(h) * aw2[tid];
    }
    float h2 = yb1[tid];
    #pragma unroll
    for (int j = 0; j < 6; ++j) h2 += sh_in[j] * yw1[j * 128 + tid];
    float py = siluf(h2) * yw2[tid];
    #pragma unroll
    for (int d = 32; d > 0; d >>= 1) {
        pa += __shfl_down(pa, d, 64);
        py += __shfl_down(py, d, 64);
    }
    int wid = tid >> 6, lane = tid & 63;
    if (lane == 0) sh_red[wid] = py;
    __syncthreads();
    if (tid == 0) {
        lam[m] = pa + ab2[0];
        float yt = sh_red[0] + sh_red[1] + yb2[0];
        phi_y[m] = 1.f / (1.f + __expf(-yt));
    }
}

// ---------------------------------------------------------------- launch
extern "C" void kernel_launch(void* const* d_in, const int* in_sizes, int n_in,
                              void* d_out, int out_size, void* d_ws, size_t ws_size,
                              hipStream_t stream)
{
    const int*   z        = (const int*)  d_in[0];
    const float* pos      = (const float*)d_in[1];
    const int*   eidx     = (const int*)  d_in[2];
    const int*   batch    = (const int*)  d_in[3];
    const float* emb      = (const float*)d_in[5];
    const float* centers  = (const float*)d_in[6];
    const float* gamma    = (const float*)d_in[7];
    const float* fw1      = (const float*)d_in[8];
    const float* fb1      = (const float*)d_in[9];
    const float* fw2      = (const float*)d_in[10];
    const float* fb2      = (const float*)d_in[11];
    const float* uw1      = (const float*)d_in[12];
    const float* ub1      = (const float*)d_in[13];
    const float* uw2      = (const float*)d_in[14];
    const float* ub2      = (const float*)d_in[15];
    const float* ew1      = (const float*)d_in[16];
    const float* eb1      = (const float*)d_in[17];
    const float* ew2      = (const float*)d_in[18];
    const float* eb2      = (const float*)d_in[19];
    const float* dipole_w = (const float*)d_in[20];
    const float* nac_w    = (const float*)d_in[21];
    const float* aw1      = (const float*)d_in[22];
    const float* ab1      = (const float*)d_in[23];
    const float* aw2      = (const float*)d_in[24];
    const float* ab2      = (const float*)d_in[25];
    const float* yw1      = (const float*)d_in[26];
    const float* yb1      = (const float*)d_in[27];
    const float* yw2      = (const float*)d_in[28];
    const float* yb2      = (const float*)d_in[29];

    const int N = in_sizes[0];
    const int E = in_sizes[2] / 2;
    const int S = in_sizes[19];            // eb2 is (S,1)
    const int P = in_sizes[21] / FDIM;     // nac_w is (P,F)
    const int L = in_sizes[9] / FDIM;      // fb1 is (L,F)
    const int M = out_size / (S + 3 + P * 3 + 2);

    float* s   = (float*)d_ws;
    float* v   = s   + (size_t)N * FDIM;
    float* m_s = v   + (size_t)N * FDIM * 3;
    float* m_v = m_s + (size_t)N * FDIM;
    int*   rowstart = (int*)(m_v + (size_t)N * FDIM * 3);
    int*   cursor   = rowstart + (N + 1);
    int*   esort    = cursor + N;

    float* out      = (float*)d_out;
    float* energies = out;
    float* dipoles  = energies + (size_t)M * S;
    float* nac      = dipoles  + (size_t)M * 3;
    float* lam      = nac      + (size_t)M * P * 3;
    float* phi_y    = lam      + M;

    const int* erow = eidx;
    const int* ecol = eidx + E;

    hipMemsetAsync(d_out, 0, (size_t)out_size * sizeof(float), stream);
    hipMemsetAsync(cursor, 0, (size_t)N * sizeof(int), stream);
    k_hist<<<(E + 255) / 256, 256, 0, stream>>>(erow, cursor, E);
    k_scan<<<1, 256, 0, stream>>>(cursor, rowstart, N);
    k_fill<<<(E + 255) / 256, 256, 0, stream>>>(erow, cursor, esort, E);
    k_init<<<(N * FDIM + 255) / 256, 256, 0, stream>>>(z, emb, s, v, N);

    for (int l = 0; l < L; ++l) {
        k_msg2<<<N, TH, 0, stream>>>(
            pos, ecol, rowstart, esort, centers, gamma,
            fw1 + (size_t)l * RDIM * FDIM, fb1 + (size_t)l * FDIM,
            fw2 + (size_t)l * FDIM * 3 * FDIM, fb2 + (size_t)l * 3 * FDIM,
            s, v, m_s, m_v, N);
        k_update<<<(N + TN_U - 1) / TN_U, TH, 0, stream>>>(
            uw1 + (size_t)l * 3 * FDIM * FDIM, ub1 + (size_t)l * FDIM,
            uw2 + (size_t)l * FDIM * 3 * FDIM, ub2 + (size_t)l * 3 * FDIM,
            s, v, m_s, m_v, N);
    }

    k_energy<<<(N + TN_E - 1) / TN_E, TH, 0, stream>>>(ew1, eb1, ew2, eb2, s, batch, energies, N, S);
    k_vec<<<(N + 3) / 4, 256, 0, stream>>>(v, dipole_w, nac_w, batch, dipoles, nac, N);
    k_heads<<<M, 128, 0, stream>>>(aw1, ab1, aw2, ab2, yw1, yb1, yw2, yb2,
                                   energies, nac, lam, phi_y, M, S);
}

// Round 3
// 1284.254 us; speedup vs baseline: 13.3860x; 6.3417x over previous
//
#include <hip/hip_runtime.h>

#define FDIM 128
#define RDIM 20

#define TAB_T 2048              // table cells; TAB_T+1 rows
#define TAB_RANGE 12.0f

constexpr int TH   = 256;
constexpr int TN_U = 16;   // nodes per block (update kernel)
constexpr int TN_E = 32;   // nodes per block (energy kernel)

__device__ __forceinline__ float siluf(float x) { return x / (1.f + __expf(-x)); }

// ---------------------------------------------------------------- init: s = emb[z], v = 0
__global__ void k_init(const int* __restrict__ z, const float* __restrict__ emb,
                       float* __restrict__ s, float* __restrict__ v, int N) {
    int i = blockIdx.x * blockDim.x + threadIdx.x;
    if (i >= N * FDIM) return;
    int n = i >> 7, f = i & 127;
    s[i] = emb[z[n] * FDIM + f];
    v[i * 3 + 0] = 0.f; v[i * 3 + 1] = 0.f; v[i * 3 + 2] = 0.f;
}

// ---------------------------------------------------------------- CSR build
__global__ void k_hist(const int* __restrict__ erow, int* __restrict__ cursor, int E) {
    int e = blockIdx.x * blockDim.x + threadIdx.x;
    if (e < E) atomicAdd(&cursor[erow[e]], 1);
}

__global__ __launch_bounds__(256) void k_scan(int* __restrict__ cursor,
                                              int* __restrict__ rowstart, int N) {
    __shared__ int sh[256];
    __shared__ int carry;
    int tid = threadIdx.x;
    if (tid == 0) carry = 0;
    __syncthreads();
    for (int base = 0; base < N; base += 256) {
        int idx = base + tid;
        int x = (idx < N) ? cursor[idx] : 0;
        sh[tid] = x;
        __syncthreads();
        for (int off = 1; off < 256; off <<= 1) {
            int t = (tid >= off) ? sh[tid - off] : 0;
            __syncthreads();
            sh[tid] += t;
            __syncthreads();
        }
        int excl = carry + sh[tid] - x;
        if (idx < N) { rowstart[idx] = excl; cursor[idx] = excl; }
        __syncthreads();
        if (tid == 0) carry += sh[255];
        __syncthreads();
    }
    if (tid == 0) rowstart[N] = carry;
}

__global__ void k_fill(const int* __restrict__ erow, int* __restrict__ cursor,
                       int* __restrict__ esort, int E) {
    int e = blockIdx.x * blockDim.x + threadIdx.x;
    if (e < E) {
        int p = atomicAdd(&cursor[erow[e]], 1);
        esort[p] = e;
    }
}

// ---------------------------------------------------------------- filter-MLP table build
// phi(dist) is a smooth 1-D function: tabulate TAB_T+1 points over [0, TAB_RANGE].
// 32 points per block; same register-tiled GEMM as the old message kernel.
__global__ __launch_bounds__(TH) void k_table(
    const float* __restrict__ centers, const float* __restrict__ gamma,
    const float* __restrict__ fw1, const float* __restrict__ fb1,
    const float* __restrict__ fw2, const float* __restrict__ fb2,
    float* __restrict__ tab, float step)
{
    __shared__ float sh_rbf[32][RDIM];
    __shared__ float sh_ht[FDIM][33];          // h transposed [k][point]
    __shared__ float sh_w[32][3 * FDIM + 4];   // fw2 chunk, stride 388

    const int p0  = blockIdx.x * 32;
    const int tid = threadIdx.x;

    // rbf
    for (int i = tid; i < 32 * RDIM; i += TH) {
        int p = i / RDIM, r = i - p * RDIM;
        float d = (float)(p0 + p) * step - centers[r];
        sh_rbf[p][r] = __expf(-gamma[r] * d * d);
    }
    __syncthreads();
    // h = silu(rbf @ fw1 + fb1), transposed
    for (int i = tid; i < 32 * FDIM; i += TH) {
        int p = i >> 7, f = i & 127;
        float acc = fb1[f];
        #pragma unroll
        for (int r = 0; r < RDIM; ++r) acc += sh_rbf[p][r] * fw1[r * FDIM + f];
        sh_ht[f][p] = siluf(acc);
    }

    const int eq = tid & 7;      // point quad
    const int fq = tid >> 3;     // 0..31
    const int f0 = fq * 4;

    float pg[3][4][4];
    #pragma unroll
    for (int g3 = 0; g3 < 3; ++g3)
        #pragma unroll
        for (int ee = 0; ee < 4; ++ee)
            #pragma unroll
            for (int i = 0; i < 4; ++i) pg[g3][ee][i] = fb2[g3 * FDIM + f0 + i];

    const int kkr = tid >> 3;
    const int t8  = tid & 7;
    for (int kc = 0; kc < 4; ++kc) {
        __syncthreads();
        #pragma unroll
        for (int j = 0; j < 12; ++j) {
            int g = (t8 * 12 + j) * 4;
            float4 w4 = *(const float4*)&fw2[(size_t)(kc * 32 + kkr) * (3 * FDIM) + g];
            *(float4*)&sh_w[kkr][g] = w4;
        }
        __syncthreads();
        #pragma unroll 4
        for (int kk = 0; kk < 32; ++kk) {
            float hv[4];
            #pragma unroll
            for (int ee = 0; ee < 4; ++ee) hv[ee] = sh_ht[kc * 32 + kk][4 * eq + ee];
            #pragma unroll
            for (int g3 = 0; g3 < 3; ++g3) {
                float4 w4 = *(const float4*)&sh_w[kk][g3 * FDIM + f0];
                #pragma unroll
                for (int ee = 0; ee < 4; ++ee) {
                    pg[g3][ee][0] += hv[ee] * w4.x;
                    pg[g3][ee][1] += hv[ee] * w4.y;
                    pg[g3][ee][2] += hv[ee] * w4.z;
                    pg[g3][ee][3] += hv[ee] * w4.w;
                }
            }
        }
    }

    #pragma unroll
    for (int ee = 0; ee < 4; ++ee) {
        int pt = p0 + 4 * eq + ee;
        if (pt <= TAB_T) {
            #pragma unroll
            for (int g3 = 0; g3 < 3; ++g3)
                *(float4*)&tab[(size_t)pt * 384 + g3 * FDIM + f0] =
                    make_float4(pg[g3][ee][0], pg[g3][ee][1], pg[g3][ee][2], pg[g3][ee][3]);
        }
    }
}

// ---------------------------------------------------------------- gather message kernel
// One 128-thread block per node; thread = feature. Table-lerp replaces the MLP.
__global__ __launch_bounds__(128) void k_gather(
    const float* __restrict__ pos, const int* __restrict__ ecol,
    const int* __restrict__ rowstart, const int* __restrict__ esort,
    const float* __restrict__ tab, const float* __restrict__ s, const float* __restrict__ v,
    float* __restrict__ m_s, float* __restrict__ m_v, float inv_step, int N)
{
    __shared__ int   sh_col[32];
    __shared__ int   sh_t0[32];
    __shared__ float sh_w[32];
    __shared__ float sh_d0[32], sh_d1[32], sh_d2[32];

    const int n   = blockIdx.x;
    const int tid = threadIdx.x;   // 0..127 = feature
    const int lo  = rowstart[n], hi = rowstart[n + 1];

    float acc_s = 0.f, av0 = 0.f, av1 = 0.f, av2 = 0.f;
    const float px = pos[n * 3 + 0], py = pos[n * 3 + 1], pz = pos[n * 3 + 2];

    for (int base = lo; base < hi; base += 32) {
        const int ne = min(32, hi - base);
        __syncthreads();
        if (tid < 32) {
            if (tid < ne) {
                int e  = esort[base + tid];
                int cl = ecol[e];
                float dx = pos[cl*3+0] - px;
                float dy = pos[cl*3+1] - py;
                float dz = pos[cl*3+2] - pz;
                float dist = sqrtf(dx*dx + dy*dy + dz*dz + 1e-12f);
                float inv = 1.f / (dist + 1e-8f);
                sh_col[tid] = cl;
                sh_d0[tid] = dx*inv; sh_d1[tid] = dy*inv; sh_d2[tid] = dz*inv;
                float u = fminf(dist * inv_step, (float)TAB_T);
                int t0 = min((int)u, TAB_T - 1);
                sh_t0[tid] = t0;
                sh_w[tid]  = u - (float)t0;
            } else {
                sh_col[tid] = 0; sh_t0[tid] = 0; sh_w[tid] = 0.f;
                sh_d0[tid] = sh_d1[tid] = sh_d2[tid] = 0.f;
            }
        }
        __syncthreads();
        #pragma unroll 2
        for (int el = 0; el < ne; ++el) {
            int   cl = sh_col[el];
            int   t0 = sh_t0[el];
            float w  = sh_w[el];
            const float* ta = tab + (size_t)t0 * 384 + tid;
            float a_ss = ta[0],   b_ss = ta[384];
            float a_vv = ta[128], b_vv = ta[512];
            float a_sv = ta[256], b_sv = ta[640];
            float pss = a_ss + w * (b_ss - a_ss);
            float pvv = a_vv + w * (b_vv - a_vv);
            float psv = a_sv + w * (b_sv - a_sv);
            float sc = s[(size_t)cl * FDIM + tid];
            const float* vp = v + ((size_t)cl * FDIM + tid) * 3;
            float svs = psv * sc;
            acc_s += pss * sc;
            av0 += pvv * vp[0] + svs * sh_d0[el];
            av1 += pvv * vp[1] + svs * sh_d1[el];
            av2 += pvv * vp[2] + svs * sh_d2[el];
        }
    }

    m_s[(size_t)n * FDIM + tid] = acc_s;
    float* mv = m_v + ((size_t)n * FDIM + tid) * 3;
    mv[0] = av0; mv[1] = av1; mv[2] = av2;
}

// ---------------------------------------------------------------- update kernel (one layer)
__global__ __launch_bounds__(TH) void k_update(
    const float* __restrict__ uw1, const float* __restrict__ ub1,
    const float* __restrict__ uw2, const float* __restrict__ ub2,
    float* __restrict__ s, float* __restrict__ v,
    const float* __restrict__ m_s, const float* __restrict__ m_v, int N)
{
    __shared__ float sh_x[TN_U][3 * FDIM + 10];  // stride 394
    __shared__ float sh_w[32][FDIM];
    __shared__ float sh_u1[TN_U][FDIM + 2];      // stride 130

    const int tid = threadIdx.x;
    const int n0  = blockIdx.x * TN_U;

    // A: x = [s, m_s, v_norm]
    for (int i = tid; i < TN_U * FDIM; i += TH) {
        int n = i >> 7, f = i & 127;
        int ng = n0 + n;
        if (ng < N) {
            sh_x[n][f]          = s[ng * FDIM + f];
            sh_x[n][FDIM + f]   = m_s[ng * FDIM + f];
            int vi = (ng * FDIM + f) * 3;
            float a = m_v[vi], b = m_v[vi+1], c = m_v[vi+2];
            sh_x[n][2*FDIM + f] = sqrtf(a*a + b*b + c*c + 1e-12f);
        } else {
            sh_x[n][f] = sh_x[n][FDIM+f] = sh_x[n][2*FDIM+f] = 0.f;
        }
    }

    const int eq = tid & 7;     // node pair: nodes 2eq, 2eq+1
    const int fq = tid >> 3;    // 0..31
    const int f0 = fq * 4;

    // B: u1 = silu(x @ uw1 + ub1)
    float accB[2][4];
    #pragma unroll
    for (int j = 0; j < 2; ++j)
        #pragma unroll
        for (int i = 0; i < 4; ++i) accB[j][i] = ub1[f0 + i];
    for (int kc = 0; kc < 12; ++kc) {
        __syncthreads();
        for (int i2 = tid; i2 < 32 * FDIM; i2 += TH) {
            int kk = i2 >> 7, f = i2 & 127;
            sh_w[kk][f] = uw1[(kc * 32 + kk) * FDIM + f];
        }
        __syncthreads();
        #pragma unroll 2
        for (int kk = 0; kk < 32; ++kk) {
            float4 w4 = *(const float4*)(&sh_w[kk][f0]);
            #pragma unroll
            for (int j = 0; j < 2; ++j) {
                float xv = sh_x[2*eq + j][kc * 32 + kk];
                accB[j][0] += xv * w4.x; accB[j][1] += xv * w4.y;
                accB[j][2] += xv * w4.z; accB[j][3] += xv * w4.w;
            }
        }
    }
    __syncthreads();
    #pragma unroll
    for (int j = 0; j < 2; ++j)
        #pragma unroll
        for (int i = 0; i < 4; ++i) sh_u1[2*eq + j][f0 + i] = siluf(accB[j][i]);

    // C: upd = u1 @ uw2 + ub2 ; apply delta_s / alpha / beta
    float alpha[2][4];
    #pragma unroll
    for (int g3 = 0; g3 < 3; ++g3) {
        float a2[2][4];
        #pragma unroll
        for (int j = 0; j < 2; ++j)
            #pragma unroll
            for (int i = 0; i < 4; ++i) a2[j][i] = ub2[g3 * FDIM + f0 + i];
        for (int kc = 0; kc < 4; ++kc) {
            __syncthreads();
            for (int i2 = tid; i2 < 32 * FDIM; i2 += TH) {
                int kk = i2 >> 7, f = i2 & 127;
                sh_w[kk][f] = uw2[(kc * 32 + kk) * (3 * FDIM) + g3 * FDIM + f];
            }
            __syncthreads();
            #pragma unroll 2
            for (int kk = 0; kk < 32; ++kk) {
                float4 w4 = *(const float4*)(&sh_w[kk][f0]);
                #pragma unroll
                for (int j = 0; j < 2; ++j) {
                    float uv = sh_u1[2*eq + j][kc * 32 + kk];
                    a2[j][0] += uv * w4.x; a2[j][1] += uv * w4.y;
                    a2[j][2] += uv * w4.z; a2[j][3] += uv * w4.w;
                }
            }
        }
        #pragma unroll
        for (int j = 0; j < 2; ++j) {
            int ng = n0 + 2*eq + j;
            if (ng >= N) continue;
            if (g3 == 0) {
                #pragma unroll
                for (int i = 0; i < 4; ++i) s[ng * FDIM + f0 + i] += a2[j][i];
            } else if (g3 == 1) {
                #pragma unroll
                for (int i = 0; i < 4; ++i) alpha[j][i] = a2[j][i];
            } else {
                #pragma unroll
                for (int i = 0; i < 4; ++i) {
                    int vi = (ng * FDIM + f0 + i) * 3;
                    #pragma unroll
                    for (int k = 0; k < 3; ++k)
                        v[vi + k] = alpha[j][i] * v[vi + k] + a2[j][i] * m_v[vi + k];
                }
            }
        }
    }
}

// ---------------------------------------------------------------- energy head
__global__ __launch_bounds__(TH) void k_energy(
    const float* __restrict__ ew1, const float* __restrict__ eb1,
    const float* __restrict__ ew2, const float* __restrict__ eb2,
    const float* __restrict__ s, const int* __restrict__ batch,
    float* __restrict__ energies, int N, int S)
{
    __shared__ float sh_s[TN_E][FDIM + 2];   // stride 130
    __shared__ float sh_w[64][FDIM];
    __shared__ float sh_e[TN_E];

    const int tid = threadIdx.x;
    const int n0  = blockIdx.x * TN_E;

    for (int i = tid; i < TN_E * FDIM; i += TH) {
        int n = i >> 7, f = i & 127;
        int ng = n0 + n;
        sh_s[n][f] = (ng < N) ? s[ng * FDIM + f] : 0.f;
    }

    const int eq = tid & 7;      // node quad
    const int gq = tid >> 3;     // 0..31
    const int g0 = gq * 4;

    for (int st = 0; st < S; ++st) {
        __syncthreads();
        if (tid < TN_E) sh_e[tid] = 0.f;
        float acc[4][4];
        #pragma unroll
        for (int ee = 0; ee < 4; ++ee)
            #pragma unroll
            for (int i = 0; i < 4; ++i) acc[ee][i] = eb1[st * FDIM + g0 + i];
        for (int fc = 0; fc < 2; ++fc) {
            __syncthreads();
            for (int i2 = tid; i2 < 64 * FDIM; i2 += TH) {
                int ff = i2 >> 7, g = i2 & 127;
                sh_w[ff][g] = ew1[(st * FDIM + fc * 64 + ff) * FDIM + g];
            }
            __syncthreads();
            #pragma unroll 2
            for (int ff = 0; ff < 64; ++ff) {
                float4 w4 = *(const float4*)(&sh_w[ff][g0]);
                #pragma unroll
                for (int ee = 0; ee < 4; ++ee) {
                    float sv = sh_s[4*eq + ee][fc * 64 + ff];
                    acc[ee][0] += sv * w4.x; acc[ee][1] += sv * w4.y;
                    acc[ee][2] += sv * w4.z; acc[ee][3] += sv * w4.w;
                }
            }
        }
        __syncthreads();
        #pragma unroll
        for (int ee = 0; ee < 4; ++ee) {
            float p = 0.f;
            #pragma unroll
            for (int i = 0; i < 4; ++i) p += siluf(acc[ee][i]) * ew2[st * FDIM + g0 + i];
            atomicAdd(&sh_e[4*eq + ee], p);
        }
        __syncthreads();
        if (tid < TN_E) {
            int ng = n0 + tid;
            if (ng < N) atomicAdd(&energies[batch[ng] * S + st], sh_e[tid] + eb2[st]);
        }
    }
}

// ---------------------------------------------------------------- dipole / nac heads
__global__ void k_vec(const float* __restrict__ v, const float* __restrict__ dipole_w,
                      const float* __restrict__ nac_w, const int* __restrict__ batch,
                      float* __restrict__ dipoles, float* __restrict__ nac, int N)
{
    int n = blockIdx.x * 4 + (threadIdx.x >> 6);
    int lane = threadIdx.x & 63;
    if (n >= N) return;
    float pd[3] = {0.f, 0.f, 0.f};
    float pn[3][3] = {{0.f}};
    for (int f = lane; f < FDIM; f += 64) {
        int vi = (n * FDIM + f) * 3;
        float v0 = v[vi], v1 = v[vi+1], v2 = v[vi+2];
        float wd = dipole_w[f];
        pd[0] += wd * v0; pd[1] += wd * v1; pd[2] += wd * v2;
        #pragma unroll
        for (int p = 0; p < 3; ++p) {
            float wn = nac_w[p * FDIM + f];
            pn[p][0] += wn * v0; pn[p][1] += wn * v1; pn[p][2] += wn * v2;
        }
    }
    #pragma unroll
    for (int d = 32; d > 0; d >>= 1) {
        #pragma unroll
        for (int k = 0; k < 3; ++k) pd[k] += __shfl_down(pd[k], d, 64);
        #pragma unroll
        for (int p = 0; p < 3; ++p)
            #pragma unroll
            for (int k = 0; k < 3; ++k) pn[p][k] += __shfl_down(pn[p][k], d, 64);
    }
    if (lane == 0) {
        int m = batch[n];
        #pragma unroll
        for (int k = 0; k < 3; ++k) atomicAdd(&dipoles[m * 3 + k], pd[k]);
        #pragma unroll
        for (int p = 0; p < 3; ++p)
            #pragma unroll
            for (int k = 0; k < 3; ++k) atomicAdd(&nac[(m * 3 + p) * 3 + k], pn[p][k]);
    }
}

// ---------------------------------------------------------------- per-molecule heads
__global__ __launch_bounds__(128) void k_heads(
    const float* __restrict__ aw1, const float* __restrict__ ab1,
    const float* __restrict__ aw2, const float* __restrict__ ab2,
    const float* __restrict__ yw1, const float* __restrict__ yb1,
    const float* __restrict__ yw2, const float* __restrict__ yb2,
    const float* __restrict__ energies, const float* __restrict__ nac,
    float* __restrict__ lam, float* __restrict__ phi_y, int M, int S)
{
    __shared__ float sh_in[8];
    __shared__ float sh_red[2];
    int m = blockIdx.x;
    if (m >= M) return;
    int tid = threadIdx.x;
    if (tid == 0) {
        float e0 = energies[m * S];
        for (int j = 0; j < 3; ++j) sh_in[j] = energies[m * S + 1 + j] - e0;
        for (int p = 0; p < 3; ++p) {
            float a = nac[(m * 3 + p) * 3 + 0];
            float b = nac[(m * 3 + p) * 3 + 1];
            float c = nac[(m * 3 + p) * 3 + 2];
            sh_in[3 + p] = sqrtf(a*a + b*b + c*c + 1e-12f);
        }
    }
    __syncthreads();
    float pa = 0.f;
    if (tid < 64) {
        float h = ab1[tid];
        #pragma unroll
        for (int j = 0; j < 3; ++j) h += sh_in[j] * aw1[j * 64 + tid];
        pa = siluf(h) * aw2[tid];
    }
    float h2 = yb1[tid];
    #pragma unroll
    for (int j = 0; j < 6; ++j) h2 += sh_in[j] * yw1[j * 128 + tid];
    float py = siluf(h2) * yw2[tid];
    #pragma unroll
    for (int d = 32; d > 0; d >>= 1) {
        pa += __shfl_down(pa, d, 64);
        py += __shfl_down(py, d, 64);
    }
    int wid = tid >> 6, lane = tid & 63;
    if (lane == 0) sh_red[wid] = py;
    __syncthreads();
    if (tid == 0) {
        lam[m] = pa + ab2[0];
        float yt = sh_red[0] + sh_red[1] + yb2[0];
        phi_y[m] = 1.f / (1.f + __expf(-yt));
    }
}

// ---------------------------------------------------------------- launch
extern "C" void kernel_launch(void* const* d_in, const int* in_sizes, int n_in,
                              void* d_out, int out_size, void* d_ws, size_t ws_size,
                              hipStream_t stream)
{
    const int*   z        = (const int*)  d_in[0];
    const float* pos      = (const float*)d_in[1];
    const int*   eidx     = (const int*)  d_in[2];
    const int*   batch    = (const int*)  d_in[3];
    const float* emb      = (const float*)d_in[5];
    const float* centers  = (const float*)d_in[6];
    const float* gamma    = (const float*)d_in[7];
    const float* fw1      = (const float*)d_in[8];
    const float* fb1      = (const float*)d_in[9];
    const float* fw2      = (const float*)d_in[10];
    const float* fb2      = (const float*)d_in[11];
    const float* uw1      = (const float*)d_in[12];
    const float* ub1      = (const float*)d_in[13];
    const float* uw2      = (const float*)d_in[14];
    const float* ub2      = (const float*)d_in[15];
    const float* ew1      = (const float*)d_in[16];
    const float* eb1      = (const float*)d_in[17];
    const float* ew2      = (const float*)d_in[18];
    const float* eb2      = (const float*)d_in[19];
    const float* dipole_w = (const float*)d_in[20];
    const float* nac_w    = (const float*)d_in[21];
    const float* aw1      = (const float*)d_in[22];
    const float* ab1      = (const float*)d_in[23];
    const float* aw2      = (const float*)d_in[24];
    const float* ab2      = (const float*)d_in[25];
    const float* yw1      = (const float*)d_in[26];
    const float* yb1      = (const float*)d_in[27];
    const float* yw2      = (const float*)d_in[28];
    const float* yb2      = (const float*)d_in[29];

    const int N = in_sizes[0];
    const int E = in_sizes[2] / 2;
    const int S = in_sizes[19];            // eb2 is (S,1)
    const int P = in_sizes[21] / FDIM;     // nac_w is (P,F)
    const int L = in_sizes[9] / FDIM;      // fb1 is (L,F)
    const int M = out_size / (S + 3 + P * 3 + 2);

    // ws layout: floats first (all multiples of 4 elems), ints last
    float* s   = (float*)d_ws;
    float* v   = s   + (size_t)N * FDIM;
    float* m_s = v   + (size_t)N * FDIM * 3;
    float* m_v = m_s + (size_t)N * FDIM;
    float* tab = m_v + (size_t)N * FDIM * 3;                 // (TAB_T+1) x 384
    int*   rowstart = (int*)(tab + (size_t)(TAB_T + 1) * 384);
    int*   cursor   = rowstart + (N + 1);
    int*   esort    = cursor + N;

    float* out      = (float*)d_out;
    float* energies = out;
    float* dipoles  = energies + (size_t)M * S;
    float* nac      = dipoles  + (size_t)M * 3;
    float* lam      = nac      + (size_t)M * P * 3;
    float* phi_y    = lam      + M;

    const int* erow = eidx;
    const int* ecol = eidx + E;

    const float step = TAB_RANGE / (float)TAB_T;
    const float inv_step = (float)TAB_T / TAB_RANGE;

    hipMemsetAsync(d_out, 0, (size_t)out_size * sizeof(float), stream);
    hipMemsetAsync(cursor, 0, (size_t)N * sizeof(int), stream);
    k_hist<<<(E + 255) / 256, 256, 0, stream>>>(erow, cursor, E);
    k_scan<<<1, 256, 0, stream>>>(cursor, rowstart, N);
    k_fill<<<(E + 255) / 256, 256, 0, stream>>>(erow, cursor, esort, E);
    k_init<<<(N * FDIM + 255) / 256, 256, 0, stream>>>(z, emb, s, v, N);

    const int tab_blocks = (TAB_T + 1 + 31) / 32;
    for (int l = 0; l < L; ++l) {
        k_table<<<tab_blocks, TH, 0, stream>>>(
            centers, gamma,
            fw1 + (size_t)l * RDIM * FDIM, fb1 + (size_t)l * FDIM,
            fw2 + (size_t)l * FDIM * 3 * FDIM, fb2 + (size_t)l * 3 * FDIM,
            tab, step);
        k_gather<<<N, 128, 0, stream>>>(
            pos, ecol, rowstart, esort, tab, s, v, m_s, m_v, inv_step, N);
        k_update<<<(N + TN_U - 1) / TN_U, TH, 0, stream>>>(
            uw1 + (size_t)l * 3 * FDIM * FDIM, ub1 + (size_t)l * FDIM,
            uw2 + (size_t)l * FDIM * 3 * FDIM, ub2 + (size_t)l * 3 * FDIM,
            s, v, m_s, m_v, N);
    }

    k_energy<<<(N + TN_E - 1) / TN_E, TH, 0, stream>>>(ew1, eb1, ew2, eb2, s, batch, energies, N, S);
    k_vec<<<(N + 3) / 4, 256, 0, stream>>>(v, dipole_w, nac_w, batch, dipoles, nac, N);
    k_heads<<<M, 128, 0, stream>>>(aw1, ab1, aw2, ab2, yw1, yb1, yw2, yb2,
                                   energies, nac, lam, phi_y, M, S);
}

// Round 4
// 927.420 us; speedup vs baseline: 18.5365x; 1.3848x over previous
//
#include <hip/hip_runtime.h>

#define FDIM 128
#define RDIM 20

#define TAB_T 2048              // table cells; TAB_T+1 rows
#define TAB_RANGE 12.0f

constexpr int TH = 256;

__device__ __forceinline__ float siluf(float x) { return x / (1.f + __expf(-x)); }

// ---------------------------------------------------------------- init: s = emb[z], v = 0
// v layout: [N][3][FDIM]
__global__ void k_init(const int* __restrict__ z, const float* __restrict__ emb,
                       float* __restrict__ s, float* __restrict__ v, int N) {
    int i = blockIdx.x * blockDim.x + threadIdx.x;
    if (i >= N * FDIM) return;
    int n = i >> 7, f = i & 127;
    s[i] = emb[z[n] * FDIM + f];
    size_t nf = (size_t)N * FDIM;
    v[i] = 0.f; v[i + nf] = 0.f; v[i + 2 * nf] = 0.f;   // covers [N][3][F] flat
}

// ---------------------------------------------------------------- CSR build
__global__ void k_hist(const int* __restrict__ erow, int* __restrict__ cursor, int E) {
    int e = blockIdx.x * blockDim.x + threadIdx.x;
    if (e < E) atomicAdd(&cursor[erow[e]], 1);
}

__global__ __launch_bounds__(256) void k_scan(int* __restrict__ cursor,
                                              int* __restrict__ rowstart, int N) {
    __shared__ int sh[256];
    __shared__ int carry;
    int tid = threadIdx.x;
    if (tid == 0) carry = 0;
    __syncthreads();
    for (int base = 0; base < N; base += 256) {
        int idx = base + tid;
        int x = (idx < N) ? cursor[idx] : 0;
        sh[tid] = x;
        __syncthreads();
        for (int off = 1; off < 256; off <<= 1) {
            int t = (tid >= off) ? sh[tid - off] : 0;
            __syncthreads();
            sh[tid] += t;
            __syncthreads();
        }
        int excl = carry + sh[tid] - x;
        if (idx < N) { rowstart[idx] = excl; cursor[idx] = excl; }
        __syncthreads();
        if (tid == 0) carry += sh[255];
        __syncthreads();
    }
    if (tid == 0) rowstart[N] = carry;
}

__global__ void k_fill(const int* __restrict__ erow, int* __restrict__ cursor,
                       int* __restrict__ esort, int E) {
    int e = blockIdx.x * blockDim.x + threadIdx.x;
    if (e < E) {
        int p = atomicAdd(&cursor[erow[e]], 1);
        esort[p] = e;
    }
}

// ---------------------------------------------------------------- filter-MLP table build
__global__ __launch_bounds__(TH) void k_table(
    const float* __restrict__ centers, const float* __restrict__ gamma,
    const float* __restrict__ fw1, const float* __restrict__ fb1,
    const float* __restrict__ fw2, const float* __restrict__ fb2,
    float* __restrict__ tab, float step)
{
    __shared__ float sh_rbf[32][RDIM];
    __shared__ float sh_ht[FDIM][33];
    __shared__ float sh_w[32][3 * FDIM + 4];

    const int p0  = blockIdx.x * 32;
    const int tid = threadIdx.x;

    for (int i = tid; i < 32 * RDIM; i += TH) {
        int p = i / RDIM, r = i - p * RDIM;
        float d = (float)(p0 + p) * step - centers[r];
        sh_rbf[p][r] = __expf(-gamma[r] * d * d);
    }
    __syncthreads();
    for (int i = tid; i < 32 * FDIM; i += TH) {
        int p = i >> 7, f = i & 127;
        float acc = fb1[f];
        #pragma unroll
        for (int r = 0; r < RDIM; ++r) acc += sh_rbf[p][r] * fw1[r * FDIM + f];
        sh_ht[f][p] = siluf(acc);
    }

    const int eq = tid & 7;
    const int fq = tid >> 3;
    const int f0 = fq * 4;

    float pg[3][4][4];
    #pragma unroll
    for (int g3 = 0; g3 < 3; ++g3)
        #pragma unroll
        for (int ee = 0; ee < 4; ++ee)
            #pragma unroll
            for (int i = 0; i < 4; ++i) pg[g3][ee][i] = fb2[g3 * FDIM + f0 + i];

    const int kkr = tid >> 3;
    const int t8  = tid & 7;
    for (int kc = 0; kc < 4; ++kc) {
        __syncthreads();
        #pragma unroll
        for (int j = 0; j < 12; ++j) {
            int g = (t8 * 12 + j) * 4;
            float4 w4 = *(const float4*)&fw2[(size_t)(kc * 32 + kkr) * (3 * FDIM) + g];
            *(float4*)&sh_w[kkr][g] = w4;
        }
        __syncthreads();
        #pragma unroll 4
        for (int kk = 0; kk < 32; ++kk) {
            float hv[4];
            #pragma unroll
            for (int ee = 0; ee < 4; ++ee) hv[ee] = sh_ht[kc * 32 + kk][4 * eq + ee];
            #pragma unroll
            for (int g3 = 0; g3 < 3; ++g3) {
                float4 w4 = *(const float4*)&sh_w[kk][g3 * FDIM + f0];
                #pragma unroll
                for (int ee = 0; ee < 4; ++ee) {
                    pg[g3][ee][0] += hv[ee] * w4.x;
                    pg[g3][ee][1] += hv[ee] * w4.y;
                    pg[g3][ee][2] += hv[ee] * w4.z;
                    pg[g3][ee][3] += hv[ee] * w4.w;
                }
            }
        }
    }

    #pragma unroll
    for (int ee = 0; ee < 4; ++ee) {
        int pt = p0 + 4 * eq + ee;
        if (pt <= TAB_T) {
            #pragma unroll
            for (int g3 = 0; g3 < 3; ++g3)
                *(float4*)&tab[(size_t)pt * 384 + g3 * FDIM + f0] =
                    make_float4(pg[g3][ee][0], pg[g3][ee][1], pg[g3][ee][2], pg[g3][ee][3]);
        }
    }
}

// ---------------------------------------------------------------- gather message kernel
// v layout [N][3][F]; m_v layout [N][3][F]
__global__ __launch_bounds__(128) void k_gather(
    const float* __restrict__ pos, const int* __restrict__ ecol,
    const int* __restrict__ rowstart, const int* __restrict__ esort,
    const float* __restrict__ tab, const float* __restrict__ s, const float* __restrict__ v,
    float* __restrict__ m_s, float* __restrict__ m_v, float inv_step, int N)
{
    __shared__ int   sh_col[32];
    __shared__ int   sh_t0[32];
    __shared__ float sh_w[32];
    __shared__ float sh_d0[32], sh_d1[32], sh_d2[32];

    const int n   = blockIdx.x;
    const int tid = threadIdx.x;
    const int lo  = rowstart[n], hi = rowstart[n + 1];

    float acc_s = 0.f, av0 = 0.f, av1 = 0.f, av2 = 0.f;
    const float px = pos[n * 3 + 0], py = pos[n * 3 + 1], pz = pos[n * 3 + 2];

    for (int base = lo; base < hi; base += 32) {
        const int ne = min(32, hi - base);
        __syncthreads();
        if (tid < 32) {
            if (tid < ne) {
                int e  = esort[base + tid];
                int cl = ecol[e];
                float dx = pos[cl*3+0] - px;
                float dy = pos[cl*3+1] - py;
                float dz = pos[cl*3+2] - pz;
                float dist = sqrtf(dx*dx + dy*dy + dz*dz + 1e-12f);
                float inv = 1.f / (dist + 1e-8f);
                sh_col[tid] = cl;
                sh_d0[tid] = dx*inv; sh_d1[tid] = dy*inv; sh_d2[tid] = dz*inv;
                float u = fminf(dist * inv_step, (float)TAB_T);
                int t0 = min((int)u, TAB_T - 1);
                sh_t0[tid] = t0;
                sh_w[tid]  = u - (float)t0;
            } else {
                sh_col[tid] = 0; sh_t0[tid] = 0; sh_w[tid] = 0.f;
                sh_d0[tid] = sh_d1[tid] = sh_d2[tid] = 0.f;
            }
        }
        __syncthreads();
        #pragma unroll 2
        for (int el = 0; el < ne; ++el) {
            int   cl = sh_col[el];
            int   t0 = sh_t0[el];
            float w  = sh_w[el];
            const float* ta = tab + (size_t)t0 * 384 + tid;
            float a_ss = ta[0],   b_ss = ta[384];
            float a_vv = ta[128], b_vv = ta[512];
            float a_sv = ta[256], b_sv = ta[640];
            float pss = a_ss + w * (b_ss - a_ss);
            float pvv = a_vv + w * (b_vv - a_vv);
            float psv = a_sv + w * (b_sv - a_sv);
            float sc = s[(size_t)cl * FDIM + tid];
            const float* vp = v + (size_t)cl * 3 * FDIM + tid;
            float svs = psv * sc;
            acc_s += pss * sc;
            av0 += pvv * vp[0]        + svs * sh_d0[el];
            av1 += pvv * vp[FDIM]     + svs * sh_d1[el];
            av2 += pvv * vp[2*FDIM]   + svs * sh_d2[el];
        }
    }

    m_s[(size_t)n * FDIM + tid] = acc_s;
    float* mv = m_v + (size_t)n * 3 * FDIM + tid;
    mv[0] = av0; mv[FDIM] = av1; mv[2*FDIM] = av2;
}

// ---------------------------------------------------------------- GEMM 1: u1 = silu(X @ uw1 + ub1)
// X = [s | m_s | ||m_v||] built on the fly. Tile 64 nodes x 128 cols, 256 thr, 4x8 micro.
__global__ __launch_bounds__(256) void k_mlp1(
    const float* __restrict__ s, const float* __restrict__ m_s, const float* __restrict__ m_v,
    const float* __restrict__ uw1, const float* __restrict__ ub1,
    float* __restrict__ u1, int N)
{
    __shared__ float shA[16][68];    // [kk][row]
    __shared__ float shB[16][132];   // [kk][col]

    const int tid = threadIdx.x;
    const int n0  = blockIdx.x * 64;
    const int tx  = tid & 15, ty = tid >> 4;
    const int cA  = tx * 4, cB = 64 + tx * 4;
    const int r0  = ty * 4;

    float acc[4][8];
    {
        float4 bA = *(const float4*)&ub1[cA];
        float4 bB = *(const float4*)&ub1[cB];
        #pragma unroll
        for (int i = 0; i < 4; ++i) {
            acc[i][0]=bA.x; acc[i][1]=bA.y; acc[i][2]=bA.z; acc[i][3]=bA.w;
            acc[i][4]=bB.x; acc[i][5]=bB.y; acc[i][6]=bB.z; acc[i][7]=bB.w;
        }
    }

    const int rs = tid >> 2;           // staging row 0..63
    const int k4 = (tid & 3) * 4;      // staging k offset

    for (int kc = 0; kc < 24; ++kc) {
        __syncthreads();
        // stage A (64 x 16)
        {
            int kg = kc * 16 + k4;
            int n  = n0 + rs;
            float4 a = make_float4(0.f, 0.f, 0.f, 0.f);
            if (n < N) {
                if (kg < 128) {
                    a = *(const float4*)&s[(size_t)n * FDIM + kg];
                } else if (kg < 256) {
                    a = *(const float4*)&m_s[(size_t)n * FDIM + kg - 128];
                } else {
                    int f = kg - 256;
                    const float* mvp = m_v + (size_t)n * 3 * FDIM + f;
                    float4 x = *(const float4*)&mvp[0];
                    float4 y = *(const float4*)&mvp[FDIM];
                    float4 zz = *(const float4*)&mvp[2*FDIM];
                    a.x = sqrtf(x.x*x.x + y.x*y.x + zz.x*zz.x + 1e-12f);
                    a.y = sqrtf(x.y*x.y + y.y*y.y + zz.y*zz.y + 1e-12f);
                    a.z = sqrtf(x.z*x.z + y.z*y.z + zz.z*zz.z + 1e-12f);
                    a.w = sqrtf(x.w*x.w + y.w*y.w + zz.w*zz.w + 1e-12f);
                }
            }
            shA[k4+0][rs] = a.x; shA[k4+1][rs] = a.y; shA[k4+2][rs] = a.z; shA[k4+3][rs] = a.w;
        }
        // stage B (16 x 128)
        #pragma unroll
        for (int i = 0; i < 2; ++i) {
            int idx = tid + i * 256;
            int kk = idx >> 5;
            int c4 = (idx & 31) * 4;
            *(float4*)&shB[kk][c4] = *(const float4*)&uw1[(size_t)(kc*16+kk) * FDIM + c4];
        }
        __syncthreads();
        #pragma unroll
        for (int kk = 0; kk < 16; ++kk) {
            float4 a4 = *(const float4*)&shA[kk][r0];
            float4 b0 = *(const float4*)&shB[kk][cA];
            float4 b1 = *(const float4*)&shB[kk][cB];
            float av[4] = {a4.x, a4.y, a4.z, a4.w};
            #pragma unroll
            for (int i = 0; i < 4; ++i) {
                acc[i][0] += av[i]*b0.x; acc[i][1] += av[i]*b0.y;
                acc[i][2] += av[i]*b0.z; acc[i][3] += av[i]*b0.w;
                acc[i][4] += av[i]*b1.x; acc[i][5] += av[i]*b1.y;
                acc[i][6] += av[i]*b1.z; acc[i][7] += av[i]*b1.w;
            }
        }
    }

    #pragma unroll
    for (int i = 0; i < 4; ++i) {
        int n = n0 + r0 + i;
        if (n < N) {
            float4 oA = make_float4(siluf(acc[i][0]), siluf(acc[i][1]), siluf(acc[i][2]), siluf(acc[i][3]));
            float4 oB = make_float4(siluf(acc[i][4]), siluf(acc[i][5]), siluf(acc[i][6]), siluf(acc[i][7]));
            *(float4*)&u1[(size_t)n * FDIM + cA] = oA;
            *(float4*)&u1[(size_t)n * FDIM + cB] = oB;
        }
    }
}

// ---------------------------------------------------------------- GEMM 2: upd = u1 @ uw2 + ub2, fused apply
// 3 gates sequential; alpha kept in registers; g0: s+=, g2: v = a*v + b*m_v.
__global__ __launch_bounds__(256) void k_mlp2(
    const float* __restrict__ u1, const float* __restrict__ uw2, const float* __restrict__ ub2,
    float* __restrict__ s, float* __restrict__ v, const float* __restrict__ m_v, int N)
{
    __shared__ float shA[16][68];
    __shared__ float shB[16][132];

    const int tid = threadIdx.x;
    const int n0  = blockIdx.x * 64;
    const int tx  = tid & 15, ty = tid >> 4;
    const int cA  = tx * 4, cB = 64 + tx * 4;
    const int r0  = ty * 4;
    const int rs  = tid >> 2;
    const int k4  = (tid & 3) * 4;

    float alpha[4][8];

    for (int g = 0; g < 3; ++g) {
        float acc[4][8];
        {
            float4 bA = *(const float4*)&ub2[g * FDIM + cA];
            float4 bB = *(const float4*)&ub2[g * FDIM + cB];
            #pragma unroll
            for (int i = 0; i < 4; ++i) {
                acc[i][0]=bA.x; acc[i][1]=bA.y; acc[i][2]=bA.z; acc[i][3]=bA.w;
                acc[i][4]=bB.x; acc[i][5]=bB.y; acc[i][6]=bB.z; acc[i][7]=bB.w;
            }
        }
        for (int kc = 0; kc < 8; ++kc) {
            __syncthreads();
            {
                int kg = kc * 16 + k4;
                int n  = n0 + rs;
                float4 a = make_float4(0.f, 0.f, 0.f, 0.f);
                if (n < N) a = *(const float4*)&u1[(size_t)n * FDIM + kg];
                shA[k4+0][rs] = a.x; shA[k4+1][rs] = a.y; shA[k4+2][rs] = a.z; shA[k4+3][rs] = a.w;
            }
            #pragma unroll
            for (int i = 0; i < 2; ++i) {
                int idx = tid + i * 256;
                int kk = idx >> 5;
                int c4 = (idx & 31) * 4;
                *(float4*)&shB[kk][c4] =
                    *(const float4*)&uw2[(size_t)(kc*16+kk) * (3*FDIM) + g * FDIM + c4];
            }
            __syncthreads();
            #pragma unroll
            for (int kk = 0; kk < 16; ++kk) {
                float4 a4 = *(const float4*)&shA[kk][r0];
                float4 b0 = *(const float4*)&shB[kk][cA];
                float4 b1 = *(const float4*)&shB[kk][cB];
                float av[4] = {a4.x, a4.y, a4.z, a4.w};
                #pragma unroll
                for (int i = 0; i < 4; ++i) {
                    acc[i][0] += av[i]*b0.x; acc[i][1] += av[i]*b0.y;
                    acc[i][2] += av[i]*b0.z; acc[i][3] += av[i]*b0.w;
                    acc[i][4] += av[i]*b1.x; acc[i][5] += av[i]*b1.y;
                    acc[i][6] += av[i]*b1.z; acc[i][7] += av[i]*b1.w;
                }
            }
        }

        if (g == 0) {
            #pragma unroll
            for (int i = 0; i < 4; ++i) {
                int n = n0 + r0 + i;
                if (n < N) {
                    float4 s0 = *(const float4*)&s[(size_t)n * FDIM + cA];
                    float4 s1 = *(const float4*)&s[(size_t)n * FDIM + cB];
                    s0.x += acc[i][0]; s0.y += acc[i][1]; s0.z += acc[i][2]; s0.w += acc[i][3];
                    s1.x += acc[i][4]; s1.y += acc[i][5]; s1.z += acc[i][6]; s1.w += acc[i][7];
                    *(float4*)&s[(size_t)n * FDIM + cA] = s0;
                    *(float4*)&s[(size_t)n * FDIM + cB] = s1;
                }
            }
        } else if (g == 1) {
            #pragma unroll
            for (int i = 0; i < 4; ++i)
                #pragma unroll
                for (int j = 0; j < 8; ++j) alpha[i][j] = acc[i][j];
        } else {
            #pragma unroll
            for (int i = 0; i < 4; ++i) {
                int n = n0 + r0 + i;
                if (n < N) {
                    #pragma unroll
                    for (int k = 0; k < 3; ++k) {
                        float* vp = v + ((size_t)n * 3 + k) * FDIM;
                        const float* mp = m_v + ((size_t)n * 3 + k) * FDIM;
                        float4 v0 = *(const float4*)&vp[cA];
                        float4 v1 = *(const float4*)&vp[cB];
                        float4 m0 = *(const float4*)&mp[cA];
                        float4 m1 = *(const float4*)&mp[cB];
                        v0.x = alpha[i][0]*v0.x + acc[i][0]*m0.x;
                        v0.y = alpha[i][1]*v0.y + acc[i][1]*m0.y;
                        v0.z = alpha[i][2]*v0.z + acc[i][2]*m0.z;
                        v0.w = alpha[i][3]*v0.w + acc[i][3]*m0.w;
                        v1.x = alpha[i][4]*v1.x + acc[i][4]*m1.x;
                        v1.y = alpha[i][5]*v1.y + acc[i][5]*m1.y;
                        v1.z = alpha[i][6]*v1.z + acc[i][6]*m1.z;
                        v1.w = alpha[i][7]*v1.w + acc[i][7]*m1.w;
                        *(float4*)&vp[cA] = v0;
                        *(float4*)&vp[cB] = v1;
                    }
                }
            }
        }
    }
}

// ---------------------------------------------------------------- energy head GEMM
// grid (nb, S). h = silu(s @ ew1[st] + eb1[st]); e_atom = h . ew2[st] + eb2[st]; atomic segsum.
__global__ __launch_bounds__(256) void k_energy2(
    const float* __restrict__ ew1, const float* __restrict__ eb1,
    const float* __restrict__ ew2, const float* __restrict__ eb2,
    const float* __restrict__ s, const int* __restrict__ batch,
    float* __restrict__ energies, int N, int S)
{
    __shared__ float shA[16][68];
    __shared__ float shB[16][132];

    const int tid = threadIdx.x;
    const int n0  = blockIdx.x * 64;
    const int st  = blockIdx.y;
    const int tx  = tid & 15, ty = tid >> 4;
    const int cA  = tx * 4, cB = 64 + tx * 4;
    const int r0  = ty * 4;
    const int rs  = tid >> 2;
    const int k4  = (tid & 3) * 4;

    float acc[4][8];
    {
        float4 bA = *(const float4*)&eb1[st * FDIM + cA];
        float4 bB = *(const float4*)&eb1[st * FDIM + cB];
        #pragma unroll
        for (int i = 0; i < 4; ++i) {
            acc[i][0]=bA.x; acc[i][1]=bA.y; acc[i][2]=bA.z; acc[i][3]=bA.w;
            acc[i][4]=bB.x; acc[i][5]=bB.y; acc[i][6]=bB.z; acc[i][7]=bB.w;
        }
    }

    for (int kc = 0; kc < 8; ++kc) {
        __syncthreads();
        {
            int kg = kc * 16 + k4;
            int n  = n0 + rs;
            float4 a = make_float4(0.f, 0.f, 0.f, 0.f);
            if (n < N) a = *(const float4*)&s[(size_t)n * FDIM + kg];
            shA[k4+0][rs] = a.x; shA[k4+1][rs] = a.y; shA[k4+2][rs] = a.z; shA[k4+3][rs] = a.w;
        }
        #pragma unroll
        for (int i = 0; i < 2; ++i) {
            int idx = tid + i * 256;
            int kk = idx >> 5;
            int c4 = (idx & 31) * 4;
            *(float4*)&shB[kk][c4] =
                *(const float4*)&ew1[(size_t)st * FDIM * FDIM + (size_t)(kc*16+kk) * FDIM + c4];
        }
        __syncthreads();
        #pragma unroll
        for (int kk = 0; kk < 16; ++kk) {
            float4 a4 = *(const float4*)&shA[kk][r0];
            float4 b0 = *(const float4*)&shB[kk][cA];
            float4 b1 = *(const float4*)&shB[kk][cB];
            float av[4] = {a4.x, a4.y, a4.z, a4.w};
            #pragma unroll
            for (int i = 0; i < 4; ++i) {
                acc[i][0] += av[i]*b0.x; acc[i][1] += av[i]*b0.y;
                acc[i][2] += av[i]*b0.z; acc[i][3] += av[i]*b0.w;
                acc[i][4] += av[i]*b1.x; acc[i][5] += av[i]*b1.y;
                acc[i][6] += av[i]*b1.z; acc[i][7] += av[i]*b1.w;
            }
        }
    }

    float4 wA = *(const float4*)&ew2[st * FDIM + cA];
    float4 wB = *(const float4*)&ew2[st * FDIM + cB];
    float p[4];
    #pragma unroll
    for (int i = 0; i < 4; ++i) {
        p[i]  = siluf(acc[i][0])*wA.x + siluf(acc[i][1])*wA.y
              + siluf(acc[i][2])*wA.z + siluf(acc[i][3])*wA.w;
        p[i] += siluf(acc[i][4])*wB.x + siluf(acc[i][5])*wB.y
              + siluf(acc[i][6])*wB.z + siluf(acc[i][7])*wB.w;
    }
    #pragma unroll
    for (int m = 1; m <= 8; m <<= 1) {
        #pragma unroll
        for (int i = 0; i < 4; ++i) p[i] += __shfl_xor(p[i], m, 64);
    }
    if (tx == 0) {
        float b2 = eb2[st];
        #pragma unroll
        for (int i = 0; i < 4; ++i) {
            int n = n0 + r0 + i;
            if (n < N) atomicAdd(&energies[batch[n] * S + st], p[i] + b2);
        }
    }
}

// ---------------------------------------------------------------- dipole / nac heads (v = [N][3][F])
__global__ void k_vec(const float* __restrict__ v, const float* __restrict__ dipole_w,
                      const float* __restrict__ nac_w, const int* __restrict__ batch,
                      float* __restrict__ dipoles, float* __restrict__ nac, int N)
{
    int n = blockIdx.x * 4 + (threadIdx.x >> 6);
    int lane = threadIdx.x & 63;
    if (n >= N) return;
    float pd[3] = {0.f, 0.f, 0.f};
    float pn[3][3] = {{0.f}};
    const float* vb = v + (size_t)n * 3 * FDIM;
    for (int f = lane; f < FDIM; f += 64) {
        float v0 = vb[f], v1 = vb[FDIM + f], v2 = vb[2*FDIM + f];
        float wd = dipole_w[f];
        pd[0] += wd * v0; pd[1] += wd * v1; pd[2] += wd * v2;
        #pragma unroll
        for (int p = 0; p < 3; ++p) {
            float wn = nac_w[p * FDIM + f];
            pn[p][0] += wn * v0; pn[p][1] += wn * v1; pn[p][2] += wn * v2;
        }
    }
    #pragma unroll
    for (int d = 32; d > 0; d >>= 1) {
        #pragma unroll
        for (int k = 0; k < 3; ++k) pd[k] += __shfl_down(pd[k], d, 64);
        #pragma unroll
        for (int p = 0; p < 3; ++p)
            #pragma unroll
            for (int k = 0; k < 3; ++k) pn[p][k] += __shfl_down(pn[p][k], d, 64);
    }
    if (lane == 0) {
        int m = batch[n];
        #pragma unroll
        for (int k = 0; k < 3; ++k) atomicAdd(&dipoles[m * 3 + k], pd[k]);
        #pragma unroll
        for (int p = 0; p < 3; ++p)
            #pragma unroll
            for (int k = 0; k < 3; ++k) atomicAdd(&nac[(m * 3 + p) * 3 + k], pn[p][k]);
    }
}

// ---------------------------------------------------------------- per-molecule heads
__global__ __launch_bounds__(128) void k_heads(
    const float* __restrict__ aw1, const float* __restrict__ ab1,
    const float* __restrict__ aw2, const float* __restrict__ ab2,
    const float* __restrict__ yw1, const float* __restrict__ yb1,
    const float* __restrict__ yw2, const float* __restrict__ yb2,
    const float* __restrict__ energies, const float* __restrict__ nac,
    float* __restrict__ lam, float* __restrict__ phi_y, int M, int S)
{
    __shared__ float sh_in[8];
    __shared__ float sh_red[2];
    int m = blockIdx.x;
    if (m >= M) return;
    int tid = threadIdx.x;
    if (tid == 0) {
        float e0 = energies[m * S];
        for (int j = 0; j < 3; ++j) sh_in[j] = energies[m * S + 1 + j] - e0;
        for (int p = 0; p < 3; ++p) {
            float a = nac[(m * 3 + p) * 3 + 0];
            float b = nac[(m * 3 + p) * 3 + 1];
            float c = nac[(m * 3 + p) * 3 + 2];
            sh_in[3 + p] = sqrtf(a*a + b*b + c*c + 1e-12f);
        }
    }
    __syncthreads();
    float pa = 0.f;
    if (tid < 64) {
        float h = ab1[tid];
        #pragma unroll
        for (int j = 0; j < 3; ++j) h += sh_in[j] * aw1[j * 64 + tid];
        pa = siluf(h) * aw2[tid];
    }
    float h2 = yb1[tid];
    #pragma unroll
    for (int j = 0; j < 6; ++j) h2 += sh_in[j] * yw1[j * 128 + tid];
    float py = siluf(h2) * yw2[tid];
    #pragma unroll
    for (int d = 32; d > 0; d >>= 1) {
        pa += __shfl_down(pa, d, 64);
        py += __shfl_down(py, d, 64);
    }
    int wid = tid >> 6, lane = tid & 63;
    if (lane == 0) sh_red[wid] = py;
    __syncthreads();
    if (tid == 0) {
        lam[m] = pa + ab2[0];
        float yt = sh_red[0] + sh_red[1] + yb2[0];
        phi_y[m] = 1.f / (1.f + __expf(-yt));
    }
}

// ---------------------------------------------------------------- launch
extern "C" void kernel_launch(void* const* d_in, const int* in_sizes, int n_in,
                              void* d_out, int out_size, void* d_ws, size_t ws_size,
                              hipStream_t stream)
{
    const int*   z        = (const int*)  d_in[0];
    const float* pos      = (const float*)d_in[1];
    const int*   eidx     = (const int*)  d_in[2];
    const int*   batch    = (const int*)  d_in[3];
    const float* emb      = (const float*)d_in[5];
    const float* centers  = (const float*)d_in[6];
    const float* gamma    = (const float*)d_in[7];
    const float* fw1      = (const float*)d_in[8];
    const float* fb1      = (const float*)d_in[9];
    const float* fw2      = (const float*)d_in[10];
    const float* fb2      = (const float*)d_in[11];
    const float* uw1      = (const float*)d_in[12];
    const float* ub1      = (const float*)d_in[13];
    const float* uw2      = (const float*)d_in[14];
    const float* ub2      = (const float*)d_in[15];
    const float* ew1      = (const float*)d_in[16];
    const float* eb1      = (const float*)d_in[17];
    const float* ew2      = (const float*)d_in[18];
    const float* eb2      = (const float*)d_in[19];
    const float* dipole_w = (const float*)d_in[20];
    const float* nac_w    = (const float*)d_in[21];
    const float* aw1      = (const float*)d_in[22];
    const float* ab1      = (const float*)d_in[23];
    const float* aw2      = (const float*)d_in[24];
    const float* ab2      = (const float*)d_in[25];
    const float* yw1      = (const float*)d_in[26];
    const float* yb1      = (const float*)d_in[27];
    const float* yw2      = (const float*)d_in[28];
    const float* yb2      = (const float*)d_in[29];

    const int N = in_sizes[0];
    const int E = in_sizes[2] / 2;
    const int S = in_sizes[19];
    const int P = in_sizes[21] / FDIM;
    const int L = in_sizes[9] / FDIM;
    const int M = out_size / (S + 3 + P * 3 + 2);

    float* s   = (float*)d_ws;                       // N x F
    float* v   = s   + (size_t)N * FDIM;             // N x 3 x F
    float* m_s = v   + (size_t)N * FDIM * 3;         // N x F   (aliased by u1)
    float* m_v = m_s + (size_t)N * FDIM;             // N x 3 x F
    float* tab = m_v + (size_t)N * FDIM * 3;         // (TAB_T+1) x 384
    int*   rowstart = (int*)(tab + (size_t)(TAB_T + 1) * 384);
    int*   cursor   = rowstart + (N + 1);
    int*   esort    = cursor + N;
    float* u1 = m_s;   // safe alias: per-block row panels, m_s fully consumed before u1 written

    float* out      = (float*)d_out;
    float* energies = out;
    float* dipoles  = energies + (size_t)M * S;
    float* nac      = dipoles  + (size_t)M * 3;
    float* lam      = nac      + (size_t)M * P * 3;
    float* phi_y    = lam      + M;

    const int* erow = eidx;
    const int* ecol = eidx + E;

    const float step = TAB_RANGE / (float)TAB_T;
    const float inv_step = (float)TAB_T / TAB_RANGE;
    const int NB = (N + 63) / 64;

    hipMemsetAsync(d_out, 0, (size_t)out_size * sizeof(float), stream);
    hipMemsetAsync(cursor, 0, (size_t)N * sizeof(int), stream);
    k_hist<<<(E + 255) / 256, 256, 0, stream>>>(erow, cursor, E);
    k_scan<<<1, 256, 0, stream>>>(cursor, rowstart, N);
    k_fill<<<(E + 255) / 256, 256, 0, stream>>>(erow, cursor, esort, E);
    k_init<<<(N * FDIM + 255) / 256, 256, 0, stream>>>(z, emb, s, v, N);

    const int tab_blocks = (TAB_T + 1 + 31) / 32;
    for (int l = 0; l < L; ++l) {
        k_table<<<tab_blocks, TH, 0, stream>>>(
            centers, gamma,
            fw1 + (size_t)l * RDIM * FDIM, fb1 + (size_t)l * FDIM,
            fw2 + (size_t)l * FDIM * 3 * FDIM, fb2 + (size_t)l * 3 * FDIM,
            tab, step);
        k_gather<<<N, 128, 0, stream>>>(
            pos, ecol, rowstart, esort, tab, s, v, m_s, m_v, inv_step, N);
        k_mlp1<<<NB, 256, 0, stream>>>(
            s, m_s, m_v, uw1 + (size_t)l * 3 * FDIM * FDIM, ub1 + (size_t)l * FDIM, u1, N);
        k_mlp2<<<NB, 256, 0, stream>>>(
            u1, uw2 + (size_t)l * FDIM * 3 * FDIM, ub2 + (size_t)l * 3 * FDIM,
            s, v, m_v, N);
    }

    k_energy2<<<dim3(NB, S), 256, 0, stream>>>(ew1, eb1, ew2, eb2, s, batch, energies, N, S);
    k_vec<<<(N + 3) / 4, 256, 0, stream>>>(v, dipole_w, nac_w, batch, dipoles, nac, N);
    k_heads<<<M, 128, 0, stream>>>(aw1, ab1, aw2, ab2, yw1, yb1, yw2, yb2,
                                   energies, nac, lam, phi_y, M, S);
}

// Round 5
// 888.844 us; speedup vs baseline: 19.3409x; 1.0434x over previous
//
#include <hip/hip_runtime.h>
#include <hip/hip_fp16.h>

#define FDIM 128
#define RDIM 20

#define TAB_T 2048              // table cells; TAB_T+1 rows
#define TAB_RANGE 12.0f

constexpr int TH = 256;

__device__ __forceinline__ float siluf(float x) { return x / (1.f + __expf(-x)); }

__device__ __forceinline__ void store_h4(__half* p, float a, float b, float c, float d) {
    __half h[4] = {__float2half(a), __float2half(b), __float2half(c), __float2half(d)};
    *(uint2*)p = *(uint2*)h;
}

// ---------------------------------------------------------------- init: s = emb[z], v = 0
// v layout: [N][3][FDIM]
__global__ void k_init(const int* __restrict__ z, const float* __restrict__ emb,
                       float* __restrict__ s, float* __restrict__ v,
                       __half* __restrict__ s_h, __half* __restrict__ v_h, int N) {
    int i = blockIdx.x * blockDim.x + threadIdx.x;
    if (i >= N * FDIM) return;
    int n = i >> 7, f = i & 127;
    float val = emb[z[n] * FDIM + f];
    s[i] = val;
    s_h[i] = __float2half(val);
    size_t nf = (size_t)N * FDIM;
    v[i] = 0.f; v[i + nf] = 0.f; v[i + 2 * nf] = 0.f;
    __half hz = __float2half(0.f);
    v_h[i] = hz; v_h[i + nf] = hz; v_h[i + 2 * nf] = hz;
}

// ---------------------------------------------------------------- CSR build
__global__ void k_hist(const int* __restrict__ erow, int* __restrict__ cursor, int E) {
    int e = blockIdx.x * blockDim.x + threadIdx.x;
    if (e < E) atomicAdd(&cursor[erow[e]], 1);
}

__global__ __launch_bounds__(256) void k_scan(int* __restrict__ cursor,
                                              int* __restrict__ rowstart, int N) {
    __shared__ int sh[256];
    __shared__ int carry;
    int tid = threadIdx.x;
    if (tid == 0) carry = 0;
    __syncthreads();
    for (int base = 0; base < N; base += 256) {
        int idx = base + tid;
        int x = (idx < N) ? cursor[idx] : 0;
        sh[tid] = x;
        __syncthreads();
        for (int off = 1; off < 256; off <<= 1) {
            int t = (tid >= off) ? sh[tid - off] : 0;
            __syncthreads();
            sh[tid] += t;
            __syncthreads();
        }
        int excl = carry + sh[tid] - x;
        if (idx < N) { rowstart[idx] = excl; cursor[idx] = excl; }
        __syncthreads();
        if (tid == 0) carry += sh[255];
        __syncthreads();
    }
    if (tid == 0) rowstart[N] = carry;
}

__global__ void k_fill(const int* __restrict__ erow, int* __restrict__ cursor,
                       int* __restrict__ esort, int E) {
    int e = blockIdx.x * blockDim.x + threadIdx.x;
    if (e < E) {
        int p = atomicAdd(&cursor[erow[e]], 1);
        esort[p] = e;
    }
}

// ---------------------------------------------------------------- filter-MLP table build (fp16 out)
__global__ __launch_bounds__(TH) void k_table(
    const float* __restrict__ centers, const float* __restrict__ gamma,
    const float* __restrict__ fw1, const float* __restrict__ fb1,
    const float* __restrict__ fw2, const float* __restrict__ fb2,
    __half* __restrict__ tab, float step)
{
    __shared__ float sh_rbf[32][RDIM];
    __shared__ float sh_ht[FDIM][33];
    __shared__ float sh_w[32][3 * FDIM + 4];

    const int p0  = blockIdx.x * 32;
    const int tid = threadIdx.x;

    for (int i = tid; i < 32 * RDIM; i += TH) {
        int p = i / RDIM, r = i - p * RDIM;
        float d = (float)(p0 + p) * step - centers[r];
        sh_rbf[p][r] = __expf(-gamma[r] * d * d);
    }
    __syncthreads();
    for (int i = tid; i < 32 * FDIM; i += TH) {
        int p = i >> 7, f = i & 127;
        float acc = fb1[f];
        #pragma unroll
        for (int r = 0; r < RDIM; ++r) acc += sh_rbf[p][r] * fw1[r * FDIM + f];
        sh_ht[f][p] = siluf(acc);
    }

    const int eq = tid & 7;
    const int fq = tid >> 3;
    const int f0 = fq * 4;

    float pg[3][4][4];
    #pragma unroll
    for (int g3 = 0; g3 < 3; ++g3)
        #pragma unroll
        for (int ee = 0; ee < 4; ++ee)
            #pragma unroll
            for (int i = 0; i < 4; ++i) pg[g3][ee][i] = fb2[g3 * FDIM + f0 + i];

    const int kkr = tid >> 3;
    const int t8  = tid & 7;
    for (int kc = 0; kc < 4; ++kc) {
        __syncthreads();
        #pragma unroll
        for (int j = 0; j < 12; ++j) {
            int g = (t8 * 12 + j) * 4;
            float4 w4 = *(const float4*)&fw2[(size_t)(kc * 32 + kkr) * (3 * FDIM) + g];
            *(float4*)&sh_w[kkr][g] = w4;
        }
        __syncthreads();
        #pragma unroll 4
        for (int kk = 0; kk < 32; ++kk) {
            float hv[4];
            #pragma unroll
            for (int ee = 0; ee < 4; ++ee) hv[ee] = sh_ht[kc * 32 + kk][4 * eq + ee];
            #pragma unroll
            for (int g3 = 0; g3 < 3; ++g3) {
                float4 w4 = *(const float4*)&sh_w[kk][g3 * FDIM + f0];
                #pragma unroll
                for (int ee = 0; ee < 4; ++ee) {
                    pg[g3][ee][0] += hv[ee] * w4.x;
                    pg[g3][ee][1] += hv[ee] * w4.y;
                    pg[g3][ee][2] += hv[ee] * w4.z;
                    pg[g3][ee][3] += hv[ee] * w4.w;
                }
            }
        }
    }

    #pragma unroll
    for (int ee = 0; ee < 4; ++ee) {
        int pt = p0 + 4 * eq + ee;
        if (pt <= TAB_T) {
            #pragma unroll
            for (int g3 = 0; g3 < 3; ++g3)
                store_h4(&tab[(size_t)pt * 384 + g3 * FDIM + f0],
                         pg[g3][ee][0], pg[g3][ee][1], pg[g3][ee][2], pg[g3][ee][3]);
        }
    }
}

// ---------------------------------------------------------------- gather message kernel (fp16 inputs)
__global__ __launch_bounds__(128) void k_gather(
    const float* __restrict__ pos, const int* __restrict__ ecol,
    const int* __restrict__ rowstart, const int* __restrict__ esort,
    const __half* __restrict__ tab, const __half* __restrict__ s_h,
    const __half* __restrict__ v_h,
    float* __restrict__ m_s, float* __restrict__ m_v, float inv_step, int withv, int N)
{
    __shared__ int   sh_col[32];
    __shared__ int   sh_t0[32];
    __shared__ float sh_w[32];
    __shared__ float sh_d0[32], sh_d1[32], sh_d2[32];

    const int n   = blockIdx.x;
    const int tid = threadIdx.x;
    const int lo  = rowstart[n], hi = rowstart[n + 1];

    float acc_s = 0.f, av0 = 0.f, av1 = 0.f, av2 = 0.f;
    const float px = pos[n * 3 + 0], py = pos[n * 3 + 1], pz = pos[n * 3 + 2];

    for (int base = lo; base < hi; base += 32) {
        const int ne = min(32, hi - base);
        __syncthreads();
        if (tid < 32) {
            if (tid < ne) {
                int e  = esort[base + tid];
                int cl = ecol[e];
                float dx = pos[cl*3+0] - px;
                float dy = pos[cl*3+1] - py;
                float dz = pos[cl*3+2] - pz;
                float dist = sqrtf(dx*dx + dy*dy + dz*dz + 1e-12f);
                float inv = 1.f / (dist + 1e-8f);
                sh_col[tid] = cl;
                sh_d0[tid] = dx*inv; sh_d1[tid] = dy*inv; sh_d2[tid] = dz*inv;
                float u = fminf(dist * inv_step, (float)TAB_T);
                int t0 = min((int)u, TAB_T - 1);
                sh_t0[tid] = t0;
                sh_w[tid]  = u - (float)t0;
            } else {
                sh_col[tid] = 0; sh_t0[tid] = 0; sh_w[tid] = 0.f;
                sh_d0[tid] = sh_d1[tid] = sh_d2[tid] = 0.f;
            }
        }
        __syncthreads();
        if (withv) {
            #pragma unroll 2
            for (int el = 0; el < ne; ++el) {
                int   cl = sh_col[el];
                int   t0 = sh_t0[el];
                float w  = sh_w[el];
                const __half* ta = tab + (size_t)t0 * 384 + tid;
                float a_ss = __half2float(ta[0]),   b_ss = __half2float(ta[384]);
                float a_vv = __half2float(ta[128]), b_vv = __half2float(ta[512]);
                float a_sv = __half2float(ta[256]), b_sv = __half2float(ta[640]);
                float pss = a_ss + w * (b_ss - a_ss);
                float pvv = a_vv + w * (b_vv - a_vv);
                float psv = a_sv + w * (b_sv - a_sv);
                float sc = __half2float(s_h[(size_t)cl * FDIM + tid]);
                const __half* vp = v_h + (size_t)cl * 3 * FDIM + tid;
                float svs = psv * sc;
                acc_s += pss * sc;
                av0 += pvv * __half2float(vp[0])        + svs * sh_d0[el];
                av1 += pvv * __half2float(vp[FDIM])     + svs * sh_d1[el];
                av2 += pvv * __half2float(vp[2*FDIM])   + svs * sh_d2[el];
            }
        } else {
            #pragma unroll 2
            for (int el = 0; el < ne; ++el) {
                int   cl = sh_col[el];
                int   t0 = sh_t0[el];
                float w  = sh_w[el];
                const __half* ta = tab + (size_t)t0 * 384 + tid;
                float a_ss = __half2float(ta[0]),   b_ss = __half2float(ta[384]);
                float a_sv = __half2float(ta[256]), b_sv = __half2float(ta[640]);
                float pss = a_ss + w * (b_ss - a_ss);
                float psv = a_sv + w * (b_sv - a_sv);
                float sc = __half2float(s_h[(size_t)cl * FDIM + tid]);
                float svs = psv * sc;
                acc_s += pss * sc;
                av0 += svs * sh_d0[el];
                av1 += svs * sh_d1[el];
                av2 += svs * sh_d2[el];
            }
        }
    }

    m_s[(size_t)n * FDIM + tid] = acc_s;
    float* mv = m_v + (size_t)n * 3 * FDIM + tid;
    mv[0] = av0; mv[FDIM] = av1; mv[2*FDIM] = av2;
}

// ---------------------------------------------------------------- fused node-update
// GEMM1 (64x128, K=384): u1 = silu(X @ uw1 + ub1), X = [s | m_s | ||m_v||]; u1 -> LDS.
// GEMM2 (3 gates, K=128): delta_s/alpha/beta fused-apply; writes s, v and fp16 mirrors.
__global__ __launch_bounds__(128) void k_update_fused(
    float* __restrict__ s, const float* __restrict__ m_s, const float* __restrict__ m_v,
    const float* __restrict__ uw1, const float* __restrict__ ub1,
    const float* __restrict__ uw2, const float* __restrict__ ub2,
    float* __restrict__ v, __half* __restrict__ s_h, __half* __restrict__ v_h, int N)
{
    __shared__ float shA[16][68];
    __shared__ float shB[16][132];
    __shared__ float shU[64][133];

    const int tid = threadIdx.x;
    const int n0  = blockIdx.x * 64;
    const int tx  = tid & 15, ty = tid >> 4;   // 16 x 8
    const int cA  = tx * 4, cB = 64 + tx * 4;
    const int r0  = ty * 8;

    // -------- GEMM1
    float acc[8][8];
    {
        float4 bA = *(const float4*)&ub1[cA];
        float4 bB = *(const float4*)&ub1[cB];
        #pragma unroll
        for (int i = 0; i < 8; ++i) {
            acc[i][0]=bA.x; acc[i][1]=bA.y; acc[i][2]=bA.z; acc[i][3]=bA.w;
            acc[i][4]=bB.x; acc[i][5]=bB.y; acc[i][6]=bB.z; acc[i][7]=bB.w;
        }
    }

    for (int kc = 0; kc < 24; ++kc) {
        __syncthreads();
        // stage A (64 rows x 16 k): 2 float4 per thread
        #pragma unroll
        for (int it = 0; it < 2; ++it) {
            int idx = it * 128 + tid;       // 0..255
            int row = idx >> 2;
            int k4  = (idx & 3) * 4;
            int kg  = kc * 16 + k4;
            int n   = n0 + row;
            float4 a = make_float4(0.f, 0.f, 0.f, 0.f);
            if (n < N) {
                if (kg < 128) {
                    a = *(const float4*)&s[(size_t)n * FDIM + kg];
                } else if (kg < 256) {
                    a = *(const float4*)&m_s[(size_t)n * FDIM + kg - 128];
                } else {
                    int f = kg - 256;
                    const float* mvp = m_v + (size_t)n * 3 * FDIM + f;
                    float4 x = *(const float4*)&mvp[0];
                    float4 y = *(const float4*)&mvp[FDIM];
                    float4 zz = *(const float4*)&mvp[2*FDIM];
                    a.x = sqrtf(x.x*x.x + y.x*y.x + zz.x*zz.x + 1e-12f);
                    a.y = sqrtf(x.y*x.y + y.y*y.y + zz.y*zz.y + 1e-12f);
                    a.z = sqrtf(x.z*x.z + y.z*y.z + zz.z*zz.z + 1e-12f);
                    a.w = sqrtf(x.w*x.w + y.w*y.w + zz.w*zz.w + 1e-12f);
                }
            }
            shA[k4+0][row] = a.x; shA[k4+1][row] = a.y;
            shA[k4+2][row] = a.z; shA[k4+3][row] = a.w;
        }
        // stage B (16 x 128): 4 float4 per thread
        #pragma unroll
        for (int it = 0; it < 4; ++it) {
            int idx = it * 128 + tid;       // 0..511
            int kk = idx >> 5;
            int c4 = (idx & 31) * 4;
            *(float4*)&shB[kk][c4] = *(const float4*)&uw1[(size_t)(kc*16+kk) * FDIM + c4];
        }
        __syncthreads();
        #pragma unroll
        for (int kk = 0; kk < 16; ++kk) {
            float4 a0 = *(const float4*)&shA[kk][r0];
            float4 a1 = *(const float4*)&shA[kk][r0+4];
            float4 b0 = *(const float4*)&shB[kk][cA];
            float4 b1 = *(const float4*)&shB[kk][cB];
            float av[8] = {a0.x,a0.y,a0.z,a0.w,a1.x,a1.y,a1.z,a1.w};
            #pragma unroll
            for (int i = 0; i < 8; ++i) {
                acc[i][0] += av[i]*b0.x; acc[i][1] += av[i]*b0.y;
                acc[i][2] += av[i]*b0.z; acc[i][3] += av[i]*b0.w;
                acc[i][4] += av[i]*b1.x; acc[i][5] += av[i]*b1.y;
                acc[i][6] += av[i]*b1.z; acc[i][7] += av[i]*b1.w;
            }
        }
    }

    // u1 -> LDS (silu applied); scalar stores, layout [row][col] stride 133 (conflict-free)
    #pragma unroll
    for (int i = 0; i < 8; ++i) {
        int r = r0 + i;
        shU[r][cA+0] = siluf(acc[i][0]); shU[r][cA+1] = siluf(acc[i][1]);
        shU[r][cA+2] = siluf(acc[i][2]); shU[r][cA+3] = siluf(acc[i][3]);
        shU[r][cB+0] = siluf(acc[i][4]); shU[r][cB+1] = siluf(acc[i][5]);
        shU[r][cB+2] = siluf(acc[i][6]); shU[r][cB+3] = siluf(acc[i][7]);
    }
    __syncthreads();

    // -------- GEMM2: 3 gates over K=128
    float alpha[8][8];
    for (int g = 0; g < 3; ++g) {
        float acc2[8][8];
        {
            float4 bA = *(const float4*)&ub2[g * FDIM + cA];
            float4 bB = *(const float4*)&ub2[g * FDIM + cB];
            #pragma unroll
            for (int i = 0; i < 8; ++i) {
                acc2[i][0]=bA.x; acc2[i][1]=bA.y; acc2[i][2]=bA.z; acc2[i][3]=bA.w;
                acc2[i][4]=bB.x; acc2[i][5]=bB.y; acc2[i][6]=bB.z; acc2[i][7]=bB.w;
            }
        }
        for (int kc = 0; kc < 8; ++kc) {
            __syncthreads();
            #pragma unroll
            for (int it = 0; it < 4; ++it) {
                int idx = it * 128 + tid;
                int kk = idx >> 5;
                int c4 = (idx & 31) * 4;
                *(float4*)&shB[kk][c4] =
                    *(const float4*)&uw2[(size_t)(kc*16+kk) * (3*FDIM) + g * FDIM + c4];
            }
            __syncthreads();
            #pragma unroll
            for (int kk = 0; kk < 16; ++kk) {
                int col = kc * 16 + kk;
                float4 b0 = *(const float4*)&shB[kk][cA];
                float4 b1 = *(const float4*)&shB[kk][cB];
                #pragma unroll
                for (int i = 0; i < 8; ++i) {
                    float uv = shU[r0+i][col];
                    acc2[i][0] += uv*b0.x; acc2[i][1] += uv*b0.y;
                    acc2[i][2] += uv*b0.z; acc2[i][3] += uv*b0.w;
                    acc2[i][4] += uv*b1.x; acc2[i][5] += uv*b1.y;
                    acc2[i][6] += uv*b1.z; acc2[i][7] += uv*b1.w;
                }
            }
        }

        if (g == 0) {
            #pragma unroll
            for (int i = 0; i < 8; ++i) {
                int n = n0 + r0 + i;
                if (n < N) {
                    float4 s0 = *(const float4*)&s[(size_t)n * FDIM + cA];
                    float4 s1 = *(const float4*)&s[(size_t)n * FDIM + cB];
                    s0.x += acc2[i][0]; s0.y += acc2[i][1]; s0.z += acc2[i][2]; s0.w += acc2[i][3];
                    s1.x += acc2[i][4]; s1.y += acc2[i][5]; s1.z += acc2[i][6]; s1.w += acc2[i][7];
                    *(float4*)&s[(size_t)n * FDIM + cA] = s0;
                    *(float4*)&s[(size_t)n * FDIM + cB] = s1;
                    store_h4(&s_h[(size_t)n * FDIM + cA], s0.x, s0.y, s0.z, s0.w);
                    store_h4(&s_h[(size_t)n * FDIM + cB], s1.x, s1.y, s1.z, s1.w);
                }
            }
        } else if (g == 1) {
            #pragma unroll
            for (int i = 0; i < 8; ++i)
                #pragma unroll
                for (int j = 0; j < 8; ++j) alpha[i][j] = acc2[i][j];
        } else {
            #pragma unroll
            for (int i = 0; i < 8; ++i) {
                int n = n0 + r0 + i;
                if (n < N) {
                    #pragma unroll
                    for (int k = 0; k < 3; ++k) {
                        float* vp = v + ((size_t)n * 3 + k) * FDIM;
                        const float* mp = m_v + ((size_t)n * 3 + k) * FDIM;
                        __half* vhp = v_h + ((size_t)n * 3 + k) * FDIM;
                        float4 v0 = *(const float4*)&vp[cA];
                        float4 v1 = *(const float4*)&vp[cB];
                        float4 m0 = *(const float4*)&mp[cA];
                        float4 m1 = *(const float4*)&mp[cB];
                        v0.x = alpha[i][0]*v0.x + acc2[i][0]*m0.x;
                        v0.y = alpha[i][1]*v0.y + acc2[i][1]*m0.y;
                        v0.z = alpha[i][2]*v0.z + acc2[i][2]*m0.z;
                        v0.w = alpha[i][3]*v0.w + acc2[i][3]*m0.w;
                        v1.x = alpha[i][4]*v1.x + acc2[i][4]*m1.x;
                        v1.y = alpha[i][5]*v1.y + acc2[i][5]*m1.y;
                        v1.z = alpha[i][6]*v1.z + acc2[i][6]*m1.z;
                        v1.w = alpha[i][7]*v1.w + acc2[i][7]*m1.w;
                        *(float4*)&vp[cA] = v0;
                        *(float4*)&vp[cB] = v1;
                        store_h4(&vhp[cA], v0.x, v0.y, v0.z, v0.w);
                        store_h4(&vhp[cB], v1.x, v1.y, v1.z, v1.w);
                    }
                }
            }
        }
    }
}

// ---------------------------------------------------------------- energy head GEMM
__global__ __launch_bounds__(256) void k_energy2(
    const float* __restrict__ ew1, const float* __restrict__ eb1,
    const float* __restrict__ ew2, const float* __restrict__ eb2,
    const float* __restrict__ s, const int* __restrict__ batch,
    float* __restrict__ energies, int N, int S)
{
    __shared__ float shA[16][68];
    __shared__ float shB[16][132];

    const int tid = threadIdx.x;
    const int n0  = blockIdx.x * 64;
    const int st  = blockIdx.y;
    const int tx  = tid & 15, ty = tid >> 4;
    const int cA  = tx * 4, cB = 64 + tx * 4;
    const int r0  = ty * 4;
    const int rs  = tid >> 2;
    const int k4  = (tid & 3) * 4;

    float acc[4][8];
    {
        float4 bA = *(const float4*)&eb1[st * FDIM + cA];
        float4 bB = *(const float4*)&eb1[st * FDIM + cB];
        #pragma unroll
        for (int i = 0; i < 4; ++i) {
            acc[i][0]=bA.x; acc[i][1]=bA.y; acc[i][2]=bA.z; acc[i][3]=bA.w;
            acc[i][4]=bB.x; acc[i][5]=bB.y; acc[i][6]=bB.z; acc[i][7]=bB.w;
        }
    }

    for (int kc = 0; kc < 8; ++kc) {
        __syncthreads();
        {
            int kg = kc * 16 + k4;
            int n  = n0 + rs;
            float4 a = make_float4(0.f, 0.f, 0.f, 0.f);
            if (n < N) a = *(const float4*)&s[(size_t)n * FDIM + kg];
            shA[k4+0][rs] = a.x; shA[k4+1][rs] = a.y; shA[k4+2][rs] = a.z; shA[k4+3][rs] = a.w;
        }
        #pragma unroll
        for (int i = 0; i < 2; ++i) {
            int idx = tid + i * 256;
            int kk = idx >> 5;
            int c4 = (idx & 31) * 4;
            *(float4*)&shB[kk][c4] =
                *(const float4*)&ew1[(size_t)st * FDIM * FDIM + (size_t)(kc*16+kk) * FDIM + c4];
        }
        __syncthreads();
        #pragma unroll
        for (int kk = 0; kk < 16; ++kk) {
            float4 a4 = *(const float4*)&shA[kk][r0];
            float4 b0 = *(const float4*)&shB[kk][cA];
            float4 b1 = *(const float4*)&shB[kk][cB];
            float av[4] = {a4.x, a4.y, a4.z, a4.w};
            #pragma unroll
            for (int i = 0; i < 4; ++i) {
                acc[i][0] += av[i]*b0.x; acc[i][1] += av[i]*b0.y;
                acc[i][2] += av[i]*b0.z; acc[i][3] += av[i]*b0.w;
                acc[i][4] += av[i]*b1.x; acc[i][5] += av[i]*b1.y;
                acc[i][6] += av[i]*b1.z; acc[i][7] += av[i]*b1.w;
            }
        }
    }

    float4 wA = *(const float4*)&ew2[st * FDIM + cA];
    float4 wB = *(const float4*)&ew2[st * FDIM + cB];
    float p[4];
    #pragma unroll
    for (int i = 0; i < 4; ++i) {
        p[i]  = siluf(acc[i][0])*wA.x + siluf(acc[i][1])*wA.y
              + siluf(acc[i][2])*wA.z + siluf(acc[i][3])*wA.w;
        p[i] += siluf(acc[i][4])*wB.x + siluf(acc[i][5])*wB.y
              + siluf(acc[i][6])*wB.z + siluf(acc[i][7])*wB.w;
    }
    #pragma unroll
    for (int m = 1; m <= 8; m <<= 1) {
        #pragma unroll
        for (int i = 0; i < 4; ++i) p[i] += __shfl_xor(p[i], m, 64);
    }
    if (tx == 0) {
        float b2 = eb2[st];
        #pragma unroll
        for (int i = 0; i < 4; ++i) {
            int n = n0 + r0 + i;
            if (n < N) atomicAdd(&energies[batch[n] * S + st], p[i] + b2);
        }
    }
}

// ---------------------------------------------------------------- dipole / nac heads
__global__ void k_vec(const float* __restrict__ v, const float* __restrict__ dipole_w,
                      const float* __restrict__ nac_w, const int* __restrict__ batch,
                      float* __restrict__ dipoles, float* __restrict__ nac, int N)
{
    int n = blockIdx.x * 4 + (threadIdx.x >> 6);
    int lane = threadIdx.x & 63;
    if (n >= N) return;
    float pd[3] = {0.f, 0.f, 0.f};
    float pn[3][3] = {{0.f}};
    const float* vb = v + (size_t)n * 3 * FDIM;
    for (int f = lane; f < FDIM; f += 64) {
        float v0 = vb[f], v1 = vb[FDIM + f], v2 = vb[2*FDIM + f];
        float wd = dipole_w[f];
        pd[0] += wd * v0; pd[1] += wd * v1; pd[2] += wd * v2;
        #pragma unroll
        for (int p = 0; p < 3; ++p) {
            float wn = nac_w[p * FDIM + f];
            pn[p][0] += wn * v0; pn[p][1] += wn * v1; pn[p][2] += wn * v2;
        }
    }
    #pragma unroll
    for (int d = 32; d > 0; d >>= 1) {
        #pragma unroll
        for (int k = 0; k < 3; ++k) pd[k] += __shfl_down(pd[k], d, 64);
        #pragma unroll
        for (int p = 0; p < 3; ++p)
            #pragma unroll
            for (int k = 0; k < 3; ++k) pn[p][k] += __shfl_down(pn[p][k], d, 64);
    }
    if (lane == 0) {
        int m = batch[n];
        #pragma unroll
        for (int k = 0; k < 3; ++k) atomicAdd(&dipoles[m * 3 + k], pd[k]);
        #pragma unroll
        for (int p = 0; p < 3; ++p)
            #pragma unroll
            for (int k = 0; k < 3; ++k) atomicAdd(&nac[(m * 3 + p) * 3 + k], pn[p][k]);
    }
}

// ---------------------------------------------------------------- per-molecule heads
__global__ __launch_bounds__(128) void k_heads(
    const float* __restrict__ aw1, const float* __restrict__ ab1,
    const float* __restrict__ aw2, const float* __restrict__ ab2,
    const float* __restrict__ yw1, const float* __restrict__ yb1,
    const float* __restrict__ yw2, const float* __restrict__ yb2,
    const float* __restrict__ energies, const float* __restrict__ nac,
    float* __restrict__ lam, float* __restrict__ phi_y, int M, int S)
{
    __shared__ float sh_in[8];
    __shared__ float sh_red[2];
    int m = blockIdx.x;
    if (m >= M) return;
    int tid = threadIdx.x;
    if (tid == 0) {
        float e0 = energies[m * S];
        for (int j = 0; j < 3; ++j) sh_in[j] = energies[m * S + 1 + j] - e0;
        for (int p = 0; p < 3; ++p) {
            float a = nac[(m * 3 + p) * 3 + 0];
            float b = nac[(m * 3 + p) * 3 + 1];
            float c = nac[(m * 3 + p) * 3 + 2];
            sh_in[3 + p] = sqrtf(a*a + b*b + c*c + 1e-12f);
        }
    }
    __syncthreads();
    float pa = 0.f;
    if (tid < 64) {
        float h = ab1[tid];
        #pragma unroll
        for (int j = 0; j < 3; ++j) h += sh_in[j] * aw1[j * 64 + tid];
        pa = siluf(h) * aw2[tid];
    }
    float h2 = yb1[tid];
    #pragma unroll
    for (int j = 0; j < 6; ++j) h2 += sh_in[j] * yw1[j * 128 + tid];
    float py = siluf(h2) * yw2[tid];
    #pragma unroll
    for (int d = 32; d > 0; d >>= 1) {
        pa += __shfl_down(pa, d, 64);
        py += __shfl_down(py, d, 64);
    }
    int wid = tid >> 6, lane = tid & 63;
    if (lane == 0) sh_red[wid] = py;
    __syncthreads();
    if (tid == 0) {
        lam[m] = pa + ab2[0];
        float yt = sh_red[0] + sh_red[1] + yb2[0];
        phi_y[m] = 1.f / (1.f + __expf(-yt));
    }
}

// ---------------------------------------------------------------- launch
extern "C" void kernel_launch(void* const* d_in, const int* in_sizes, int n_in,
                              void* d_out, int out_size, void* d_ws, size_t ws_size,
                              hipStream_t stream)
{
    const int*   z        = (const int*)  d_in[0];
    const float* pos      = (const float*)d_in[1];
    const int*   eidx     = (const int*)  d_in[2];
    const int*   batch    = (const int*)  d_in[3];
    const float* emb      = (const float*)d_in[5];
    const float* centers  = (const float*)d_in[6];
    const float* gamma    = (const float*)d_in[7];
    const float* fw1      = (const float*)d_in[8];
    const float* fb1      = (const float*)d_in[9];
    const float* fw2      = (const float*)d_in[10];
    const float* fb2      = (const float*)d_in[11];
    const float* uw1      = (const float*)d_in[12];
    const float* ub1      = (const float*)d_in[13];
    const float* uw2      = (const float*)d_in[14];
    const float* ub2      = (const float*)d_in[15];
    const float* ew1      = (const float*)d_in[16];
    const float* eb1      = (const float*)d_in[17];
    const float* ew2      = (const float*)d_in[18];
    const float* eb2      = (const float*)d_in[19];
    const float* dipole_w = (const float*)d_in[20];
    const float* nac_w    = (const float*)d_in[21];
    const float* aw1      = (const float*)d_in[22];
    const float* ab1      = (const float*)d_in[23];
    const float* aw2      = (const float*)d_in[24];
    const float* ab2      = (const float*)d_in[25];
    const float* yw1      = (const float*)d_in[26];
    const float* yb1      = (const float*)d_in[27];
    const float* yw2      = (const float*)d_in[28];
    const float* yb2      = (const float*)d_in[29];

    const int N = in_sizes[0];
    const int E = in_sizes[2] / 2;
    const int S = in_sizes[19];
    const int P = in_sizes[21] / FDIM;
    const int L = in_sizes[9] / FDIM;
    const int M = out_size / (S + 3 + P * 3 + 2);

    const size_t NF = (size_t)N * FDIM;
    float*  s    = (float*)d_ws;                 // NF
    float*  v    = s + NF;                       // 3 NF
    float*  m_s  = v + 3 * NF;                   // NF
    float*  m_v  = m_s + NF;                     // 3 NF
    __half* s_h  = (__half*)(m_v + 3 * NF);      // NF halves
    __half* v_h  = s_h + NF;                     // 3 NF halves
    __half* tab  = v_h + 3 * NF;                 // (TAB_T+1)*384 halves
    int* rowstart = (int*)(tab + (size_t)(TAB_T + 1) * 384);
    int* cursor   = rowstart + (N + 1);
    int* esort    = cursor + N;

    float* out      = (float*)d_out;
    float* energies = out;
    float* dipoles  = energies + (size_t)M * S;
    float* nac      = dipoles  + (size_t)M * 3;
    float* lam      = nac      + (size_t)M * P * 3;
    float* phi_y    = lam      + M;

    const int* erow = eidx;
    const int* ecol = eidx + E;

    const float step = TAB_RANGE / (float)TAB_T;
    const float inv_step = (float)TAB_T / TAB_RANGE;
    const int NB = (N + 63) / 64;

    hipMemsetAsync(d_out, 0, (size_t)out_size * sizeof(float), stream);
    hipMemsetAsync(cursor, 0, (size_t)N * sizeof(int), stream);
    k_hist<<<(E + 255) / 256, 256, 0, stream>>>(erow, cursor, E);
    k_scan<<<1, 256, 0, stream>>>(cursor, rowstart, N);
    k_fill<<<(E + 255) / 256, 256, 0, stream>>>(erow, cursor, esort, E);
    k_init<<<(N * FDIM + 255) / 256, 256, 0, stream>>>(z, emb, s, v, s_h, v_h, N);

    const int tab_blocks = (TAB_T + 1 + 31) / 32;
    for (int l = 0; l < L; ++l) {
        k_table<<<tab_blocks, TH, 0, stream>>>(
            centers, gamma,
            fw1 + (size_t)l * RDIM * FDIM, fb1 + (size_t)l * FDIM,
            fw2 + (size_t)l * FDIM * 3 * FDIM, fb2 + (size_t)l * 3 * FDIM,
            tab, step);
        k_gather<<<N, 128, 0, stream>>>(
            pos, ecol, rowstart, esort, tab, s_h, v_h, m_s, m_v, inv_step, (l > 0) ? 1 : 0, N);
        k_update_fused<<<NB, 128, 0, stream>>>(
            s, m_s, m_v,
            uw1 + (size_t)l * 3 * FDIM * FDIM, ub1 + (size_t)l * FDIM,
            uw2 + (size_t)l * FDIM * 3 * FDIM, ub2 + (size_t)l * 3 * FDIM,
            v, s_h, v_h, N);
    }

    k_energy2<<<dim3(NB, S), 256, 0, stream>>>(ew1, eb1, ew2, eb2, s, batch, energies, N, S);
    k_vec<<<(N + 3) / 4, 256, 0, stream>>>(v, dipole_w, nac_w, batch, dipoles, nac, N);
    k_heads<<<M, 128, 0, stream>>>(aw1, ab1, aw2, ab2, yw1, yb1, yw2, yb2,
                                   energies, nac, lam, phi_y, M, S);
}

// Round 6
// 727.808 us; speedup vs baseline: 23.6203x; 1.2213x over previous
//
#include <hip/hip_runtime.h>
#include <hip/hip_fp16.h>

#define FDIM 128
#define RDIM 20

#define TAB_T 2048              // table cells; TAB_T+1 rows
#define TAB_RANGE 12.0f

constexpr int TH = 256;

__device__ __forceinline__ float siluf(float x) { return x / (1.f + __expf(-x)); }

__device__ __forceinline__ void store_h4(__half* p, float a, float b, float c, float d) {
    __half h[4] = {__float2half(a), __float2half(b), __float2half(c), __float2half(d)};
    *(uint2*)p = *(uint2*)h;
}

// ---------------------------------------------------------------- init: s = emb[z], v = 0
// v layout: [N][3][FDIM]
__global__ void k_init(const int* __restrict__ z, const float* __restrict__ emb,
                       float* __restrict__ s, float* __restrict__ v,
                       __half* __restrict__ s_h, __half* __restrict__ v_h, int N) {
    int i = blockIdx.x * blockDim.x + threadIdx.x;
    if (i >= N * FDIM) return;
    int n = i >> 7, f = i & 127;
    float val = emb[z[n] * FDIM + f];
    s[i] = val;
    s_h[i] = __float2half(val);
    size_t nf = (size_t)N * FDIM;
    v[i] = 0.f; v[i + nf] = 0.f; v[i + 2 * nf] = 0.f;
    __half hz = __float2half(0.f);
    v_h[i] = hz; v_h[i + nf] = hz; v_h[i + 2 * nf] = hz;
}

// ---------------------------------------------------------------- CSR build
__global__ void k_hist(const int* __restrict__ erow, int* __restrict__ cursor, int E) {
    int e = blockIdx.x * blockDim.x + threadIdx.x;
    if (e < E) atomicAdd(&cursor[erow[e]], 1);
}

__global__ __launch_bounds__(256) void k_scan(int* __restrict__ cursor,
                                              int* __restrict__ rowstart, int N) {
    __shared__ int sh[256];
    __shared__ int carry;
    int tid = threadIdx.x;
    if (tid == 0) carry = 0;
    __syncthreads();
    for (int base = 0; base < N; base += 256) {
        int idx = base + tid;
        int x = (idx < N) ? cursor[idx] : 0;
        sh[tid] = x;
        __syncthreads();
        for (int off = 1; off < 256; off <<= 1) {
            int t = (tid >= off) ? sh[tid - off] : 0;
            __syncthreads();
            sh[tid] += t;
            __syncthreads();
        }
        int excl = carry + sh[tid] - x;
        if (idx < N) { rowstart[idx] = excl; cursor[idx] = excl; }
        __syncthreads();
        if (tid == 0) carry += sh[255];
        __syncthreads();
    }
    if (tid == 0) rowstart[N] = carry;
}

__global__ void k_fill(const int* __restrict__ erow, int* __restrict__ cursor,
                       int* __restrict__ esort, int E) {
    int e = blockIdx.x * blockDim.x + threadIdx.x;
    if (e < E) {
        int p = atomicAdd(&cursor[erow[e]], 1);
        esort[p] = e;
    }
}

// ---------------------------------------------------------------- filter-MLP table build (all layers, fp16 out)
__global__ __launch_bounds__(TH) void k_table(
    const float* __restrict__ centers, const float* __restrict__ gamma,
    const float* __restrict__ fw1b, const float* __restrict__ fb1b,
    const float* __restrict__ fw2b, const float* __restrict__ fb2b,
    __half* __restrict__ tabb, float step)
{
    __shared__ float sh_rbf[32][RDIM];
    __shared__ float sh_ht[FDIM][33];
    __shared__ float sh_w[32][3 * FDIM + 4];

    const int l   = blockIdx.y;
    const float* fw1 = fw1b + (size_t)l * RDIM * FDIM;
    const float* fb1 = fb1b + (size_t)l * FDIM;
    const float* fw2 = fw2b + (size_t)l * FDIM * 3 * FDIM;
    const float* fb2 = fb2b + (size_t)l * 3 * FDIM;
    __half* tab = tabb + (size_t)l * (TAB_T + 1) * 384;

    const int p0  = blockIdx.x * 32;
    const int tid = threadIdx.x;

    for (int i = tid; i < 32 * RDIM; i += TH) {
        int p = i / RDIM, r = i - p * RDIM;
        float d = (float)(p0 + p) * step - centers[r];
        sh_rbf[p][r] = __expf(-gamma[r] * d * d);
    }
    __syncthreads();
    for (int i = tid; i < 32 * FDIM; i += TH) {
        int p = i >> 7, f = i & 127;
        float acc = fb1[f];
        #pragma unroll
        for (int r = 0; r < RDIM; ++r) acc += sh_rbf[p][r] * fw1[r * FDIM + f];
        sh_ht[f][p] = siluf(acc);
    }

    const int eq = tid & 7;
    const int fq = tid >> 3;
    const int f0 = fq * 4;

    float pg[3][4][4];
    #pragma unroll
    for (int g3 = 0; g3 < 3; ++g3)
        #pragma unroll
        for (int ee = 0; ee < 4; ++ee)
            #pragma unroll
            for (int i = 0; i < 4; ++i) pg[g3][ee][i] = fb2[g3 * FDIM + f0 + i];

    const int kkr = tid >> 3;
    const int t8  = tid & 7;
    for (int kc = 0; kc < 4; ++kc) {
        __syncthreads();
        #pragma unroll
        for (int j = 0; j < 12; ++j) {
            int g = (t8 * 12 + j) * 4;
            float4 w4 = *(const float4*)&fw2[(size_t)(kc * 32 + kkr) * (3 * FDIM) + g];
            *(float4*)&sh_w[kkr][g] = w4;
        }
        __syncthreads();
        #pragma unroll 4
        for (int kk = 0; kk < 32; ++kk) {
            float hv[4];
            #pragma unroll
            for (int ee = 0; ee < 4; ++ee) hv[ee] = sh_ht[kc * 32 + kk][4 * eq + ee];
            #pragma unroll
            for (int g3 = 0; g3 < 3; ++g3) {
                float4 w4 = *(const float4*)&sh_w[kk][g3 * FDIM + f0];
                #pragma unroll
                for (int ee = 0; ee < 4; ++ee) {
                    pg[g3][ee][0] += hv[ee] * w4.x;
                    pg[g3][ee][1] += hv[ee] * w4.y;
                    pg[g3][ee][2] += hv[ee] * w4.z;
                    pg[g3][ee][3] += hv[ee] * w4.w;
                }
            }
        }
    }

    #pragma unroll
    for (int ee = 0; ee < 4; ++ee) {
        int pt = p0 + 4 * eq + ee;
        if (pt <= TAB_T) {
            #pragma unroll
            for (int g3 = 0; g3 < 3; ++g3)
                store_h4(&tab[(size_t)pt * 384 + g3 * FDIM + f0],
                         pg[g3][ee][0], pg[g3][ee][1], pg[g3][ee][2], pg[g3][ee][3]);
        }
    }
}

// ---------------------------------------------------------------- gather message kernel (fp16 inputs)
__global__ __launch_bounds__(128) void k_gather(
    const float* __restrict__ pos, const int* __restrict__ ecol,
    const int* __restrict__ rowstart, const int* __restrict__ esort,
    const __half* __restrict__ tab, const __half* __restrict__ s_h,
    const __half* __restrict__ v_h,
    float* __restrict__ m_s, float* __restrict__ m_v, float inv_step, int withv, int N)
{
    __shared__ int   sh_col[32];
    __shared__ int   sh_t0[32];
    __shared__ float sh_w[32];
    __shared__ float sh_d0[32], sh_d1[32], sh_d2[32];

    const int n   = blockIdx.x;
    const int tid = threadIdx.x;
    const int lo  = rowstart[n], hi = rowstart[n + 1];

    float acc_s = 0.f, av0 = 0.f, av1 = 0.f, av2 = 0.f;
    const float px = pos[n * 3 + 0], py = pos[n * 3 + 1], pz = pos[n * 3 + 2];

    for (int base = lo; base < hi; base += 32) {
        const int ne = min(32, hi - base);
        __syncthreads();
        if (tid < 32) {
            if (tid < ne) {
                int e  = esort[base + tid];
                int cl = ecol[e];
                float dx = pos[cl*3+0] - px;
                float dy = pos[cl*3+1] - py;
                float dz = pos[cl*3+2] - pz;
                float dist = sqrtf(dx*dx + dy*dy + dz*dz + 1e-12f);
                float inv = 1.f / (dist + 1e-8f);
                sh_col[tid] = cl;
                sh_d0[tid] = dx*inv; sh_d1[tid] = dy*inv; sh_d2[tid] = dz*inv;
                float u = fminf(dist * inv_step, (float)TAB_T);
                int t0 = min((int)u, TAB_T - 1);
                sh_t0[tid] = t0;
                sh_w[tid]  = u - (float)t0;
            } else {
                sh_col[tid] = 0; sh_t0[tid] = 0; sh_w[tid] = 0.f;
                sh_d0[tid] = sh_d1[tid] = sh_d2[tid] = 0.f;
            }
        }
        __syncthreads();
        if (withv) {
            #pragma unroll 2
            for (int el = 0; el < ne; ++el) {
                int   cl = sh_col[el];
                int   t0 = sh_t0[el];
                float w  = sh_w[el];
                const __half* ta = tab + (size_t)t0 * 384 + tid;
                float a_ss = __half2float(ta[0]),   b_ss = __half2float(ta[384]);
                float a_vv = __half2float(ta[128]), b_vv = __half2float(ta[512]);
                float a_sv = __half2float(ta[256]), b_sv = __half2float(ta[640]);
                float pss = a_ss + w * (b_ss - a_ss);
                float pvv = a_vv + w * (b_vv - a_vv);
                float psv = a_sv + w * (b_sv - a_sv);
                float sc = __half2float(s_h[(size_t)cl * FDIM + tid]);
                const __half* vp = v_h + (size_t)cl * 3 * FDIM + tid;
                float svs = psv * sc;
                acc_s += pss * sc;
                av0 += pvv * __half2float(vp[0])        + svs * sh_d0[el];
                av1 += pvv * __half2float(vp[FDIM])     + svs * sh_d1[el];
                av2 += pvv * __half2float(vp[2*FDIM])   + svs * sh_d2[el];
            }
        } else {
            #pragma unroll 2
            for (int el = 0; el < ne; ++el) {
                int   cl = sh_col[el];
                int   t0 = sh_t0[el];
                float w  = sh_w[el];
                const __half* ta = tab + (size_t)t0 * 384 + tid;
                float a_ss = __half2float(ta[0]),   b_ss = __half2float(ta[384]);
                float a_sv = __half2float(ta[256]), b_sv = __half2float(ta[640]);
                float pss = a_ss + w * (b_ss - a_ss);
                float psv = a_sv + w * (b_sv - a_sv);
                float sc = __half2float(s_h[(size_t)cl * FDIM + tid]);
                float svs = psv * sc;
                acc_s += pss * sc;
                av0 += svs * sh_d0[el];
                av1 += svs * sh_d1[el];
                av2 += svs * sh_d2[el];
            }
        }
    }

    m_s[(size_t)n * FDIM + tid] = acc_s;
    float* mv = m_v + (size_t)n * 3 * FDIM + tid;
    mv[0] = av0; mv[FDIM] = av1; mv[2*FDIM] = av2;
}

// ---------------------------------------------------------------- GEMM 1: u1 = silu(X @ uw1 + ub1)
// X = [s | m_s | ||m_v||]. Tile 64x128, 256 thr, 4x8 micro, K=384.
// Software-pipelined: next K-tile loaded into registers while current computes.
__global__ __launch_bounds__(256) void k_mlp1(
    const float* __restrict__ s, const float* __restrict__ m_s, const float* __restrict__ m_v,
    const float* __restrict__ uw1, const float* __restrict__ ub1,
    float* __restrict__ u1, int N)
{
    __shared__ float shA[16][68];    // [kk][row]
    __shared__ float shB[16][132];   // [kk][col]

    const int tid = threadIdx.x;
    const int n0  = blockIdx.x * 64;
    const int tx  = tid & 15, ty = tid >> 4;
    const int cA  = tx * 4, cB = 64 + tx * 4;
    const int r0  = ty * 4;
    const int rs  = tid >> 2;           // staging row 0..63
    const int k4  = (tid & 3) * 4;      // staging k offset
    const int bk  = tid >> 5;           // B staging row 0..7
    const int bc4 = (tid & 31) * 4;     // B staging col

    float acc[4][8];
    {
        float4 bA = *(const float4*)&ub1[cA];
        float4 bB = *(const float4*)&ub1[cB];
        #pragma unroll
        for (int i = 0; i < 4; ++i) {
            acc[i][0]=bA.x; acc[i][1]=bA.y; acc[i][2]=bA.z; acc[i][3]=bA.w;
            acc[i][4]=bB.x; acc[i][5]=bB.y; acc[i][6]=bB.z; acc[i][7]=bB.w;
        }
    }

    float4 pa, pay, paz, pb0, pb1;

#define MLP1_LOAD(kc) do { \
        int kg = (kc) * 16 + k4; int n = n0 + rs; \
        pa = make_float4(0.f,0.f,0.f,0.f); \
        pay = make_float4(0.f,0.f,0.f,0.f); paz = make_float4(0.f,0.f,0.f,0.f); \
        if (n < N) { \
            if (kg < 128) { pa = *(const float4*)&s[(size_t)n * FDIM + kg]; } \
            else if (kg < 256) { pa = *(const float4*)&m_s[(size_t)n * FDIM + kg - 128]; } \
            else { const float* mvp = m_v + (size_t)n * 3 * FDIM + (kg - 256); \
                   pa = *(const float4*)&mvp[0]; \
                   pay = *(const float4*)&mvp[FDIM]; \
                   paz = *(const float4*)&mvp[2*FDIM]; } \
        } \
        pb0 = *(const float4*)&uw1[(size_t)((kc)*16 + bk) * FDIM + bc4]; \
        pb1 = *(const float4*)&uw1[(size_t)((kc)*16 + 8 + bk) * FDIM + bc4]; \
    } while (0)

    MLP1_LOAD(0);
    for (int kc = 0; kc < 24; ++kc) {
        __syncthreads();
        // store current regs -> LDS
        {
            int kg = kc * 16 + k4;
            float4 a = pa;
            if (kg >= 256) {
                a.x = sqrtf(pa.x*pa.x + pay.x*pay.x + paz.x*paz.x + 1e-12f);
                a.y = sqrtf(pa.y*pa.y + pay.y*pay.y + paz.y*paz.y + 1e-12f);
                a.z = sqrtf(pa.z*pa.z + pay.z*pay.z + paz.z*paz.z + 1e-12f);
                a.w = sqrtf(pa.w*pa.w + pay.w*pay.w + paz.w*paz.w + 1e-12f);
            }
            shA[k4+0][rs] = a.x; shA[k4+1][rs] = a.y;
            shA[k4+2][rs] = a.z; shA[k4+3][rs] = a.w;
            *(float4*)&shB[bk][bc4]     = pb0;
            *(float4*)&shB[8 + bk][bc4] = pb1;
        }
        // prefetch next tile (latency hides under compute below)
        if (kc + 1 < 24) MLP1_LOAD(kc + 1);
        __syncthreads();
        #pragma unroll
        for (int kk = 0; kk < 16; ++kk) {
            float4 a4 = *(const float4*)&shA[kk][r0];
            float4 b0 = *(const float4*)&shB[kk][cA];
            float4 b1 = *(const float4*)&shB[kk][cB];
            float av[4] = {a4.x, a4.y, a4.z, a4.w};
            #pragma unroll
            for (int i = 0; i < 4; ++i) {
                acc[i][0] += av[i]*b0.x; acc[i][1] += av[i]*b0.y;
                acc[i][2] += av[i]*b0.z; acc[i][3] += av[i]*b0.w;
                acc[i][4] += av[i]*b1.x; acc[i][5] += av[i]*b1.y;
                acc[i][6] += av[i]*b1.z; acc[i][7] += av[i]*b1.w;
            }
        }
    }
#undef MLP1_LOAD

    #pragma unroll
    for (int i = 0; i < 4; ++i) {
        int n = n0 + r0 + i;
        if (n < N) {
            float4 oA = make_float4(siluf(acc[i][0]), siluf(acc[i][1]), siluf(acc[i][2]), siluf(acc[i][3]));
            float4 oB = make_float4(siluf(acc[i][4]), siluf(acc[i][5]), siluf(acc[i][6]), siluf(acc[i][7]));
            *(float4*)&u1[(size_t)n * FDIM + cA] = oA;
            *(float4*)&u1[(size_t)n * FDIM + cB] = oB;
        }
    }
}

// ---------------------------------------------------------------- GEMM 2: upd = u1 @ uw2 + ub2, fused apply
// u1 tile staged in LDS once; B tiles software-pipelined; alpha in regs;
// g0: s += delta (and s_h), g2: v = a*v + b*m_v (and v_h).
__global__ __launch_bounds__(256) void k_mlp2(
    const float* __restrict__ u1, const float* __restrict__ uw2, const float* __restrict__ ub2,
    float* __restrict__ s, float* __restrict__ v, const float* __restrict__ m_v,
    __half* __restrict__ s_h, __half* __restrict__ v_h, int N)
{
    __shared__ float shU[64][132];
    __shared__ float shB[16][132];

    const int tid = threadIdx.x;
    const int n0  = blockIdx.x * 64;
    const int tx  = tid & 15, ty = tid >> 4;
    const int cA  = tx * 4, cB = 64 + tx * 4;
    const int r0  = ty * 4;
    const int bk  = tid >> 5;
    const int bc4 = (tid & 31) * 4;

    // stage u1 tile (64 x 128) once
    #pragma unroll
    for (int it = 0; it < 8; ++it) {
        int idx = it * 256 + tid;
        int row = idx >> 5;
        int c4  = (idx & 31) * 4;
        int n = n0 + row;
        float4 a = make_float4(0.f,0.f,0.f,0.f);
        if (n < N) a = *(const float4*)&u1[(size_t)n * FDIM + c4];
        *(float4*)&shU[row][c4] = a;
    }

    float4 pb0, pb1;
#define MLP2_LOADB(g, kc) do { \
        pb0 = *(const float4*)&uw2[(size_t)((kc)*16 + bk) * (3*FDIM) + (g) * FDIM + bc4]; \
        pb1 = *(const float4*)&uw2[(size_t)((kc)*16 + 8 + bk) * (3*FDIM) + (g) * FDIM + bc4]; \
    } while (0)

    MLP2_LOADB(0, 0);
    float alpha[4][8];

    for (int g = 0; g < 3; ++g) {
        float acc2[4][8];
        {
            float4 bA = *(const float4*)&ub2[g * FDIM + cA];
            float4 bB = *(const float4*)&ub2[g * FDIM + cB];
            #pragma unroll
            for (int i = 0; i < 4; ++i) {
                acc2[i][0]=bA.x; acc2[i][1]=bA.y; acc2[i][2]=bA.z; acc2[i][3]=bA.w;
                acc2[i][4]=bB.x; acc2[i][5]=bB.y; acc2[i][6]=bB.z; acc2[i][7]=bB.w;
            }
        }
        for (int kc = 0; kc < 8; ++kc) {
            __syncthreads();
            *(float4*)&shB[bk][bc4]     = pb0;
            *(float4*)&shB[8 + bk][bc4] = pb1;
            if (kc + 1 < 8)      MLP2_LOADB(g, kc + 1);
            else if (g + 1 < 3)  MLP2_LOADB(g + 1, 0);   // overlaps this gate's epilogue too
            __syncthreads();
            #pragma unroll
            for (int kk = 0; kk < 16; ++kk) {
                int col = kc * 16 + kk;
                float4 b0 = *(const float4*)&shB[kk][cA];
                float4 b1 = *(const float4*)&shB[kk][cB];
                #pragma unroll
                for (int i = 0; i < 4; ++i) {
                    float uv = shU[r0 + i][col];
                    acc2[i][0] += uv*b0.x; acc2[i][1] += uv*b0.y;
                    acc2[i][2] += uv*b0.z; acc2[i][3] += uv*b0.w;
                    acc2[i][4] += uv*b1.x; acc2[i][5] += uv*b1.y;
                    acc2[i][6] += uv*b1.z; acc2[i][7] += uv*b1.w;
                }
            }
        }

        if (g == 0) {
            #pragma unroll
            for (int i = 0; i < 4; ++i) {
                int n = n0 + r0 + i;
                if (n < N) {
                    float4 s0 = *(const float4*)&s[(size_t)n * FDIM + cA];
                    float4 s1 = *(const float4*)&s[(size_t)n * FDIM + cB];
                    s0.x += acc2[i][0]; s0.y += acc2[i][1]; s0.z += acc2[i][2]; s0.w += acc2[i][3];
                    s1.x += acc2[i][4]; s1.y += acc2[i][5]; s1.z += acc2[i][6]; s1.w += acc2[i][7];
                    *(float4*)&s[(size_t)n * FDIM + cA] = s0;
                    *(float4*)&s[(size_t)n * FDIM + cB] = s1;
                    store_h4(&s_h[(size_t)n * FDIM + cA], s0.x, s0.y, s0.z, s0.w);
                    store_h4(&s_h[(size_t)n * FDIM + cB], s1.x, s1.y, s1.z, s1.w);
                }
            }
        } else if (g == 1) {
            #pragma unroll
            for (int i = 0; i < 4; ++i)
                #pragma unroll
                for (int j = 0; j < 8; ++j) alpha[i][j] = acc2[i][j];
        } else {
            #pragma unroll
            for (int i = 0; i < 4; ++i) {
                int n = n0 + r0 + i;
                if (n < N) {
                    #pragma unroll
                    for (int k = 0; k < 3; ++k) {
                        float* vp = v + ((size_t)n * 3 + k) * FDIM;
                        const float* mp = m_v + ((size_t)n * 3 + k) * FDIM;
                        __half* vhp = v_h + ((size_t)n * 3 + k) * FDIM;
                        float4 v0 = *(const float4*)&vp[cA];
                        float4 v1 = *(const float4*)&vp[cB];
                        float4 m0 = *(const float4*)&mp[cA];
                        float4 m1 = *(const float4*)&mp[cB];
                        v0.x = alpha[i][0]*v0.x + acc2[i][0]*m0.x;
                        v0.y = alpha[i][1]*v0.y + acc2[i][1]*m0.y;
                        v0.z = alpha[i][2]*v0.z + acc2[i][2]*m0.z;
                        v0.w = alpha[i][3]*v0.w + acc2[i][3]*m0.w;
                        v1.x = alpha[i][4]*v1.x + acc2[i][4]*m1.x;
                        v1.y = alpha[i][5]*v1.y + acc2[i][5]*m1.y;
                        v1.z = alpha[i][6]*v1.z + acc2[i][6]*m1.z;
                        v1.w = alpha[i][7]*v1.w + acc2[i][7]*m1.w;
                        *(float4*)&vp[cA] = v0;
                        *(float4*)&vp[cB] = v1;
                        store_h4(&vhp[cA], v0.x, v0.y, v0.z, v0.w);
                        store_h4(&vhp[cB], v1.x, v1.y, v1.z, v1.w);
                    }
                }
            }
        }
    }
#undef MLP2_LOADB
}

// ---------------------------------------------------------------- energy head GEMM
__global__ __launch_bounds__(256) void k_energy2(
    const float* __restrict__ ew1, const float* __restrict__ eb1,
    const float* __restrict__ ew2, const float* __restrict__ eb2,
    const float* __restrict__ s, const int* __restrict__ batch,
    float* __restrict__ energies, int N, int S)
{
    __shared__ float shA[16][68];
    __shared__ float shB[16][132];

    const int tid = threadIdx.x;
    const int n0  = blockIdx.x * 64;
    const int st  = blockIdx.y;
    const int tx  = tid & 15, ty = tid >> 4;
    const int cA  = tx * 4, cB = 64 + tx * 4;
    const int r0  = ty * 4;
    const int rs  = tid >> 2;
    const int k4  = (tid & 3) * 4;

    float acc[4][8];
    {
        float4 bA = *(const float4*)&eb1[st * FDIM + cA];
        float4 bB = *(const float4*)&eb1[st * FDIM + cB];
        #pragma unroll
        for (int i = 0; i < 4; ++i) {
            acc[i][0]=bA.x; acc[i][1]=bA.y; acc[i][2]=bA.z; acc[i][3]=bA.w;
            acc[i][4]=bB.x; acc[i][5]=bB.y; acc[i][6]=bB.z; acc[i][7]=bB.w;
        }
    }

    for (int kc = 0; kc < 8; ++kc) {
        __syncthreads();
        {
            int kg = kc * 16 + k4;
            int n  = n0 + rs;
            float4 a = make_float4(0.f, 0.f, 0.f, 0.f);
            if (n < N) a = *(const float4*)&s[(size_t)n * FDIM + kg];
            shA[k4+0][rs] = a.x; shA[k4+1][rs] = a.y; shA[k4+2][rs] = a.z; shA[k4+3][rs] = a.w;
        }
        #pragma unroll
        for (int i = 0; i < 2; ++i) {
            int idx = tid + i * 256;
            int kk = idx >> 5;
            int c4 = (idx & 31) * 4;
            *(float4*)&shB[kk][c4] =
                *(const float4*)&ew1[(size_t)st * FDIM * FDIM + (size_t)(kc*16+kk) * FDIM + c4];
        }
        __syncthreads();
        #pragma unroll
        for (int kk = 0; kk < 16; ++kk) {
            float4 a4 = *(const float4*)&shA[kk][r0];
            float4 b0 = *(const float4*)&shB[kk][cA];
            float4 b1 = *(const float4*)&shB[kk][cB];
            float av[4] = {a4.x, a4.y, a4.z, a4.w};
            #pragma unroll
            for (int i = 0; i < 4; ++i) {
                acc[i][0] += av[i]*b0.x; acc[i][1] += av[i]*b0.y;
                acc[i][2] += av[i]*b0.z; acc[i][3] += av[i]*b0.w;
                acc[i][4] += av[i]*b1.x; acc[i][5] += av[i]*b1.y;
                acc[i][6] += av[i]*b1.z; acc[i][7] += av[i]*b1.w;
            }
        }
    }

    float4 wA = *(const float4*)&ew2[st * FDIM + cA];
    float4 wB = *(const float4*)&ew2[st * FDIM + cB];
    float p[4];
    #pragma unroll
    for (int i = 0; i < 4; ++i) {
        p[i]  = siluf(acc[i][0])*wA.x + siluf(acc[i][1])*wA.y
              + siluf(acc[i][2])*wA.z + siluf(acc[i][3])*wA.w;
        p[i] += siluf(acc[i][4])*wB.x + siluf(acc[i][5])*wB.y
              + siluf(acc[i][6])*wB.z + siluf(acc[i][7])*wB.w;
    }
    #pragma unroll
    for (int m = 1; m <= 8; m <<= 1) {
        #pragma unroll
        for (int i = 0; i < 4; ++i) p[i] += __shfl_xor(p[i], m, 64);
    }
    if (tx == 0) {
        float b2 = eb2[st];
        #pragma unroll
        for (int i = 0; i < 4; ++i) {
            int n = n0 + r0 + i;
            if (n < N) atomicAdd(&energies[batch[n] * S + st], p[i] + b2);
        }
    }
}

// ---------------------------------------------------------------- dipole / nac heads
__global__ void k_vec(const float* __restrict__ v, const float* __restrict__ dipole_w,
                      const float* __restrict__ nac_w, const int* __restrict__ batch,
                      float* __restrict__ dipoles, float* __restrict__ nac, int N)
{
    int n = blockIdx.x * 4 + (threadIdx.x >> 6);
    int lane = threadIdx.x & 63;
    if (n >= N) return;
    float pd[3] = {0.f, 0.f, 0.f};
    float pn[3][3] = {{0.f}};
    const float* vb = v + (size_t)n * 3 * FDIM;
    for (int f = lane; f < FDIM; f += 64) {
        float v0 = vb[f], v1 = vb[FDIM + f], v2 = vb[2*FDIM + f];
        float wd = dipole_w[f];
        pd[0] += wd * v0; pd[1] += wd * v1; pd[2] += wd * v2;
        #pragma unroll
        for (int p = 0; p < 3; ++p) {
            float wn = nac_w[p * FDIM + f];
            pn[p][0] += wn * v0; pn[p][1] += wn * v1; pn[p][2] += wn * v2;
        }
    }
    #pragma unroll
    for (int d = 32; d > 0; d >>= 1) {
        #pragma unroll
        for (int k = 0; k < 3; ++k) pd[k] += __shfl_down(pd[k], d, 64);
        #pragma unroll
        for (int p = 0; p < 3; ++p)
            #pragma unroll
            for (int k = 0; k < 3; ++k) pn[p][k] += __shfl_down(pn[p][k], d, 64);
    }
    if (lane == 0) {
        int m = batch[n];
        #pragma unroll
        for (int k = 0; k < 3; ++k) atomicAdd(&dipoles[m * 3 + k], pd[k]);
        #pragma unroll
        for (int p = 0; p < 3; ++p)
            #pragma unroll
            for (int k = 0; k < 3; ++k) atomicAdd(&nac[(m * 3 + p) * 3 + k], pn[p][k]);
    }
}

// ---------------------------------------------------------------- per-molecule heads
__global__ __launch_bounds__(128) void k_heads(
    const float* __restrict__ aw1, const float* __restrict__ ab1,
    const float* __restrict__ aw2, const float* __restrict__ ab2,
    const float* __restrict__ yw1, const float* __restrict__ yb1,
    const float* __restrict__ yw2, const float* __restrict__ yb2,
    const float* __restrict__ energies, const float* __restrict__ nac,
    float* __restrict__ lam, float* __restrict__ phi_y, int M, int S)
{
    __shared__ float sh_in[8];
    __shared__ float sh_red[2];
    int m = blockIdx.x;
    if (m >= M) return;
    int tid = threadIdx.x;
    if (tid == 0) {
        float e0 = energies[m * S];
        for (int j = 0; j < 3; ++j) sh_in[j] = energies[m * S + 1 + j] - e0;
        for (int p = 0; p < 3; ++p) {
            float a = nac[(m * 3 + p) * 3 + 0];
            float b = nac[(m * 3 + p) * 3 + 1];
            float c = nac[(m * 3 + p) * 3 + 2];
            sh_in[3 + p] = sqrtf(a*a + b*b + c*c + 1e-12f);
        }
    }
    __syncthreads();
    float pa = 0.f;
    if (tid < 64) {
        float h = ab1[tid];
        #pragma unroll
        for (int j = 0; j < 3; ++j) h += sh_in[j] * aw1[j * 64 + tid];
        pa = siluf(h) * aw2[tid];
    }
    float h2 = yb1[tid];
    #pragma unroll
    for (int j = 0; j < 6; ++j) h2 += sh_in[j] * yw1[j * 128 + tid];
    float py = siluf(h2) * yw2[tid];
    #pragma unroll
    for (int d = 32; d > 0; d >>= 1) {
        pa += __shfl_down(pa, d, 64);
        py += __shfl_down(py, d, 64);
    }
    int wid = tid >> 6, lane = tid & 63;
    if (lane == 0) sh_red[wid] = py;
    __syncthreads();
    if (tid == 0) {
        lam[m] = pa + ab2[0];
        float yt = sh_red[0] + sh_red[1] + yb2[0];
        phi_y[m] = 1.f / (1.f + __expf(-yt));
    }
}

// ---------------------------------------------------------------- launch
extern "C" void kernel_launch(void* const* d_in, const int* in_sizes, int n_in,
                              void* d_out, int out_size, void* d_ws, size_t ws_size,
                              hipStream_t stream)
{
    const int*   z        = (const int*)  d_in[0];
    const float* pos      = (const float*)d_in[1];
    const int*   eidx     = (const int*)  d_in[2];
    const int*   batch    = (const int*)  d_in[3];
    const float* emb      = (const float*)d_in[5];
    const float* centers  = (const float*)d_in[6];
    const float* gamma    = (const float*)d_in[7];
    const float* fw1      = (const float*)d_in[8];
    const float* fb1      = (const float*)d_in[9];
    const float* fw2      = (const float*)d_in[10];
    const float* fb2      = (const float*)d_in[11];
    const float* uw1      = (const float*)d_in[12];
    const float* ub1      = (const float*)d_in[13];
    const float* uw2      = (const float*)d_in[14];
    const float* ub2      = (const float*)d_in[15];
    const float* ew1      = (const float*)d_in[16];
    const float* eb1      = (const float*)d_in[17];
    const float* ew2      = (const float*)d_in[18];
    const float* eb2      = (const float*)d_in[19];
    const float* dipole_w = (const float*)d_in[20];
    const float* nac_w    = (const float*)d_in[21];
    const float* aw1      = (const float*)d_in[22];
    const float* ab1      = (const float*)d_in[23];
    const float* aw2      = (const float*)d_in[24];
    const float* ab2      = (const float*)d_in[25];
    const float* yw1      = (const float*)d_in[26];
    const float* yb1      = (const float*)d_in[27];
    const float* yw2      = (const float*)d_in[28];
    const float* yb2      = (const float*)d_in[29];

    const int N = in_sizes[0];
    const int E = in_sizes[2] / 2;
    const int S = in_sizes[19];
    const int P = in_sizes[21] / FDIM;
    const int L = in_sizes[9] / FDIM;
    const int M = out_size / (S + 3 + P * 3 + 2);

    const size_t NF = (size_t)N * FDIM;
    float*  s    = (float*)d_ws;                 // NF
    float*  v    = s + NF;                       // 3 NF
    float*  m_s  = v + 3 * NF;                   // NF   (aliased by u1)
    float*  m_v  = m_s + NF;                     // 3 NF
    __half* s_h  = (__half*)(m_v + 3 * NF);      // NF halves
    __half* v_h  = s_h + NF;                     // 3 NF halves
    __half* tab  = v_h + 3 * NF;                 // L * (TAB_T+1) * 384 halves
    int* rowstart = (int*)(tab + (size_t)L * (TAB_T + 1) * 384);
    int* cursor   = rowstart + (N + 1);
    int* esort    = cursor + N;
    float* u1 = m_s;   // safe alias: block-local row panels, m_s fully consumed before u1 written

    float* out      = (float*)d_out;
    float* energies = out;
    float* dipoles  = energies + (size_t)M * S;
    float* nac      = dipoles  + (size_t)M * 3;
    float* lam      = nac      + (size_t)M * P * 3;
    float* phi_y    = lam      + M;

    const int* erow = eidx;
    const int* ecol = eidx + E;

    const float step = TAB_RANGE / (float)TAB_T;
    const float inv_step = (float)TAB_T / TAB_RANGE;
    const int NB = (N + 63) / 64;

    hipMemsetAsync(d_out, 0, (size_t)out_size * sizeof(float), stream);
    hipMemsetAsync(cursor, 0, (size_t)N * sizeof(int), stream);
    k_hist<<<(E + 255) / 256, 256, 0, stream>>>(erow, cursor, E);
    k_scan<<<1, 256, 0, stream>>>(cursor, rowstart, N);
    k_fill<<<(E + 255) / 256, 256, 0, stream>>>(erow, cursor, esort, E);
    k_init<<<(N * FDIM + 255) / 256, 256, 0, stream>>>(z, emb, s, v, s_h, v_h, N);

    // all layers' tables in one dispatch (out of the serial layer loop)
    const int tab_blocks = (TAB_T + 1 + 31) / 32;
    k_table<<<dim3(tab_blocks, L), TH, 0, stream>>>(centers, gamma, fw1, fb1, fw2, fb2, tab, step);

    for (int l = 0; l < L; ++l) {
        const __half* tab_l = tab + (size_t)l * (TAB_T + 1) * 384;
        k_gather<<<N, 128, 0, stream>>>(
            pos, ecol, rowstart, esort, tab_l, s_h, v_h, m_s, m_v, inv_step, (l > 0) ? 1 : 0, N);
        k_mlp1<<<NB, 256, 0, stream>>>(
            s, m_s, m_v, uw1 + (size_t)l * 3 * FDIM * FDIM, ub1 + (size_t)l * FDIM, u1, N);
        k_mlp2<<<NB, 256, 0, stream>>>(
            u1, uw2 + (size_t)l * FDIM * 3 * FDIM, ub2 + (size_t)l * 3 * FDIM,
            s, v, m_v, s_h, v_h, N);
    }

    k_energy2<<<dim3(NB, S), 256, 0, stream>>>(ew1, eb1, ew2, eb2, s, batch, energies, N, S);
    k_vec<<<(N + 3) / 4, 256, 0, stream>>>(v, dipole_w, nac_w, batch, dipoles, nac, N);
    k_heads<<<M, 128, 0, stream>>>(aw1, ab1, aw2, ab2, yw1, yb1, yw2, yb2,
                                   energies, nac, lam, phi_y, M, S);
}

// Round 7
// 649.581 us; speedup vs baseline: 26.4649x; 1.1204x over previous
//
#include <hip/hip_runtime.h>
#include <hip/hip_fp16.h>

#define FDIM 128
#define RDIM 20

#define TAB_T 2048              // table cells; TAB_T+1 rows
#define TAB_RANGE 12.0f

constexpr int TH = 256;

__device__ __forceinline__ float siluf(float x) { return x / (1.f + __expf(-x)); }

__device__ __forceinline__ void store_h4(__half* p, float a, float b, float c, float d) {
    __half h[4] = {__float2half(a), __float2half(b), __float2half(c), __float2half(d)};
    *(uint2*)p = *(uint2*)h;
}

// ---------------------------------------------------------------- init: s = emb[z], v = 0
// v layout: [N][3][FDIM]
__global__ void k_init(const int* __restrict__ z, const float* __restrict__ emb,
                       float* __restrict__ s, float* __restrict__ v,
                       __half* __restrict__ s_h, __half* __restrict__ v_h, int N) {
    int i = blockIdx.x * blockDim.x + threadIdx.x;
    if (i >= N * FDIM) return;
    int n = i >> 7, f = i & 127;
    float val = emb[z[n] * FDIM + f];
    s[i] = val;
    s_h[i] = __float2half(val);
    size_t nf = (size_t)N * FDIM;
    v[i] = 0.f; v[i + nf] = 0.f; v[i + 2 * nf] = 0.f;
    __half hz = __float2half(0.f);
    v_h[i] = hz; v_h[i + nf] = hz; v_h[i + 2 * nf] = hz;
}

// ---------------------------------------------------------------- CSR build
__global__ void k_hist(const int* __restrict__ erow, int* __restrict__ cursor, int E) {
    int e = blockIdx.x * blockDim.x + threadIdx.x;
    if (e < E) atomicAdd(&cursor[erow[e]], 1);
}

// hierarchical scan: phase 1 — per-block exclusive scan + block sums
__global__ __launch_bounds__(256) void k_scan1(const int* __restrict__ cursor,
                                               int* __restrict__ rowstart,
                                               int* __restrict__ bsum, int N) {
    __shared__ int sh[256];
    int tid = threadIdx.x;
    int idx = blockIdx.x * 256 + tid;
    int x = (idx < N) ? cursor[idx] : 0;
    sh[tid] = x;
    __syncthreads();
    #pragma unroll
    for (int off = 1; off < 256; off <<= 1) {
        int t = (tid >= off) ? sh[tid - off] : 0;
        __syncthreads();
        sh[tid] += t;
        __syncthreads();
    }
    if (idx < N) rowstart[idx] = sh[tid] - x;    // local exclusive
    if (tid == 255) bsum[blockIdx.x] = sh[255];  // block total
}

// phase 2 — single block scans the block sums (nb <= a few hundred), writes rowstart[N]
__global__ __launch_bounds__(256) void k_scan2(int* __restrict__ bsum,
                                               int* __restrict__ rowstart, int nb, int N) {
    __shared__ int sh[256];
    __shared__ int carry;
    int tid = threadIdx.x;
    if (tid == 0) carry = 0;
    __syncthreads();
    for (int base = 0; base < nb; base += 256) {
        int idx = base + tid;
        int x = (idx < nb) ? bsum[idx] : 0;
        sh[tid] = x;
        __syncthreads();
        #pragma unroll
        for (int off = 1; off < 256; off <<= 1) {
            int t = (tid >= off) ? sh[tid - off] : 0;
            __syncthreads();
            sh[tid] += t;
            __syncthreads();
        }
        if (idx < nb) bsum[idx] = carry + sh[tid] - x;   // exclusive
        __syncthreads();
        if (tid == 0) carry += sh[255];
        __syncthreads();
    }
    if (tid == 0) rowstart[N] = carry;
}

// phase 3 — add block offsets, init cursor
__global__ __launch_bounds__(256) void k_scan3(int* __restrict__ rowstart,
                                               int* __restrict__ cursor,
                                               const int* __restrict__ bsum, int N) {
    int idx = blockIdx.x * 256 + threadIdx.x;
    if (idx < N) {
        int val = rowstart[idx] + bsum[blockIdx.x];
        rowstart[idx] = val;
        cursor[idx] = val;
    }
}

__global__ void k_fill(const int* __restrict__ erow, int* __restrict__ cursor,
                       int* __restrict__ esort, int E) {
    int e = blockIdx.x * blockDim.x + threadIdx.x;
    if (e < E) {
        int p = atomicAdd(&cursor[erow[e]], 1);
        esort[p] = e;
    }
}

// ---------------------------------------------------------------- filter-MLP table build (all layers, fp16 out)
__global__ __launch_bounds__(TH) void k_table(
    const float* __restrict__ centers, const float* __restrict__ gamma,
    const float* __restrict__ fw1b, const float* __restrict__ fb1b,
    const float* __restrict__ fw2b, const float* __restrict__ fb2b,
    __half* __restrict__ tabb, float step)
{
    __shared__ float sh_rbf[32][RDIM];
    __shared__ float sh_ht[FDIM][33];
    __shared__ float sh_w[32][3 * FDIM + 4];

    const int l   = blockIdx.y;
    const float* fw1 = fw1b + (size_t)l * RDIM * FDIM;
    const float* fb1 = fb1b + (size_t)l * FDIM;
    const float* fw2 = fw2b + (size_t)l * FDIM * 3 * FDIM;
    const float* fb2 = fb2b + (size_t)l * 3 * FDIM;
    __half* tab = tabb + (size_t)l * (TAB_T + 1) * 384;

    const int p0  = blockIdx.x * 32;
    const int tid = threadIdx.x;

    for (int i = tid; i < 32 * RDIM; i += TH) {
        int p = i / RDIM, r = i - p * RDIM;
        float d = (float)(p0 + p) * step - centers[r];
        sh_rbf[p][r] = __expf(-gamma[r] * d * d);
    }
    __syncthreads();
    for (int i = tid; i < 32 * FDIM; i += TH) {
        int p = i >> 7, f = i & 127;
        float acc = fb1[f];
        #pragma unroll
        for (int r = 0; r < RDIM; ++r) acc += sh_rbf[p][r] * fw1[r * FDIM + f];
        sh_ht[f][p] = siluf(acc);
    }

    const int eq = tid & 7;
    const int fq = tid >> 3;
    const int f0 = fq * 4;

    float pg[3][4][4];
    #pragma unroll
    for (int g3 = 0; g3 < 3; ++g3)
        #pragma unroll
        for (int ee = 0; ee < 4; ++ee)
            #pragma unroll
            for (int i = 0; i < 4; ++i) pg[g3][ee][i] = fb2[g3 * FDIM + f0 + i];

    const int kkr = tid >> 3;
    const int t8  = tid & 7;
    for (int kc = 0; kc < 4; ++kc) {
        __syncthreads();
        #pragma unroll
        for (int j = 0; j < 12; ++j) {
            int g = (t8 * 12 + j) * 4;
            float4 w4 = *(const float4*)&fw2[(size_t)(kc * 32 + kkr) * (3 * FDIM) + g];
            *(float4*)&sh_w[kkr][g] = w4;
        }
        __syncthreads();
        #pragma unroll 4
        for (int kk = 0; kk < 32; ++kk) {
            float hv[4];
            #pragma unroll
            for (int ee = 0; ee < 4; ++ee) hv[ee] = sh_ht[kc * 32 + kk][4 * eq + ee];
            #pragma unroll
            for (int g3 = 0; g3 < 3; ++g3) {
                float4 w4 = *(const float4*)&sh_w[kk][g3 * FDIM + f0];
                #pragma unroll
                for (int ee = 0; ee < 4; ++ee) {
                    pg[g3][ee][0] += hv[ee] * w4.x;
                    pg[g3][ee][1] += hv[ee] * w4.y;
                    pg[g3][ee][2] += hv[ee] * w4.z;
                    pg[g3][ee][3] += hv[ee] * w4.w;
                }
            }
        }
    }

    #pragma unroll
    for (int ee = 0; ee < 4; ++ee) {
        int pt = p0 + 4 * eq + ee;
        if (pt <= TAB_T) {
            #pragma unroll
            for (int g3 = 0; g3 < 3; ++g3)
                store_h4(&tab[(size_t)pt * 384 + g3 * FDIM + f0],
                         pg[g3][ee][0], pg[g3][ee][1], pg[g3][ee][2], pg[g3][ee][3]);
        }
    }
}

// ---------------------------------------------------------------- gather message kernel (fp16 inputs)
__global__ __launch_bounds__(128) void k_gather(
    const float* __restrict__ pos, const int* __restrict__ ecol,
    const int* __restrict__ rowstart, const int* __restrict__ esort,
    const __half* __restrict__ tab, const __half* __restrict__ s_h,
    const __half* __restrict__ v_h,
    float* __restrict__ m_s, float* __restrict__ m_v, float inv_step, int withv, int N)
{
    __shared__ int   sh_col[32];
    __shared__ int   sh_t0[32];
    __shared__ float sh_w[32];
    __shared__ float sh_d0[32], sh_d1[32], sh_d2[32];

    const int n   = blockIdx.x;
    const int tid = threadIdx.x;
    const int lo  = rowstart[n], hi = rowstart[n + 1];

    float acc_s = 0.f, av0 = 0.f, av1 = 0.f, av2 = 0.f;
    const float px = pos[n * 3 + 0], py = pos[n * 3 + 1], pz = pos[n * 3 + 2];

    for (int base = lo; base < hi; base += 32) {
        const int ne = min(32, hi - base);
        __syncthreads();
        if (tid < 32) {
            if (tid < ne) {
                int e  = esort[base + tid];
                int cl = ecol[e];
                float dx = pos[cl*3+0] - px;
                float dy = pos[cl*3+1] - py;
                float dz = pos[cl*3+2] - pz;
                float dist = sqrtf(dx*dx + dy*dy + dz*dz + 1e-12f);
                float inv = 1.f / (dist + 1e-8f);
                sh_col[tid] = cl;
                sh_d0[tid] = dx*inv; sh_d1[tid] = dy*inv; sh_d2[tid] = dz*inv;
                float u = fminf(dist * inv_step, (float)TAB_T);
                int t0 = min((int)u, TAB_T - 1);
                sh_t0[tid] = t0;
                sh_w[tid]  = u - (float)t0;
            } else {
                sh_col[tid] = 0; sh_t0[tid] = 0; sh_w[tid] = 0.f;
                sh_d0[tid] = sh_d1[tid] = sh_d2[tid] = 0.f;
            }
        }
        __syncthreads();
        if (withv) {
            #pragma unroll 2
            for (int el = 0; el < ne; ++el) {
                int   cl = sh_col[el];
                int   t0 = sh_t0[el];
                float w  = sh_w[el];
                const __half* ta = tab + (size_t)t0 * 384 + tid;
                float a_ss = __half2float(ta[0]),   b_ss = __half2float(ta[384]);
                float a_vv = __half2float(ta[128]), b_vv = __half2float(ta[512]);
                float a_sv = __half2float(ta[256]), b_sv = __half2float(ta[640]);
                float pss = a_ss + w * (b_ss - a_ss);
                float pvv = a_vv + w * (b_vv - a_vv);
                float psv = a_sv + w * (b_sv - a_sv);
                float sc = __half2float(s_h[(size_t)cl * FDIM + tid]);
                const __half* vp = v_h + (size_t)cl * 3 * FDIM + tid;
                float svs = psv * sc;
                acc_s += pss * sc;
                av0 += pvv * __half2float(vp[0])        + svs * sh_d0[el];
                av1 += pvv * __half2float(vp[FDIM])     + svs * sh_d1[el];
                av2 += pvv * __half2float(vp[2*FDIM])   + svs * sh_d2[el];
            }
        } else {
            #pragma unroll 2
            for (int el = 0; el < ne; ++el) {
                int   cl = sh_col[el];
                int   t0 = sh_t0[el];
                float w  = sh_w[el];
                const __half* ta = tab + (size_t)t0 * 384 + tid;
                float a_ss = __half2float(ta[0]),   b_ss = __half2float(ta[384]);
                float a_sv = __half2float(ta[256]), b_sv = __half2float(ta[640]);
                float pss = a_ss + w * (b_ss - a_ss);
                float psv = a_sv + w * (b_sv - a_sv);
                float sc = __half2float(s_h[(size_t)cl * FDIM + tid]);
                float svs = psv * sc;
                acc_s += pss * sc;
                av0 += svs * sh_d0[el];
                av1 += svs * sh_d1[el];
                av2 += svs * sh_d2[el];
            }
        }
    }

    m_s[(size_t)n * FDIM + tid] = acc_s;
    float* mv = m_v + (size_t)n * 3 * FDIM + tid;
    mv[0] = av0; mv[FDIM] = av1; mv[2*FDIM] = av2;
}

// ---------------------------------------------------------------- GEMM 1: u1 = silu(X @ uw1 + ub1)
// X = [s | m_s | ||m_v||]. Tile 64x128, 256 thr, 4x8 micro, K=384.
// Software-pipelined: next K-tile loaded into registers while current computes.
__global__ __launch_bounds__(256) void k_mlp1(
    const float* __restrict__ s, const float* __restrict__ m_s, const float* __restrict__ m_v,
    const float* __restrict__ uw1, const float* __restrict__ ub1,
    float* __restrict__ u1, int N)
{
    __shared__ float shA[16][68];    // [kk][row]
    __shared__ float shB[16][132];   // [kk][col]

    const int tid = threadIdx.x;
    const int n0  = blockIdx.x * 64;
    const int tx  = tid & 15, ty = tid >> 4;
    const int cA  = tx * 4, cB = 64 + tx * 4;
    const int r0  = ty * 4;
    const int rs  = tid >> 2;           // staging row 0..63
    const int k4  = (tid & 3) * 4;      // staging k offset
    const int bk  = tid >> 5;           // B staging row 0..7
    const int bc4 = (tid & 31) * 4;     // B staging col

    float acc[4][8];
    {
        float4 bA = *(const float4*)&ub1[cA];
        float4 bB = *(const float4*)&ub1[cB];
        #pragma unroll
        for (int i = 0; i < 4; ++i) {
            acc[i][0]=bA.x; acc[i][1]=bA.y; acc[i][2]=bA.z; acc[i][3]=bA.w;
            acc[i][4]=bB.x; acc[i][5]=bB.y; acc[i][6]=bB.z; acc[i][7]=bB.w;
        }
    }

    float4 pa, pay, paz, pb0, pb1;

#define MLP1_LOAD(kc) do { \
        int kg = (kc) * 16 + k4; int n = n0 + rs; \
        pa = make_float4(0.f,0.f,0.f,0.f); \
        pay = make_float4(0.f,0.f,0.f,0.f); paz = make_float4(0.f,0.f,0.f,0.f); \
        if (n < N) { \
            if (kg < 128) { pa = *(const float4*)&s[(size_t)n * FDIM + kg]; } \
            else if (kg < 256) { pa = *(const float4*)&m_s[(size_t)n * FDIM + kg - 128]; } \
            else { const float* mvp = m_v + (size_t)n * 3 * FDIM + (kg - 256); \
                   pa = *(const float4*)&mvp[0]; \
                   pay = *(const float4*)&mvp[FDIM]; \
                   paz = *(const float4*)&mvp[2*FDIM]; } \
        } \
        pb0 = *(const float4*)&uw1[(size_t)((kc)*16 + bk) * FDIM + bc4]; \
        pb1 = *(const float4*)&uw1[(size_t)((kc)*16 + 8 + bk) * FDIM + bc4]; \
    } while (0)

    MLP1_LOAD(0);
    for (int kc = 0; kc < 24; ++kc) {
        __syncthreads();
        // store current regs -> LDS
        {
            int kg = kc * 16 + k4;
            float4 a = pa;
            if (kg >= 256) {
                a.x = sqrtf(pa.x*pa.x + pay.x*pay.x + paz.x*paz.x + 1e-12f);
                a.y = sqrtf(pa.y*pa.y + pay.y*pay.y + paz.y*paz.y + 1e-12f);
                a.z = sqrtf(pa.z*pa.z + pay.z*pay.z + paz.z*paz.z + 1e-12f);
                a.w = sqrtf(pa.w*pa.w + pay.w*pay.w + paz.w*paz.w + 1e-12f);
            }
            shA[k4+0][rs] = a.x; shA[k4+1][rs] = a.y;
            shA[k4+2][rs] = a.z; shA[k4+3][rs] = a.w;
            *(float4*)&shB[bk][bc4]     = pb0;
            *(float4*)&shB[8 + bk][bc4] = pb1;
        }
        // prefetch next tile (latency hides under compute below)
        if (kc + 1 < 24) MLP1_LOAD(kc + 1);
        __syncthreads();
        #pragma unroll
        for (int kk = 0; kk < 16; ++kk) {
            float4 a4 = *(const float4*)&shA[kk][r0];
            float4 b0 = *(const float4*)&shB[kk][cA];
            float4 b1 = *(const float4*)&shB[kk][cB];
            float av[4] = {a4.x, a4.y, a4.z, a4.w};
            #pragma unroll
            for (int i = 0; i < 4; ++i) {
                acc[i][0] += av[i]*b0.x; acc[i][1] += av[i]*b0.y;
                acc[i][2] += av[i]*b0.z; acc[i][3] += av[i]*b0.w;
                acc[i][4] += av[i]*b1.x; acc[i][5] += av[i]*b1.y;
                acc[i][6] += av[i]*b1.z; acc[i][7] += av[i]*b1.w;
            }
        }
    }
#undef MLP1_LOAD

    #pragma unroll
    for (int i = 0; i < 4; ++i) {
        int n = n0 + r0 + i;
        if (n < N) {
            float4 oA = make_float4(siluf(acc[i][0]), siluf(acc[i][1]), siluf(acc[i][2]), siluf(acc[i][3]));
            float4 oB = make_float4(siluf(acc[i][4]), siluf(acc[i][5]), siluf(acc[i][6]), siluf(acc[i][7]));
            *(float4*)&u1[(size_t)n * FDIM + cA] = oA;
            *(float4*)&u1[(size_t)n * FDIM + cB] = oB;
        }
    }
}

// ---------------------------------------------------------------- GEMM 2: upd = u1 @ uw2 + ub2, fused apply
__global__ __launch_bounds__(256) void k_mlp2(
    const float* __restrict__ u1, const float* __restrict__ uw2, const float* __restrict__ ub2,
    float* __restrict__ s, float* __restrict__ v, const float* __restrict__ m_v,
    __half* __restrict__ s_h, __half* __restrict__ v_h, int N)
{
    __shared__ float shU[64][132];
    __shared__ float shB[16][132];

    const int tid = threadIdx.x;
    const int n0  = blockIdx.x * 64;
    const int tx  = tid & 15, ty = tid >> 4;
    const int cA  = tx * 4, cB = 64 + tx * 4;
    const int r0  = ty * 4;
    const int bk  = tid >> 5;
    const int bc4 = (tid & 31) * 4;

    // stage u1 tile (64 x 128) once
    #pragma unroll
    for (int it = 0; it < 8; ++it) {
        int idx = it * 256 + tid;
        int row = idx >> 5;
        int c4  = (idx & 31) * 4;
        int n = n0 + row;
        float4 a = make_float4(0.f,0.f,0.f,0.f);
        if (n < N) a = *(const float4*)&u1[(size_t)n * FDIM + c4];
        *(float4*)&shU[row][c4] = a;
    }

    float4 pb0, pb1;
#define MLP2_LOADB(g, kc) do { \
        pb0 = *(const float4*)&uw2[(size_t)((kc)*16 + bk) * (3*FDIM) + (g) * FDIM + bc4]; \
        pb1 = *(const float4*)&uw2[(size_t)((kc)*16 + 8 + bk) * (3*FDIM) + (g) * FDIM + bc4]; \
    } while (0)

    MLP2_LOADB(0, 0);
    float alpha[4][8];

    for (int g = 0; g < 3; ++g) {
        float acc2[4][8];
        {
            float4 bA = *(const float4*)&ub2[g * FDIM + cA];
            float4 bB = *(const float4*)&ub2[g * FDIM + cB];
            #pragma unroll
            for (int i = 0; i < 4; ++i) {
                acc2[i][0]=bA.x; acc2[i][1]=bA.y; acc2[i][2]=bA.z; acc2[i][3]=bA.w;
                acc2[i][4]=bB.x; acc2[i][5]=bB.y; acc2[i][6]=bB.z; acc2[i][7]=bB.w;
            }
        }
        for (int kc = 0; kc < 8; ++kc) {
            __syncthreads();
            *(float4*)&shB[bk][bc4]     = pb0;
            *(float4*)&shB[8 + bk][bc4] = pb1;
            if (kc + 1 < 8)      MLP2_LOADB(g, kc + 1);
            else if (g + 1 < 3)  MLP2_LOADB(g + 1, 0);   // overlaps this gate's epilogue too
            __syncthreads();
            #pragma unroll
            for (int kk = 0; kk < 16; ++kk) {
                int col = kc * 16 + kk;
                float4 b0 = *(const float4*)&shB[kk][cA];
                float4 b1 = *(const float4*)&shB[kk][cB];
                #pragma unroll
                for (int i = 0; i < 4; ++i) {
                    float uv = shU[r0 + i][col];
                    acc2[i][0] += uv*b0.x; acc2[i][1] += uv*b0.y;
                    acc2[i][2] += uv*b0.z; acc2[i][3] += uv*b0.w;
                    acc2[i][4] += uv*b1.x; acc2[i][5] += uv*b1.y;
                    acc2[i][6] += uv*b1.z; acc2[i][7] += uv*b1.w;
                }
            }
        }

        if (g == 0) {
            #pragma unroll
            for (int i = 0; i < 4; ++i) {
                int n = n0 + r0 + i;
                if (n < N) {
                    float4 s0 = *(const float4*)&s[(size_t)n * FDIM + cA];
                    float4 s1 = *(const float4*)&s[(size_t)n * FDIM + cB];
                    s0.x += acc2[i][0]; s0.y += acc2[i][1]; s0.z += acc2[i][2]; s0.w += acc2[i][3];
                    s1.x += acc2[i][4]; s1.y += acc2[i][5]; s1.z += acc2[i][6]; s1.w += acc2[i][7];
                    *(float4*)&s[(size_t)n * FDIM + cA] = s0;
                    *(float4*)&s[(size_t)n * FDIM + cB] = s1;
                    store_h4(&s_h[(size_t)n * FDIM + cA], s0.x, s0.y, s0.z, s0.w);
                    store_h4(&s_h[(size_t)n * FDIM + cB], s1.x, s1.y, s1.z, s1.w);
                }
            }
        } else if (g == 1) {
            #pragma unroll
            for (int i = 0; i < 4; ++i)
                #pragma unroll
                for (int j = 0; j < 8; ++j) alpha[i][j] = acc2[i][j];
        } else {
            #pragma unroll
            for (int i = 0; i < 4; ++i) {
                int n = n0 + r0 + i;
                if (n < N) {
                    #pragma unroll
                    for (int k = 0; k < 3; ++k) {
                        float* vp = v + ((size_t)n * 3 + k) * FDIM;
                        const float* mp = m_v + ((size_t)n * 3 + k) * FDIM;
                        __half* vhp = v_h + ((size_t)n * 3 + k) * FDIM;
                        float4 v0 = *(const float4*)&vp[cA];
                        float4 v1 = *(const float4*)&vp[cB];
                        float4 m0 = *(const float4*)&mp[cA];
                        float4 m1 = *(const float4*)&mp[cB];
                        v0.x = alpha[i][0]*v0.x + acc2[i][0]*m0.x;
                        v0.y = alpha[i][1]*v0.y + acc2[i][1]*m0.y;
                        v0.z = alpha[i][2]*v0.z + acc2[i][2]*m0.z;
                        v0.w = alpha[i][3]*v0.w + acc2[i][3]*m0.w;
                        v1.x = alpha[i][4]*v1.x + acc2[i][4]*m1.x;
                        v1.y = alpha[i][5]*v1.y + acc2[i][5]*m1.y;
                        v1.z = alpha[i][6]*v1.z + acc2[i][6]*m1.z;
                        v1.w = alpha[i][7]*v1.w + acc2[i][7]*m1.w;
                        *(float4*)&vp[cA] = v0;
                        *(float4*)&vp[cB] = v1;
                        store_h4(&vhp[cA], v0.x, v0.y, v0.z, v0.w);
                        store_h4(&vhp[cB], v1.x, v1.y, v1.z, v1.w);
                    }
                }
            }
        }
    }
#undef MLP2_LOADB
}

// ---------------------------------------------------------------- energy head GEMM
__global__ __launch_bounds__(256) void k_energy2(
    const float* __restrict__ ew1, const float* __restrict__ eb1,
    const float* __restrict__ ew2, const float* __restrict__ eb2,
    const float* __restrict__ s, const int* __restrict__ batch,
    float* __restrict__ energies, int N, int S)
{
    __shared__ float shA[16][68];
    __shared__ float shB[16][132];

    const int tid = threadIdx.x;
    const int n0  = blockIdx.x * 64;
    const int st  = blockIdx.y;
    const int tx  = tid & 15, ty = tid >> 4;
    const int cA  = tx * 4, cB = 64 + tx * 4;
    const int r0  = ty * 4;
    const int rs  = tid >> 2;
    const int k4  = (tid & 3) * 4;

    float acc[4][8];
    {
        float4 bA = *(const float4*)&eb1[st * FDIM + cA];
        float4 bB = *(const float4*)&eb1[st * FDIM + cB];
        #pragma unroll
        for (int i = 0; i < 4; ++i) {
            acc[i][0]=bA.x; acc[i][1]=bA.y; acc[i][2]=bA.z; acc[i][3]=bA.w;
            acc[i][4]=bB.x; acc[i][5]=bB.y; acc[i][6]=bB.z; acc[i][7]=bB.w;
        }
    }

    for (int kc = 0; kc < 8; ++kc) {
        __syncthreads();
        {
            int kg = kc * 16 + k4;
            int n  = n0 + rs;
            float4 a = make_float4(0.f, 0.f, 0.f, 0.f);
            if (n < N) a = *(const float4*)&s[(size_t)n * FDIM + kg];
            shA[k4+0][rs] = a.x; shA[k4+1][rs] = a.y; shA[k4+2][rs] = a.z; shA[k4+3][rs] = a.w;
        }
        #pragma unroll
        for (int i = 0; i < 2; ++i) {
            int idx = tid + i * 256;
            int kk = idx >> 5;
            int c4 = (idx & 31) * 4;
            *(float4*)&shB[kk][c4] =
                *(const float4*)&ew1[(size_t)st * FDIM * FDIM + (size_t)(kc*16+kk) * FDIM + c4];
        }
        __syncthreads();
        #pragma unroll
        for (int kk = 0; kk < 16; ++kk) {
            float4 a4 = *(const float4*)&shA[kk][r0];
            float4 b0 = *(const float4*)&shB[kk][cA];
            float4 b1 = *(const float4*)&shB[kk][cB];
            float av[4] = {a4.x, a4.y, a4.z, a4.w};
            #pragma unroll
            for (int i = 0; i < 4; ++i) {
                acc[i][0] += av[i]*b0.x; acc[i][1] += av[i]*b0.y;
                acc[i][2] += av[i]*b0.z; acc[i][3] += av[i]*b0.w;
                acc[i][4] += av[i]*b1.x; acc[i][5] += av[i]*b1.y;
                acc[i][6] += av[i]*b1.z; acc[i][7] += av[i]*b1.w;
            }
        }
    }

    float4 wA = *(const float4*)&ew2[st * FDIM + cA];
    float4 wB = *(const float4*)&ew2[st * FDIM + cB];
    float p[4];
    #pragma unroll
    for (int i = 0; i < 4; ++i) {
        p[i]  = siluf(acc[i][0])*wA.x + siluf(acc[i][1])*wA.y
              + siluf(acc[i][2])*wA.z + siluf(acc[i][3])*wA.w;
        p[i] += siluf(acc[i][4])*wB.x + siluf(acc[i][5])*wB.y
              + siluf(acc[i][6])*wB.z + siluf(acc[i][7])*wB.w;
    }
    #pragma unroll
    for (int m = 1; m <= 8; m <<= 1) {
        #pragma unroll
        for (int i = 0; i < 4; ++i) p[i] += __shfl_xor(p[i], m, 64);
    }
    if (tx == 0) {
        float b2 = eb2[st];
        #pragma unroll
        for (int i = 0; i < 4; ++i) {
            int n = n0 + r0 + i;
            if (n < N) atomicAdd(&energies[batch[n] * S + st], p[i] + b2);
        }
    }
}

// ---------------------------------------------------------------- dipole / nac heads
__global__ void k_vec(const float* __restrict__ v, const float* __restrict__ dipole_w,
                      const float* __restrict__ nac_w, const int* __restrict__ batch,
                      float* __restrict__ dipoles, float* __restrict__ nac, int N)
{
    int n = blockIdx.x * 4 + (threadIdx.x >> 6);
    int lane = threadIdx.x & 63;
    if (n >= N) return;
    float pd[3] = {0.f, 0.f, 0.f};
    float pn[3][3] = {{0.f}};
    const float* vb = v + (size_t)n * 3 * FDIM;
    for (int f = lane; f < FDIM; f += 64) {
        float v0 = vb[f], v1 = vb[FDIM + f], v2 = vb[2*FDIM + f];
        float wd = dipole_w[f];
        pd[0] += wd * v0; pd[1] += wd * v1; pd[2] += wd * v2;
        #pragma unroll
        for (int p = 0; p < 3; ++p) {
            float wn = nac_w[p * FDIM + f];
            pn[p][0] += wn * v0; pn[p][1] += wn * v1; pn[p][2] += wn * v2;
        }
    }
    #pragma unroll
    for (int d = 32; d > 0; d >>= 1) {
        #pragma unroll
        for (int k = 0; k < 3; ++k) pd[k] += __shfl_down(pd[k], d, 64);
        #pragma unroll
        for (int p = 0; p < 3; ++p)
            #pragma unroll
            for (int k = 0; k < 3; ++k) pn[p][k] += __shfl_down(pn[p][k], d, 64);
    }
    if (lane == 0) {
        int m = batch[n];
        #pragma unroll
        for (int k = 0; k < 3; ++k) atomicAdd(&dipoles[m * 3 + k], pd[k]);
        #pragma unroll
        for (int p = 0; p < 3; ++p)
            #pragma unroll
            for (int k = 0; k < 3; ++k) atomicAdd(&nac[(m * 3 + p) * 3 + k], pn[p][k]);
    }
}

// ---------------------------------------------------------------- per-molecule heads
__global__ __launch_bounds__(128) void k_heads(
    const float* __restrict__ aw1, const float* __restrict__ ab1,
    const float* __restrict__ aw2, const float* __restrict__ ab2,
    const float* __restrict__ yw1, const float* __restrict__ yb1,
    const float* __restrict__ yw2, const float* __restrict__ yb2,
    const float* __restrict__ energies, const float* __restrict__ nac,
    float* __restrict__ lam, float* __restrict__ phi_y, int M, int S)
{
    __shared__ float sh_in[8];
    __shared__ float sh_red[2];
    int m = blockIdx.x;
    if (m >= M) return;
    int tid = threadIdx.x;
    if (tid == 0) {
        float e0 = energies[m * S];
        for (int j = 0; j < 3; ++j) sh_in[j] = energies[m * S + 1 + j] - e0;
        for (int p = 0; p < 3; ++p) {
            float a = nac[(m * 3 + p) * 3 + 0];
            float b = nac[(m * 3 + p) * 3 + 1];
            float c = nac[(m * 3 + p) * 3 + 2];
            sh_in[3 + p] = sqrtf(a*a + b*b + c*c + 1e-12f);
        }
    }
    __syncthreads();
    float pa = 0.f;
    if (tid < 64) {
        float h = ab1[tid];
        #pragma unroll
        for (int j = 0; j < 3; ++j) h += sh_in[j] * aw1[j * 64 + tid];
        pa = siluf(h) * aw2[tid];
    }
    float h2 = yb1[tid];
    #pragma unroll
    for (int j = 0; j < 6; ++j) h2 += sh_in[j] * yw1[j * 128 + tid];
    float py = siluf(h2) * yw2[tid];
    #pragma unroll
    for (int d = 32; d > 0; d >>= 1) {
        pa += __shfl_down(pa, d, 64);
        py += __shfl_down(py, d, 64);
    }
    int wid = tid >> 6, lane = tid & 63;
    if (lane == 0) sh_red[wid] = py;
    __syncthreads();
    if (tid == 0) {
        lam[m] = pa + ab2[0];
        float yt = sh_red[0] + sh_red[1] + yb2[0];
        phi_y[m] = 1.f / (1.f + __expf(-yt));
    }
}

// ---------------------------------------------------------------- launch
extern "C" void kernel_launch(void* const* d_in, const int* in_sizes, int n_in,
                              void* d_out, int out_size, void* d_ws, size_t ws_size,
                              hipStream_t stream)
{
    const int*   z        = (const int*)  d_in[0];
    const float* pos      = (const float*)d_in[1];
    const int*   eidx     = (const int*)  d_in[2];
    const int*   batch    = (const int*)  d_in[3];
    const float* emb      = (const float*)d_in[5];
    const float* centers  = (const float*)d_in[6];
    const float* gamma    = (const float*)d_in[7];
    const float* fw1      = (const float*)d_in[8];
    const float* fb1      = (const float*)d_in[9];
    const float* fw2      = (const float*)d_in[10];
    const float* fb2      = (const float*)d_in[11];
    const float* uw1      = (const float*)d_in[12];
    const float* ub1      = (const float*)d_in[13];
    const float* uw2      = (const float*)d_in[14];
    const float* ub2      = (const float*)d_in[15];
    const float* ew1      = (const float*)d_in[16];
    const float* eb1      = (const float*)d_in[17];
    const float* ew2      = (const float*)d_in[18];
    const float* eb2      = (const float*)d_in[19];
    const float* dipole_w = (const float*)d_in[20];
    const float* nac_w    = (const float*)d_in[21];
    const float* aw1      = (const float*)d_in[22];
    const float* ab1      = (const float*)d_in[23];
    const float* aw2      = (const float*)d_in[24];
    const float* ab2      = (const float*)d_in[25];
    const float* yw1      = (const float*)d_in[26];
    const float* yb1      = (const float*)d_in[27];
    const float* yw2      = (const float*)d_in[28];
    const float* yb2      = (const float*)d_in[29];

    const int N = in_sizes[0];
    const int E = in_sizes[2] / 2;
    const int S = in_sizes[19];
    const int P = in_sizes[21] / FDIM;
    const int L = in_sizes[9] / FDIM;
    const int M = out_size / (S + 3 + P * 3 + 2);

    const size_t NF = (size_t)N * FDIM;
    float*  s    = (float*)d_ws;                 // NF
    float*  v    = s + NF;                       // 3 NF
    float*  m_s  = v + 3 * NF;                   // NF   (aliased by u1)
    float*  m_v  = m_s + NF;                     // 3 NF
    __half* s_h  = (__half*)(m_v + 3 * NF);      // NF halves
    __half* v_h  = s_h + NF;                     // 3 NF halves
    __half* tab  = v_h + 3 * NF;                 // L * (TAB_T+1) * 384 halves
    int* rowstart = (int*)(tab + (size_t)L * (TAB_T + 1) * 384);
    int* cursor   = rowstart + (N + 1);
    int* esort    = cursor + N;
    int* bsum     = esort + E;
    float* u1 = m_s;   // safe alias: block-local row panels, m_s fully consumed before u1 written

    float* out      = (float*)d_out;
    float* energies = out;
    float* dipoles  = energies + (size_t)M * S;
    float* nac      = dipoles  + (size_t)M * 3;
    float* lam      = nac      + (size_t)M * P * 3;
    float* phi_y    = lam      + M;

    const int* erow = eidx;
    const int* ecol = eidx + E;

    const float step = TAB_RANGE / (float)TAB_T;
    const float inv_step = (float)TAB_T / TAB_RANGE;
    const int NB = (N + 63) / 64;
    const int NSB = (N + 255) / 256;   // scan blocks

    hipMemsetAsync(d_out, 0, (size_t)out_size * sizeof(float), stream);
    hipMemsetAsync(cursor, 0, (size_t)N * sizeof(int), stream);
    k_hist<<<(E + 255) / 256, 256, 0, stream>>>(erow, cursor, E);
    k_scan1<<<NSB, 256, 0, stream>>>(cursor, rowstart, bsum, N);
    k_scan2<<<1, 256, 0, stream>>>(bsum, rowstart, NSB, N);
    k_scan3<<<NSB, 256, 0, stream>>>(rowstart, cursor, bsum, N);
    k_fill<<<(E + 255) / 256, 256, 0, stream>>>(erow, cursor, esort, E);
    k_init<<<(N * FDIM + 255) / 256, 256, 0, stream>>>(z, emb, s, v, s_h, v_h, N);

    // all layers' tables in one dispatch (out of the serial layer loop)
    const int tab_blocks = (TAB_T + 1 + 31) / 32;
    k_table<<<dim3(tab_blocks, L), TH, 0, stream>>>(centers, gamma, fw1, fb1, fw2, fb2, tab, step);

    for (int l = 0; l < L; ++l) {
        const __half* tab_l = tab + (size_t)l * (TAB_T + 1) * 384;
        k_gather<<<N, 128, 0, stream>>>(
            pos, ecol, rowstart, esort, tab_l, s_h, v_h, m_s, m_v, inv_step, (l > 0) ? 1 : 0, N);
        k_mlp1<<<NB, 256, 0, stream>>>(
            s, m_s, m_v, uw1 + (size_t)l * 3 * FDIM * FDIM, ub1 + (size_t)l * FDIM, u1, N);
        k_mlp2<<<NB, 256, 0, stream>>>(
            u1, uw2 + (size_t)l * FDIM * 3 * FDIM, ub2 + (size_t)l * 3 * FDIM,
            s, v, m_v, s_h, v_h, N);
    }

    k_energy2<<<dim3(NB, S), 256, 0, stream>>>(ew1, eb1, ew2, eb2, s, batch, energies, N, S);
    k_vec<<<(N + 3) / 4, 256, 0, stream>>>(v, dipole_w, nac_w, batch, dipoles, nac, N);
    k_heads<<<M, 128, 0, stream>>>(aw1, ab1, aw2, ab2, yw1, yb1, yw2, yb2,
                                   energies, nac, lam, phi_y, M, S);
}

// Round 8
// 646.094 us; speedup vs baseline: 26.6077x; 1.0054x over previous
//
#include <hip/hip_runtime.h>
#include <hip/hip_fp16.h>

#define FDIM 128
#define RDIM 20

#define TAB_T 2048              // table cells; TAB_T+1 rows (scalar), TAB_T pair rows
#define TAB_RANGE 12.0f

constexpr int TH = 256;

__device__ __forceinline__ float siluf(float x) { return x / (1.f + __expf(-x)); }

__device__ __forceinline__ void store_h4(__half* p, float a, float b, float c, float d) {
    __half h[4] = {__float2half(a), __float2half(b), __float2half(c), __float2half(d)};
    *(uint2*)p = *(uint2*)h;
}

// ---------------------------------------------------------------- init: s = emb[z], v = 0
// v layout: [N][3][FDIM]
__global__ void k_init(const int* __restrict__ z, const float* __restrict__ emb,
                       float* __restrict__ s, float* __restrict__ v,
                       __half* __restrict__ s_h, __half* __restrict__ v_h, int N) {
    int i = blockIdx.x * blockDim.x + threadIdx.x;
    if (i >= N * FDIM) return;
    int n = i >> 7, f = i & 127;
    float val = emb[z[n] * FDIM + f];
    s[i] = val;
    s_h[i] = __float2half(val);
    size_t nf = (size_t)N * FDIM;
    v[i] = 0.f; v[i + nf] = 0.f; v[i + 2 * nf] = 0.f;
    __half hz = __float2half(0.f);
    v_h[i] = hz; v_h[i + nf] = hz; v_h[i + 2 * nf] = hz;
}

// ---------------------------------------------------------------- CSR build
__global__ void k_hist(const int* __restrict__ erow, int* __restrict__ cursor, int E) {
    int e = blockIdx.x * blockDim.x + threadIdx.x;
    if (e < E) atomicAdd(&cursor[erow[e]], 1);
}

__global__ __launch_bounds__(256) void k_scan1(const int* __restrict__ cursor,
                                               int* __restrict__ rowstart,
                                               int* __restrict__ bsum, int N) {
    __shared__ int sh[256];
    int tid = threadIdx.x;
    int idx = blockIdx.x * 256 + tid;
    int x = (idx < N) ? cursor[idx] : 0;
    sh[tid] = x;
    __syncthreads();
    #pragma unroll
    for (int off = 1; off < 256; off <<= 1) {
        int t = (tid >= off) ? sh[tid - off] : 0;
        __syncthreads();
        sh[tid] += t;
        __syncthreads();
    }
    if (idx < N) rowstart[idx] = sh[tid] - x;
    if (tid == 255) bsum[blockIdx.x] = sh[255];
}

__global__ __launch_bounds__(256) void k_scan2(int* __restrict__ bsum,
                                               int* __restrict__ rowstart, int nb, int N) {
    __shared__ int sh[256];
    __shared__ int carry;
    int tid = threadIdx.x;
    if (tid == 0) carry = 0;
    __syncthreads();
    for (int base = 0; base < nb; base += 256) {
        int idx = base + tid;
        int x = (idx < nb) ? bsum[idx] : 0;
        sh[tid] = x;
        __syncthreads();
        #pragma unroll
        for (int off = 1; off < 256; off <<= 1) {
            int t = (tid >= off) ? sh[tid - off] : 0;
            __syncthreads();
            sh[tid] += t;
            __syncthreads();
        }
        if (idx < nb) bsum[idx] = carry + sh[tid] - x;
        __syncthreads();
        if (tid == 0) carry += sh[255];
        __syncthreads();
    }
    if (tid == 0) rowstart[N] = carry;
}

__global__ __launch_bounds__(256) void k_scan3(int* __restrict__ rowstart,
                                               int* __restrict__ cursor,
                                               const int* __restrict__ bsum, int N) {
    int idx = blockIdx.x * 256 + threadIdx.x;
    if (idx < N) {
        int val = rowstart[idx] + bsum[blockIdx.x];
        rowstart[idx] = val;
        cursor[idx] = val;
    }
}

__global__ void k_fill(const int* __restrict__ erow, int* __restrict__ cursor,
                       int* __restrict__ esort, int E) {
    int e = blockIdx.x * blockDim.x + threadIdx.x;
    if (e < E) {
        int p = atomicAdd(&cursor[erow[e]], 1);
        esort[p] = e;
    }
}

// ---------------------------------------------------------------- filter-MLP table build (all layers, fp16 out)
__global__ __launch_bounds__(TH) void k_table(
    const float* __restrict__ centers, const float* __restrict__ gamma,
    const float* __restrict__ fw1b, const float* __restrict__ fb1b,
    const float* __restrict__ fw2b, const float* __restrict__ fb2b,
    __half* __restrict__ tabb, float step)
{
    __shared__ float sh_rbf[32][RDIM];
    __shared__ float sh_ht[FDIM][33];
    __shared__ float sh_w[32][3 * FDIM + 4];

    const int l   = blockIdx.y;
    const float* fw1 = fw1b + (size_t)l * RDIM * FDIM;
    const float* fb1 = fb1b + (size_t)l * FDIM;
    const float* fw2 = fw2b + (size_t)l * FDIM * 3 * FDIM;
    const float* fb2 = fb2b + (size_t)l * 3 * FDIM;
    __half* tab = tabb + (size_t)l * (TAB_T + 1) * 384;

    const int p0  = blockIdx.x * 32;
    const int tid = threadIdx.x;

    for (int i = tid; i < 32 * RDIM; i += TH) {
        int p = i / RDIM, r = i - p * RDIM;
        float d = (float)(p0 + p) * step - centers[r];
        sh_rbf[p][r] = __expf(-gamma[r] * d * d);
    }
    __syncthreads();
    for (int i = tid; i < 32 * FDIM; i += TH) {
        int p = i >> 7, f = i & 127;
        float acc = fb1[f];
        #pragma unroll
        for (int r = 0; r < RDIM; ++r) acc += sh_rbf[p][r] * fw1[r * FDIM + f];
        sh_ht[f][p] = siluf(acc);
    }

    const int eq = tid & 7;
    const int fq = tid >> 3;
    const int f0 = fq * 4;

    float pg[3][4][4];
    #pragma unroll
    for (int g3 = 0; g3 < 3; ++g3)
        #pragma unroll
        for (int ee = 0; ee < 4; ++ee)
            #pragma unroll
            for (int i = 0; i < 4; ++i) pg[g3][ee][i] = fb2[g3 * FDIM + f0 + i];

    const int kkr = tid >> 3;
    const int t8  = tid & 7;
    for (int kc = 0; kc < 4; ++kc) {
        __syncthreads();
        #pragma unroll
        for (int j = 0; j < 12; ++j) {
            int g = (t8 * 12 + j) * 4;
            float4 w4 = *(const float4*)&fw2[(size_t)(kc * 32 + kkr) * (3 * FDIM) + g];
            *(float4*)&sh_w[kkr][g] = w4;
        }
        __syncthreads();
        #pragma unroll 4
        for (int kk = 0; kk < 32; ++kk) {
            float hv[4];
            #pragma unroll
            for (int ee = 0; ee < 4; ++ee) hv[ee] = sh_ht[kc * 32 + kk][4 * eq + ee];
            #pragma unroll
            for (int g3 = 0; g3 < 3; ++g3) {
                float4 w4 = *(const float4*)&sh_w[kk][g3 * FDIM + f0];
                #pragma unroll
                for (int ee = 0; ee < 4; ++ee) {
                    pg[g3][ee][0] += hv[ee] * w4.x;
                    pg[g3][ee][1] += hv[ee] * w4.y;
                    pg[g3][ee][2] += hv[ee] * w4.z;
                    pg[g3][ee][3] += hv[ee] * w4.w;
                }
            }
        }
    }

    #pragma unroll
    for (int ee = 0; ee < 4; ++ee) {
        int pt = p0 + 4 * eq + ee;
        if (pt <= TAB_T) {
            #pragma unroll
            for (int g3 = 0; g3 < 3; ++g3)
                store_h4(&tab[(size_t)pt * 384 + g3 * FDIM + f0],
                         pg[g3][ee][0], pg[g3][ee][1], pg[g3][ee][2], pg[g3][ee][3]);
        }
    }
}

// ---------------------------------------------------------------- repack: tab2[t][j] = {tab[t][j], tab[t+1][j]}
__global__ __launch_bounds__(256) void k_repack(const __half* __restrict__ tab,
                                                __half2* __restrict__ tab2) {
    int l = blockIdx.y;
    const __half* t  = tab  + (size_t)l * (TAB_T + 1) * 384;
    __half2*      t2 = tab2 + (size_t)l * TAB_T * 384;
    int i = blockIdx.x * 256 + threadIdx.x;        // < TAB_T*384 exactly
    t2[i] = __halves2half2(t[i], t[i + 384]);
}

// ---------------------------------------------------------------- gather message kernel (fp16 inputs, paired table)
// outputs: m_s fp32, vnorm fp32 (=||m_v||), m_v_h fp16
__global__ __launch_bounds__(128) void k_gather(
    const float* __restrict__ pos, const int* __restrict__ ecol,
    const int* __restrict__ rowstart, const int* __restrict__ esort,
    const __half2* __restrict__ tab2, const __half* __restrict__ s_h,
    const __half* __restrict__ v_h,
    float* __restrict__ m_s, float* __restrict__ vnorm, __half* __restrict__ m_v_h,
    float inv_step, int withv, int N)
{
    __shared__ int   sh_col[32];
    __shared__ int   sh_t0[32];
    __shared__ float sh_w[32];
    __shared__ float sh_d0[32], sh_d1[32], sh_d2[32];

    const int n   = blockIdx.x;
    const int tid = threadIdx.x;
    const int lo  = rowstart[n], hi = rowstart[n + 1];

    float acc_s = 0.f, av0 = 0.f, av1 = 0.f, av2 = 0.f;
    const float px = pos[n * 3 + 0], py = pos[n * 3 + 1], pz = pos[n * 3 + 2];

    for (int base = lo; base < hi; base += 32) {
        const int ne = min(32, hi - base);
        __syncthreads();
        if (tid < 32) {
            if (tid < ne) {
                int e  = esort[base + tid];
                int cl = ecol[e];
                float dx = pos[cl*3+0] - px;
                float dy = pos[cl*3+1] - py;
                float dz = pos[cl*3+2] - pz;
                float dist = sqrtf(dx*dx + dy*dy + dz*dz + 1e-12f);
                float inv = 1.f / (dist + 1e-8f);
                sh_col[tid] = cl;
                sh_d0[tid] = dx*inv; sh_d1[tid] = dy*inv; sh_d2[tid] = dz*inv;
                float u = fminf(dist * inv_step, (float)TAB_T);
                int t0 = min((int)u, TAB_T - 1);
                sh_t0[tid] = t0;
                sh_w[tid]  = u - (float)t0;
            } else {
                sh_col[tid] = 0; sh_t0[tid] = 0; sh_w[tid] = 0.f;
                sh_d0[tid] = sh_d1[tid] = sh_d2[tid] = 0.f;
            }
        }
        __syncthreads();
        if (withv) {
            #pragma unroll 2
            for (int el = 0; el < ne; ++el) {
                int   cl = sh_col[el];
                int   t0 = sh_t0[el];
                float w  = sh_w[el];
                const __half2* t2 = tab2 + (size_t)t0 * 384 + tid;
                float2 pss2 = __half22float2(t2[0]);
                float2 pvv2 = __half22float2(t2[128]);
                float2 psv2 = __half22float2(t2[256]);
                float pss = pss2.x + w * (pss2.y - pss2.x);
                float pvv = pvv2.x + w * (pvv2.y - pvv2.x);
                float psv = psv2.x + w * (psv2.y - psv2.x);
                float sc = __half2float(s_h[(size_t)cl * FDIM + tid]);
                const __half* vp = v_h + (size_t)cl * 3 * FDIM + tid;
                float svs = psv * sc;
                acc_s += pss * sc;
                av0 += pvv * __half2float(vp[0])        + svs * sh_d0[el];
                av1 += pvv * __half2float(vp[FDIM])     + svs * sh_d1[el];
                av2 += pvv * __half2float(vp[2*FDIM])   + svs * sh_d2[el];
            }
        } else {
            #pragma unroll 2
            for (int el = 0; el < ne; ++el) {
                int   cl = sh_col[el];
                int   t0 = sh_t0[el];
                float w  = sh_w[el];
                const __half2* t2 = tab2 + (size_t)t0 * 384 + tid;
                float2 pss2 = __half22float2(t2[0]);
                float2 psv2 = __half22float2(t2[256]);
                float pss = pss2.x + w * (pss2.y - pss2.x);
                float psv = psv2.x + w * (psv2.y - psv2.x);
                float sc = __half2float(s_h[(size_t)cl * FDIM + tid]);
                float svs = psv * sc;
                acc_s += pss * sc;
                av0 += svs * sh_d0[el];
                av1 += svs * sh_d1[el];
                av2 += svs * sh_d2[el];
            }
        }
    }

    m_s[(size_t)n * FDIM + tid] = acc_s;
    vnorm[(size_t)n * FDIM + tid] = sqrtf(av0*av0 + av1*av1 + av2*av2 + 1e-12f);
    __half* mh = m_v_h + (size_t)n * 3 * FDIM + tid;
    mh[0]      = __float2half(av0);
    mh[FDIM]   = __float2half(av1);
    mh[2*FDIM] = __float2half(av2);
}

// ---------------------------------------------------------------- GEMM 1: u1 = silu(X @ uw1 + ub1)
// X = [s | m_s | vnorm]. Tile 64x128, 256 thr, 4x8 micro, K=384, reg-pipelined.
__global__ __launch_bounds__(256) void k_mlp1(
    const float* __restrict__ s, const float* __restrict__ m_s, const float* __restrict__ vnorm,
    const float* __restrict__ uw1, const float* __restrict__ ub1,
    float* __restrict__ u1, int N)
{
    __shared__ float shA[16][68];    // [kk][row]
    __shared__ float shB[16][132];   // [kk][col]

    const int tid = threadIdx.x;
    const int n0  = blockIdx.x * 64;
    const int tx  = tid & 15, ty = tid >> 4;
    const int cA  = tx * 4, cB = 64 + tx * 4;
    const int r0  = ty * 4;
    const int rs  = tid >> 2;
    const int k4  = (tid & 3) * 4;
    const int bk  = tid >> 5;
    const int bc4 = (tid & 31) * 4;

    float acc[4][8];
    {
        float4 bA = *(const float4*)&ub1[cA];
        float4 bB = *(const float4*)&ub1[cB];
        #pragma unroll
        for (int i = 0; i < 4; ++i) {
            acc[i][0]=bA.x; acc[i][1]=bA.y; acc[i][2]=bA.z; acc[i][3]=bA.w;
            acc[i][4]=bB.x; acc[i][5]=bB.y; acc[i][6]=bB.z; acc[i][7]=bB.w;
        }
    }

    float4 pa, pb0, pb1;

#define MLP1_LOAD(kc) do { \
        int kg = (kc) * 16 + k4; int n = n0 + rs; \
        pa = make_float4(0.f,0.f,0.f,0.f); \
        if (n < N) { \
            if (kg < 128)      pa = *(const float4*)&s[(size_t)n * FDIM + kg]; \
            else if (kg < 256) pa = *(const float4*)&m_s[(size_t)n * FDIM + kg - 128]; \
            else               pa = *(const float4*)&vnorm[(size_t)n * FDIM + kg - 256]; \
        } \
        pb0 = *(const float4*)&uw1[(size_t)((kc)*16 + bk) * FDIM + bc4]; \
        pb1 = *(const float4*)&uw1[(size_t)((kc)*16 + 8 + bk) * FDIM + bc4]; \
    } while (0)

    MLP1_LOAD(0);
    for (int kc = 0; kc < 24; ++kc) {
        __syncthreads();
        shA[k4+0][rs] = pa.x; shA[k4+1][rs] = pa.y;
        shA[k4+2][rs] = pa.z; shA[k4+3][rs] = pa.w;
        *(float4*)&shB[bk][bc4]     = pb0;
        *(float4*)&shB[8 + bk][bc4] = pb1;
        if (kc + 1 < 24) MLP1_LOAD(kc + 1);
        __syncthreads();
        #pragma unroll
        for (int kk = 0; kk < 16; ++kk) {
            float4 a4 = *(const float4*)&shA[kk][r0];
            float4 b0 = *(const float4*)&shB[kk][cA];
            float4 b1 = *(const float4*)&shB[kk][cB];
            float av[4] = {a4.x, a4.y, a4.z, a4.w};
            #pragma unroll
            for (int i = 0; i < 4; ++i) {
                acc[i][0] += av[i]*b0.x; acc[i][1] += av[i]*b0.y;
                acc[i][2] += av[i]*b0.z; acc[i][3] += av[i]*b0.w;
                acc[i][4] += av[i]*b1.x; acc[i][5] += av[i]*b1.y;
                acc[i][6] += av[i]*b1.z; acc[i][7] += av[i]*b1.w;
            }
        }
    }
#undef MLP1_LOAD

    #pragma unroll
    for (int i = 0; i < 4; ++i) {
        int n = n0 + r0 + i;
        if (n < N) {
            float4 oA = make_float4(siluf(acc[i][0]), siluf(acc[i][1]), siluf(acc[i][2]), siluf(acc[i][3]));
            float4 oB = make_float4(siluf(acc[i][4]), siluf(acc[i][5]), siluf(acc[i][6]), siluf(acc[i][7]));
            *(float4*)&u1[(size_t)n * FDIM + cA] = oA;
            *(float4*)&u1[(size_t)n * FDIM + cB] = oB;
        }
    }
}

// ---------------------------------------------------------------- GEMM 2: upd = u1 @ uw2 + ub2, fused apply
// m_v read as fp16; v fp32 RMW + fp16 mirror.
__global__ __launch_bounds__(256) void k_mlp2(
    const float* __restrict__ u1, const float* __restrict__ uw2, const float* __restrict__ ub2,
    float* __restrict__ s, float* __restrict__ v, const __half* __restrict__ m_v_h,
    __half* __restrict__ s_h, __half* __restrict__ v_h, int N)
{
    __shared__ float shU[64][132];
    __shared__ float shB[16][132];

    const int tid = threadIdx.x;
    const int n0  = blockIdx.x * 64;
    const int tx  = tid & 15, ty = tid >> 4;
    const int cA  = tx * 4, cB = 64 + tx * 4;
    const int r0  = ty * 4;
    const int bk  = tid >> 5;
    const int bc4 = (tid & 31) * 4;

    #pragma unroll
    for (int it = 0; it < 8; ++it) {
        int idx = it * 256 + tid;
        int row = idx >> 5;
        int c4  = (idx & 31) * 4;
        int n = n0 + row;
        float4 a = make_float4(0.f,0.f,0.f,0.f);
        if (n < N) a = *(const float4*)&u1[(size_t)n * FDIM + c4];
        *(float4*)&shU[row][c4] = a;
    }

    float4 pb0, pb1;
#define MLP2_LOADB(g, kc) do { \
        pb0 = *(const float4*)&uw2[(size_t)((kc)*16 + bk) * (3*FDIM) + (g) * FDIM + bc4]; \
        pb1 = *(const float4*)&uw2[(size_t)((kc)*16 + 8 + bk) * (3*FDIM) + (g) * FDIM + bc4]; \
    } while (0)

    MLP2_LOADB(0, 0);
    float alpha[4][8];

    for (int g = 0; g < 3; ++g) {
        float acc2[4][8];
        {
            float4 bA = *(const float4*)&ub2[g * FDIM + cA];
            float4 bB = *(const float4*)&ub2[g * FDIM + cB];
            #pragma unroll
            for (int i = 0; i < 4; ++i) {
                acc2[i][0]=bA.x; acc2[i][1]=bA.y; acc2[i][2]=bA.z; acc2[i][3]=bA.w;
                acc2[i][4]=bB.x; acc2[i][5]=bB.y; acc2[i][6]=bB.z; acc2[i][7]=bB.w;
            }
        }
        for (int kc = 0; kc < 8; ++kc) {
            __syncthreads();
            *(float4*)&shB[bk][bc4]     = pb0;
            *(float4*)&shB[8 + bk][bc4] = pb1;
            if (kc + 1 < 8)      MLP2_LOADB(g, kc + 1);
            else if (g + 1 < 3)  MLP2_LOADB(g + 1, 0);
            __syncthreads();
            #pragma unroll
            for (int kk = 0; kk < 16; ++kk) {
                int col = kc * 16 + kk;
                float4 b0 = *(const float4*)&shB[kk][cA];
                float4 b1 = *(const float4*)&shB[kk][cB];
                #pragma unroll
                for (int i = 0; i < 4; ++i) {
                    float uv = shU[r0 + i][col];
                    acc2[i][0] += uv*b0.x; acc2[i][1] += uv*b0.y;
                    acc2[i][2] += uv*b0.z; acc2[i][3] += uv*b0.w;
                    acc2[i][4] += uv*b1.x; acc2[i][5] += uv*b1.y;
                    acc2[i][6] += uv*b1.z; acc2[i][7] += uv*b1.w;
                }
            }
        }

        if (g == 0) {
            #pragma unroll
            for (int i = 0; i < 4; ++i) {
                int n = n0 + r0 + i;
                if (n < N) {
                    float4 s0 = *(const float4*)&s[(size_t)n * FDIM + cA];
                    float4 s1 = *(const float4*)&s[(size_t)n * FDIM + cB];
                    s0.x += acc2[i][0]; s0.y += acc2[i][1]; s0.z += acc2[i][2]; s0.w += acc2[i][3];
                    s1.x += acc2[i][4]; s1.y += acc2[i][5]; s1.z += acc2[i][6]; s1.w += acc2[i][7];
                    *(float4*)&s[(size_t)n * FDIM + cA] = s0;
                    *(float4*)&s[(size_t)n * FDIM + cB] = s1;
                    store_h4(&s_h[(size_t)n * FDIM + cA], s0.x, s0.y, s0.z, s0.w);
                    store_h4(&s_h[(size_t)n * FDIM + cB], s1.x, s1.y, s1.z, s1.w);
                }
            }
        } else if (g == 1) {
            #pragma unroll
            for (int i = 0; i < 4; ++i)
                #pragma unroll
                for (int j = 0; j < 8; ++j) alpha[i][j] = acc2[i][j];
        } else {
            #pragma unroll
            for (int i = 0; i < 4; ++i) {
                int n = n0 + r0 + i;
                if (n < N) {
                    #pragma unroll
                    for (int k = 0; k < 3; ++k) {
                        float* vp = v + ((size_t)n * 3 + k) * FDIM;
                        const __half* mp = m_v_h + ((size_t)n * 3 + k) * FDIM;
                        __half* vhp = v_h + ((size_t)n * 3 + k) * FDIM;
                        __half mh[8];
                        *(uint2*)&mh[0] = *(const uint2*)&mp[cA];
                        *(uint2*)&mh[4] = *(const uint2*)&mp[cB];
                        float4 v0 = *(const float4*)&vp[cA];
                        float4 v1 = *(const float4*)&vp[cB];
                        v0.x = alpha[i][0]*v0.x + acc2[i][0]*__half2float(mh[0]);
                        v0.y = alpha[i][1]*v0.y + acc2[i][1]*__half2float(mh[1]);
                        v0.z = alpha[i][2]*v0.z + acc2[i][2]*__half2float(mh[2]);
                        v0.w = alpha[i][3]*v0.w + acc2[i][3]*__half2float(mh[3]);
                        v1.x = alpha[i][4]*v1.x + acc2[i][4]*__half2float(mh[4]);
                        v1.y = alpha[i][5]*v1.y + acc2[i][5]*__half2float(mh[5]);
                        v1.z = alpha[i][6]*v1.z + acc2[i][6]*__half2float(mh[6]);
                        v1.w = alpha[i][7]*v1.w + acc2[i][7]*__half2float(mh[7]);
                        *(float4*)&vp[cA] = v0;
                        *(float4*)&vp[cB] = v1;
                        store_h4(&vhp[cA], v0.x, v0.y, v0.z, v0.w);
                        store_h4(&vhp[cB], v1.x, v1.y, v1.z, v1.w);
                    }
                }
            }
        }
    }
#undef MLP2_LOADB
}

// ---------------------------------------------------------------- energy head GEMM, all states in-block
__global__ __launch_bounds__(256) void k_energy2(
    const float* __restrict__ ew1, const float* __restrict__ eb1,
    const float* __restrict__ ew2, const float* __restrict__ eb2,
    const float* __restrict__ s, const int* __restrict__ batch,
    float* __restrict__ energies, int N, int S)
{
    __shared__ float shS[64][132];
    __shared__ float shB[16][132];

    const int tid = threadIdx.x;
    const int n0  = blockIdx.x * 64;
    const int tx  = tid & 15, ty = tid >> 4;
    const int cA  = tx * 4, cB = 64 + tx * 4;
    const int r0  = ty * 4;
    const int bk  = tid >> 5;
    const int bc4 = (tid & 31) * 4;

    // stage s tile once (reused for all S states)
    #pragma unroll
    for (int it = 0; it < 8; ++it) {
        int idx = it * 256 + tid;
        int row = idx >> 5;
        int c4  = (idx & 31) * 4;
        int n = n0 + row;
        float4 a = make_float4(0.f,0.f,0.f,0.f);
        if (n < N) a = *(const float4*)&s[(size_t)n * FDIM + c4];
        *(float4*)&shS[row][c4] = a;
    }

    float4 pb0, pb1;
#define EN_LOADB(st, kc) do { \
        pb0 = *(const float4*)&ew1[(size_t)(st) * FDIM * FDIM + (size_t)((kc)*16 + bk) * FDIM + bc4]; \
        pb1 = *(const float4*)&ew1[(size_t)(st) * FDIM * FDIM + (size_t)((kc)*16 + 8 + bk) * FDIM + bc4]; \
    } while (0)

    EN_LOADB(0, 0);
    for (int st = 0; st < S; ++st) {
        float acc[4][8];
        {
            float4 bA = *(const float4*)&eb1[st * FDIM + cA];
            float4 bB = *(const float4*)&eb1[st * FDIM + cB];
            #pragma unroll
            for (int i = 0; i < 4; ++i) {
                acc[i][0]=bA.x; acc[i][1]=bA.y; acc[i][2]=bA.z; acc[i][3]=bA.w;
                acc[i][4]=bB.x; acc[i][5]=bB.y; acc[i][6]=bB.z; acc[i][7]=bB.w;
            }
        }
        for (int kc = 0; kc < 8; ++kc) {
            __syncthreads();
            *(float4*)&shB[bk][bc4]     = pb0;
            *(float4*)&shB[8 + bk][bc4] = pb1;
            if (kc + 1 < 8)      EN_LOADB(st, kc + 1);
            else if (st + 1 < S) EN_LOADB(st + 1, 0);
            __syncthreads();
            #pragma unroll
            for (int kk = 0; kk < 16; ++kk) {
                int col = kc * 16 + kk;
                float4 b0 = *(const float4*)&shB[kk][cA];
                float4 b1 = *(const float4*)&shB[kk][cB];
                #pragma unroll
                for (int i = 0; i < 4; ++i) {
                    float sv = shS[r0 + i][col];
                    acc[i][0] += sv*b0.x; acc[i][1] += sv*b0.y;
                    acc[i][2] += sv*b0.z; acc[i][3] += sv*b0.w;
                    acc[i][4] += sv*b1.x; acc[i][5] += sv*b1.y;
                    acc[i][6] += sv*b1.z; acc[i][7] += sv*b1.w;
                }
            }
        }

        float4 wA = *(const float4*)&ew2[st * FDIM + cA];
        float4 wB = *(const float4*)&ew2[st * FDIM + cB];
        float p[4];
        #pragma unroll
        for (int i = 0; i < 4; ++i) {
            p[i]  = siluf(acc[i][0])*wA.x + siluf(acc[i][1])*wA.y
                  + siluf(acc[i][2])*wA.z + siluf(acc[i][3])*wA.w;
            p[i] += siluf(acc[i][4])*wB.x + siluf(acc[i][5])*wB.y
                  + siluf(acc[i][6])*wB.z + siluf(acc[i][7])*wB.w;
        }
        #pragma unroll
        for (int m = 1; m <= 8; m <<= 1) {
            #pragma unroll
            for (int i = 0; i < 4; ++i) p[i] += __shfl_xor(p[i], m, 64);
        }
        if (tx == 0) {
            float b2 = eb2[st];
            #pragma unroll
            for (int i = 0; i < 4; ++i) {
                int n = n0 + r0 + i;
                if (n < N) atomicAdd(&energies[batch[n] * S + st], p[i] + b2);
            }
        }
    }
#undef EN_LOADB
}

// ---------------------------------------------------------------- dipole / nac heads
__global__ void k_vec(const float* __restrict__ v, const float* __restrict__ dipole_w,
                      const float* __restrict__ nac_w, const int* __restrict__ batch,
                      float* __restrict__ dipoles, float* __restrict__ nac, int N)
{
    int n = blockIdx.x * 4 + (threadIdx.x >> 6);
    int lane = threadIdx.x & 63;
    if (n >= N) return;
    float pd[3] = {0.f, 0.f, 0.f};
    float pn[3][3] = {{0.f}};
    const float* vb = v + (size_t)n * 3 * FDIM;
    for (int f = lane; f < FDIM; f += 64) {
        float v0 = vb[f], v1 = vb[FDIM + f], v2 = vb[2*FDIM + f];
        float wd = dipole_w[f];
        pd[0] += wd * v0; pd[1] += wd * v1; pd[2] += wd * v2;
        #pragma unroll
        for (int p = 0; p < 3; ++p) {
            float wn = nac_w[p * FDIM + f];
            pn[p][0] += wn * v0; pn[p][1] += wn * v1; pn[p][2] += wn * v2;
        }
    }
    #pragma unroll
    for (int d = 32; d > 0; d >>= 1) {
        #pragma unroll
        for (int k = 0; k < 3; ++k) pd[k] += __shfl_down(pd[k], d, 64);
        #pragma unroll
        for (int p = 0; p < 3; ++p)
            #pragma unroll
            for (int k = 0; k < 3; ++k) pn[p][k] += __shfl_down(pn[p][k], d, 64);
    }
    if (lane == 0) {
        int m = batch[n];
        #pragma unroll
        for (int k = 0; k < 3; ++k) atomicAdd(&dipoles[m * 3 + k], pd[k]);
        #pragma unroll
        for (int p = 0; p < 3; ++p)
            #pragma unroll
            for (int k = 0; k < 3; ++k) atomicAdd(&nac[(m * 3 + p) * 3 + k], pn[p][k]);
    }
}

// ---------------------------------------------------------------- per-molecule heads
__global__ __launch_bounds__(128) void k_heads(
    const float* __restrict__ aw1, const float* __restrict__ ab1,
    const float* __restrict__ aw2, const float* __restrict__ ab2,
    const float* __restrict__ yw1, const float* __restrict__ yb1,
    const float* __restrict__ yw2, const float* __restrict__ yb2,
    const float* __restrict__ energies, const float* __restrict__ nac,
    float* __restrict__ lam, float* __restrict__ phi_y, int M, int S)
{
    __shared__ float sh_in[8];
    __shared__ float sh_red[2];
    int m = blockIdx.x;
    if (m >= M) return;
    int tid = threadIdx.x;
    if (tid == 0) {
        float e0 = energies[m * S];
        for (int j = 0; j < 3; ++j) sh_in[j] = energies[m * S + 1 + j] - e0;
        for (int p = 0; p < 3; ++p) {
            float a = nac[(m * 3 + p) * 3 + 0];
            float b = nac[(m * 3 + p) * 3 + 1];
            float c = nac[(m * 3 + p) * 3 + 2];
            sh_in[3 + p] = sqrtf(a*a + b*b + c*c + 1e-12f);
        }
    }
    __syncthreads();
    float pa = 0.f;
    if (tid < 64) {
        float h = ab1[tid];
        #pragma unroll
        for (int j = 0; j < 3; ++j) h += sh_in[j] * aw1[j * 64 + tid];
        pa = siluf(h) * aw2[tid];
    }
    float h2 = yb1[tid];
    #pragma unroll
    for (int j = 0; j < 6; ++j) h2 += sh_in[j] * yw1[j * 128 + tid];
    float py = siluf(h2) * yw2[tid];
    #pragma unroll
    for (int d = 32; d > 0; d >>= 1) {
        pa += __shfl_down(pa, d, 64);
        py += __shfl_down(py, d, 64);
    }
    int wid = tid >> 6, lane = tid & 63;
    if (lane == 0) sh_red[wid] = py;
    __syncthreads();
    if (tid == 0) {
        lam[m] = pa + ab2[0];
        float yt = sh_red[0] + sh_red[1] + yb2[0];
        phi_y[m] = 1.f / (1.f + __expf(-yt));
    }
}

// ---------------------------------------------------------------- launch
extern "C" void kernel_launch(void* const* d_in, const int* in_sizes, int n_in,
                              void* d_out, int out_size, void* d_ws, size_t ws_size,
                              hipStream_t stream)
{
    const int*   z        = (const int*)  d_in[0];
    const float* pos      = (const float*)d_in[1];
    const int*   eidx     = (const int*)  d_in[2];
    const int*   batch    = (const int*)  d_in[3];
    const float* emb      = (const float*)d_in[5];
    const float* centers  = (const float*)d_in[6];
    const float* gamma    = (const float*)d_in[7];
    const float* fw1      = (const float*)d_in[8];
    const float* fb1      = (const float*)d_in[9];
    const float* fw2      = (const float*)d_in[10];
    const float* fb2      = (const float*)d_in[11];
    const float* uw1      = (const float*)d_in[12];
    const float* ub1      = (const float*)d_in[13];
    const float* uw2      = (const float*)d_in[14];
    const float* ub2      = (const float*)d_in[15];
    const float* ew1      = (const float*)d_in[16];
    const float* eb1      = (const float*)d_in[17];
    const float* ew2      = (const float*)d_in[18];
    const float* eb2      = (const float*)d_in[19];
    const float* dipole_w = (const float*)d_in[20];
    const float* nac_w    = (const float*)d_in[21];
    const float* aw1      = (const float*)d_in[22];
    const float* ab1      = (const float*)d_in[23];
    const float* aw2      = (const float*)d_in[24];
    const float* ab2      = (const float*)d_in[25];
    const float* yw1      = (const float*)d_in[26];
    const float* yb1      = (const float*)d_in[27];
    const float* yw2      = (const float*)d_in[28];
    const float* yb2      = (const float*)d_in[29];

    const int N = in_sizes[0];
    const int E = in_sizes[2] / 2;
    const int S = in_sizes[19];
    const int P = in_sizes[21] / FDIM;
    const int L = in_sizes[9] / FDIM;
    const int M = out_size / (S + 3 + P * 3 + 2);

    const size_t NF = (size_t)N * FDIM;
    float*   s     = (float*)d_ws;                  // NF
    float*   v     = s + NF;                        // 3 NF
    float*   m_s   = v + 3 * NF;                    // NF   (aliased by u1)
    float*   vnorm = m_s + NF;                      // NF
    __half*  s_h   = (__half*)(vnorm + NF);         // NF halves
    __half*  v_h   = s_h + NF;                      // 3 NF halves
    __half*  m_v_h = v_h + 3 * NF;                  // 3 NF halves
    __half*  tab   = m_v_h + 3 * NF;                // L * (TAB_T+1) * 384 halves
    __half2* tab2  = (__half2*)(tab + (size_t)L * (TAB_T + 1) * 384);  // L * TAB_T * 384 half2
    int* rowstart = (int*)(tab2 + (size_t)L * TAB_T * 384);
    int* cursor   = rowstart + (N + 1);
    int* esort    = cursor + N;
    int* bsum     = esort + E;
    float* u1 = m_s;   // safe alias: block-local row panels, m_s fully consumed before u1 written

    float* out      = (float*)d_out;
    float* energies = out;
    float* dipoles  = energies + (size_t)M * S;
    float* nac      = dipoles  + (size_t)M * 3;
    float* lam      = nac      + (size_t)M * P * 3;
    float* phi_y    = lam      + M;

    const int* erow = eidx;
    const int* ecol = eidx + E;

    const float step = TAB_RANGE / (float)TAB_T;
    const float inv_step = (float)TAB_T / TAB_RANGE;
    const int NB = (N + 63) / 64;
    const int NSB = (N + 255) / 256;

    hipMemsetAsync(d_out, 0, (size_t)out_size * sizeof(float), stream);
    hipMemsetAsync(cursor, 0, (size_t)N * sizeof(int), stream);
    k_hist<<<(E + 255) / 256, 256, 0, stream>>>(erow, cursor, E);
    k_scan1<<<NSB, 256, 0, stream>>>(cursor, rowstart, bsum, N);
    k_scan2<<<1, 256, 0, stream>>>(bsum, rowstart, NSB, N);
    k_scan3<<<NSB, 256, 0, stream>>>(rowstart, cursor, bsum, N);
    k_fill<<<(E + 255) / 256, 256, 0, stream>>>(erow, cursor, esort, E);
    k_init<<<(N * FDIM + 255) / 256, 256, 0, stream>>>(z, emb, s, v, s_h, v_h, N);

    const int tab_blocks = (TAB_T + 1 + 31) / 32;
    k_table<<<dim3(tab_blocks, L), TH, 0, stream>>>(centers, gamma, fw1, fb1, fw2, fb2, tab, step);
    k_repack<<<dim3(TAB_T * 384 / 256, L), 256, 0, stream>>>(tab, tab2);

    for (int l = 0; l < L; ++l) {
        const __half2* tab2_l = tab2 + (size_t)l * TAB_T * 384;
        k_gather<<<N, 128, 0, stream>>>(
            pos, ecol, rowstart, esort, tab2_l, s_h, v_h,
            m_s, vnorm, m_v_h, inv_step, (l > 0) ? 1 : 0, N);
        k_mlp1<<<NB, 256, 0, stream>>>(
            s, m_s, vnorm, uw1 + (size_t)l * 3 * FDIM * FDIM, ub1 + (size_t)l * FDIM, u1, N);
        k_mlp2<<<NB, 256, 0, stream>>>(
            u1, uw2 + (size_t)l * FDIM * 3 * FDIM, ub2 + (size_t)l * 3 * FDIM,
            s, v, m_v_h, s_h, v_h, N);
    }

    k_energy2<<<NB, 256, 0, stream>>>(ew1, eb1, ew2, eb2, s, batch, energies, N, S);
    k_vec<<<(N + 3) / 4, 256, 0, stream>>>(v, dipole_w, nac_w, batch, dipoles, nac, N);
    k_heads<<<M, 128, 0, stream>>>(aw1, ab1, aw2, ab2, yw1, yb1, yw2, yb2,
                                   energies, nac, lam, phi_y, M, S);
}

// Round 9
// 605.818 us; speedup vs baseline: 28.3766x; 1.0665x over previous
//
#include <hip/hip_runtime.h>
#include <hip/hip_fp16.h>

#define FDIM 128
#define RDIM 20

#define TAB_T 2048              // table cells; TAB_T+1 rows (scalar), TAB_T pair rows
#define TAB_RANGE 12.0f

constexpr int TH = 256;

__device__ __forceinline__ float siluf(float x) { return x / (1.f + __expf(-x)); }

__device__ __forceinline__ void store_h4(__half* p, float a, float b, float c, float d) {
    __half h[4] = {__float2half(a), __float2half(b), __float2half(c), __float2half(d)};
    *(uint2*)p = *(uint2*)h;
}

// ---------------------------------------------------------------- init: s = emb[z], v = 0
__global__ void k_init(const int* __restrict__ z, const float* __restrict__ emb,
                       float* __restrict__ s, float* __restrict__ v,
                       __half* __restrict__ s_h, __half* __restrict__ v_h, int N) {
    int i = blockIdx.x * blockDim.x + threadIdx.x;
    if (i >= N * FDIM) return;
    int n = i >> 7, f = i & 127;
    float val = emb[z[n] * FDIM + f];
    s[i] = val;
    s_h[i] = __float2half(val);
    size_t nf = (size_t)N * FDIM;
    v[i] = 0.f; v[i + nf] = 0.f; v[i + 2 * nf] = 0.f;
    __half hz = __float2half(0.f);
    v_h[i] = hz; v_h[i + nf] = hz; v_h[i + 2 * nf] = hz;
}

// ---------------------------------------------------------------- CSR build
__global__ void k_hist(const int* __restrict__ erow, int* __restrict__ cursor, int E) {
    int e = blockIdx.x * blockDim.x + threadIdx.x;
    if (e < E) atomicAdd(&cursor[erow[e]], 1);
}

__global__ __launch_bounds__(256) void k_scan1(const int* __restrict__ cursor,
                                               int* __restrict__ rowstart,
                                               int* __restrict__ bsum, int N) {
    __shared__ int sh[256];
    int tid = threadIdx.x;
    int idx = blockIdx.x * 256 + tid;
    int x = (idx < N) ? cursor[idx] : 0;
    sh[tid] = x;
    __syncthreads();
    #pragma unroll
    for (int off = 1; off < 256; off <<= 1) {
        int t = (tid >= off) ? sh[tid - off] : 0;
        __syncthreads();
        sh[tid] += t;
        __syncthreads();
    }
    if (idx < N) rowstart[idx] = sh[tid] - x;
    if (tid == 255) bsum[blockIdx.x] = sh[255];
}

__global__ __launch_bounds__(256) void k_scan2(int* __restrict__ bsum,
                                               int* __restrict__ rowstart, int nb, int N) {
    __shared__ int sh[256];
    __shared__ int carry;
    int tid = threadIdx.x;
    if (tid == 0) carry = 0;
    __syncthreads();
    for (int base = 0; base < nb; base += 256) {
        int idx = base + tid;
        int x = (idx < nb) ? bsum[idx] : 0;
        sh[tid] = x;
        __syncthreads();
        #pragma unroll
        for (int off = 1; off < 256; off <<= 1) {
            int t = (tid >= off) ? sh[tid - off] : 0;
            __syncthreads();
            sh[tid] += t;
            __syncthreads();
        }
        if (idx < nb) bsum[idx] = carry + sh[tid] - x;
        __syncthreads();
        if (tid == 0) carry += sh[255];
        __syncthreads();
    }
    if (tid == 0) rowstart[N] = carry;
}

__global__ __launch_bounds__(256) void k_scan3(int* __restrict__ rowstart,
                                               int* __restrict__ cursor,
                                               const int* __restrict__ bsum, int N) {
    int idx = blockIdx.x * 256 + threadIdx.x;
    if (idx < N) {
        int val = rowstart[idx] + bsum[blockIdx.x];
        rowstart[idx] = val;
        cursor[idx] = val;
    }
}

__global__ void k_fill(const int* __restrict__ erow, int* __restrict__ cursor,
                       int* __restrict__ esort, int E) {
    int e = blockIdx.x * blockDim.x + threadIdx.x;
    if (e < E) {
        int p = atomicAdd(&cursor[erow[e]], 1);
        esort[p] = e;
    }
}

// ---------------------------------------------------------------- per-slot edge geometry (once, reused 3 layers)
__global__ void k_geom(const float* __restrict__ pos, const int* __restrict__ erow,
                       const int* __restrict__ ecol, const int* __restrict__ esort,
                       int2* __restrict__ geo_ci, float4* __restrict__ geo_wd,
                       float inv_step, int E) {
    int i = blockIdx.x * blockDim.x + threadIdx.x;
    if (i >= E) return;
    int e  = esort[i];
    int rw = erow[e], cl = ecol[e];
    float dx = pos[cl*3+0] - pos[rw*3+0];
    float dy = pos[cl*3+1] - pos[rw*3+1];
    float dz = pos[cl*3+2] - pos[rw*3+2];
    float dist = sqrtf(dx*dx + dy*dy + dz*dz + 1e-12f);
    float inv = 1.f / (dist + 1e-8f);
    float u = fminf(dist * inv_step, (float)TAB_T);
    int t0 = min((int)u, TAB_T - 1);
    geo_ci[i] = make_int2(cl, t0);
    geo_wd[i] = make_float4(u - (float)t0, dx*inv, dy*inv, dz*inv);
}

// ---------------------------------------------------------------- filter-MLP table build (all layers, fp16 out)
__global__ __launch_bounds__(TH) void k_table(
    const float* __restrict__ centers, const float* __restrict__ gamma,
    const float* __restrict__ fw1b, const float* __restrict__ fb1b,
    const float* __restrict__ fw2b, const float* __restrict__ fb2b,
    __half* __restrict__ tabb, float step)
{
    __shared__ float sh_rbf[32][RDIM];
    __shared__ float sh_ht[FDIM][33];
    __shared__ float sh_w[32][3 * FDIM + 4];

    const int l   = blockIdx.y;
    const float* fw1 = fw1b + (size_t)l * RDIM * FDIM;
    const float* fb1 = fb1b + (size_t)l * FDIM;
    const float* fw2 = fw2b + (size_t)l * FDIM * 3 * FDIM;
    const float* fb2 = fb2b + (size_t)l * 3 * FDIM;
    __half* tab = tabb + (size_t)l * (TAB_T + 1) * 384;

    const int p0  = blockIdx.x * 32;
    const int tid = threadIdx.x;

    for (int i = tid; i < 32 * RDIM; i += TH) {
        int p = i / RDIM, r = i - p * RDIM;
        float d = (float)(p0 + p) * step - centers[r];
        sh_rbf[p][r] = __expf(-gamma[r] * d * d);
    }
    __syncthreads();
    for (int i = tid; i < 32 * FDIM; i += TH) {
        int p = i >> 7, f = i & 127;
        float acc = fb1[f];
        #pragma unroll
        for (int r = 0; r < RDIM; ++r) acc += sh_rbf[p][r] * fw1[r * FDIM + f];
        sh_ht[f][p] = siluf(acc);
    }

    const int eq = tid & 7;
    const int fq = tid >> 3;
    const int f0 = fq * 4;

    float pg[3][4][4];
    #pragma unroll
    for (int g3 = 0; g3 < 3; ++g3)
        #pragma unroll
        for (int ee = 0; ee < 4; ++ee)
            #pragma unroll
            for (int i = 0; i < 4; ++i) pg[g3][ee][i] = fb2[g3 * FDIM + f0 + i];

    const int kkr = tid >> 3;
    const int t8  = tid & 7;
    for (int kc = 0; kc < 4; ++kc) {
        __syncthreads();
        #pragma unroll
        for (int j = 0; j < 12; ++j) {
            int g = (t8 * 12 + j) * 4;
            float4 w4 = *(const float4*)&fw2[(size_t)(kc * 32 + kkr) * (3 * FDIM) + g];
            *(float4*)&sh_w[kkr][g] = w4;
        }
        __syncthreads();
        #pragma unroll 4
        for (int kk = 0; kk < 32; ++kk) {
            float hv[4];
            #pragma unroll
            for (int ee = 0; ee < 4; ++ee) hv[ee] = sh_ht[kc * 32 + kk][4 * eq + ee];
            #pragma unroll
            for (int g3 = 0; g3 < 3; ++g3) {
                float4 w4 = *(const float4*)&sh_w[kk][g3 * FDIM + f0];
                #pragma unroll
                for (int ee = 0; ee < 4; ++ee) {
                    pg[g3][ee][0] += hv[ee] * w4.x;
                    pg[g3][ee][1] += hv[ee] * w4.y;
                    pg[g3][ee][2] += hv[ee] * w4.z;
                    pg[g3][ee][3] += hv[ee] * w4.w;
                }
            }
        }
    }

    #pragma unroll
    for (int ee = 0; ee < 4; ++ee) {
        int pt = p0 + 4 * eq + ee;
        if (pt <= TAB_T) {
            #pragma unroll
            for (int g3 = 0; g3 < 3; ++g3)
                store_h4(&tab[(size_t)pt * 384 + g3 * FDIM + f0],
                         pg[g3][ee][0], pg[g3][ee][1], pg[g3][ee][2], pg[g3][ee][3]);
        }
    }
}

// ---------------------------------------------------------------- repack: tab2[t][j] = {tab[t][j], tab[t+1][j]}
__global__ __launch_bounds__(256) void k_repack(const __half* __restrict__ tab,
                                                __half2* __restrict__ tab2) {
    int l = blockIdx.y;
    const __half* t  = tab  + (size_t)l * (TAB_T + 1) * 384;
    __half2*      t2 = tab2 + (size_t)l * TAB_T * 384;
    int i = blockIdx.x * 256 + threadIdx.x;
    t2[i] = __halves2half2(t[i], t[i + 384]);
}

// ---------------------------------------------------------------- gather message kernel (fp16, precomputed geometry)
__global__ __launch_bounds__(128) void k_gather(
    const int* __restrict__ rowstart,
    const int2* __restrict__ geo_ci, const float4* __restrict__ geo_wd,
    const __half2* __restrict__ tab2, const __half* __restrict__ s_h,
    const __half* __restrict__ v_h,
    float* __restrict__ m_s, float* __restrict__ vnorm, __half* __restrict__ m_v_h,
    int withv, int N)
{
    __shared__ int   sh_col[32];
    __shared__ int   sh_t0[32];
    __shared__ float sh_w[32];
    __shared__ float sh_d0[32], sh_d1[32], sh_d2[32];

    const int n   = blockIdx.x;
    const int tid = threadIdx.x;
    const int lo  = rowstart[n], hi = rowstart[n + 1];

    float acc_s = 0.f, av0 = 0.f, av1 = 0.f, av2 = 0.f;

    for (int base = lo; base < hi; base += 32) {
        const int ne = min(32, hi - base);
        __syncthreads();
        if (tid < 32) {
            int idx = base + tid;
            if (tid < ne) {
                int2   ci = geo_ci[idx];
                float4 wd = geo_wd[idx];
                sh_col[tid] = ci.x; sh_t0[tid] = ci.y;
                sh_w[tid] = wd.x;
                sh_d0[tid] = wd.y; sh_d1[tid] = wd.z; sh_d2[tid] = wd.w;
            } else {
                sh_col[tid] = 0; sh_t0[tid] = 0; sh_w[tid] = 0.f;
                sh_d0[tid] = sh_d1[tid] = sh_d2[tid] = 0.f;
            }
        }
        __syncthreads();
        if (withv) {
            #pragma unroll 2
            for (int el = 0; el < ne; ++el) {
                int   cl = sh_col[el];
                int   t0 = sh_t0[el];
                float w  = sh_w[el];
                const __half2* t2 = tab2 + (size_t)t0 * 384 + tid;
                float2 pss2 = __half22float2(t2[0]);
                float2 pvv2 = __half22float2(t2[128]);
                float2 psv2 = __half22float2(t2[256]);
                float pss = pss2.x + w * (pss2.y - pss2.x);
                float pvv = pvv2.x + w * (pvv2.y - pvv2.x);
                float psv = psv2.x + w * (psv2.y - psv2.x);
                float sc = __half2float(s_h[(size_t)cl * FDIM + tid]);
                const __half* vp = v_h + (size_t)cl * 3 * FDIM + tid;
                float svs = psv * sc;
                acc_s += pss * sc;
                av0 += pvv * __half2float(vp[0])        + svs * sh_d0[el];
                av1 += pvv * __half2float(vp[FDIM])     + svs * sh_d1[el];
                av2 += pvv * __half2float(vp[2*FDIM])   + svs * sh_d2[el];
            }
        } else {
            #pragma unroll 2
            for (int el = 0; el < ne; ++el) {
                int   cl = sh_col[el];
                int   t0 = sh_t0[el];
                float w  = sh_w[el];
                const __half2* t2 = tab2 + (size_t)t0 * 384 + tid;
                float2 pss2 = __half22float2(t2[0]);
                float2 psv2 = __half22float2(t2[256]);
                float pss = pss2.x + w * (pss2.y - pss2.x);
                float psv = psv2.x + w * (psv2.y - psv2.x);
                float sc = __half2float(s_h[(size_t)cl * FDIM + tid]);
                float svs = psv * sc;
                acc_s += pss * sc;
                av0 += svs * sh_d0[el];
                av1 += svs * sh_d1[el];
                av2 += svs * sh_d2[el];
            }
        }
    }

    m_s[(size_t)n * FDIM + tid] = acc_s;
    vnorm[(size_t)n * FDIM + tid] = sqrtf(av0*av0 + av1*av1 + av2*av2 + 1e-12f);
    __half* mh = m_v_h + (size_t)n * 3 * FDIM + tid;
    mh[0]      = __float2half(av0);
    mh[FDIM]   = __float2half(av1);
    mh[2*FDIM] = __float2half(av2);
}

// ---------------------------------------------------------------- GEMM 1: u1 = silu(X @ uw1 + ub1)
__global__ __launch_bounds__(256) void k_mlp1(
    const float* __restrict__ s, const float* __restrict__ m_s, const float* __restrict__ vnorm,
    const float* __restrict__ uw1, const float* __restrict__ ub1,
    float* __restrict__ u1, int N)
{
    __shared__ float shA[16][68];
    __shared__ float shB[16][132];

    const int tid = threadIdx.x;
    const int n0  = blockIdx.x * 64;
    const int tx  = tid & 15, ty = tid >> 4;
    const int cA  = tx * 4, cB = 64 + tx * 4;
    const int r0  = ty * 4;
    const int rs  = tid >> 2;
    const int k4  = (tid & 3) * 4;
    const int bk  = tid >> 5;
    const int bc4 = (tid & 31) * 4;

    float acc[4][8];
    {
        float4 bA = *(const float4*)&ub1[cA];
        float4 bB = *(const float4*)&ub1[cB];
        #pragma unroll
        for (int i = 0; i < 4; ++i) {
            acc[i][0]=bA.x; acc[i][1]=bA.y; acc[i][2]=bA.z; acc[i][3]=bA.w;
            acc[i][4]=bB.x; acc[i][5]=bB.y; acc[i][6]=bB.z; acc[i][7]=bB.w;
        }
    }

    float4 pa, pb0, pb1;

#define MLP1_LOAD(kc) do { \
        int kg = (kc) * 16 + k4; int n = n0 + rs; \
        pa = make_float4(0.f,0.f,0.f,0.f); \
        if (n < N) { \
            if (kg < 128)      pa = *(const float4*)&s[(size_t)n * FDIM + kg]; \
            else if (kg < 256) pa = *(const float4*)&m_s[(size_t)n * FDIM + kg - 128]; \
            else               pa = *(const float4*)&vnorm[(size_t)n * FDIM + kg - 256]; \
        } \
        pb0 = *(const float4*)&uw1[(size_t)((kc)*16 + bk) * FDIM + bc4]; \
        pb1 = *(const float4*)&uw1[(size_t)((kc)*16 + 8 + bk) * FDIM + bc4]; \
    } while (0)

    MLP1_LOAD(0);
    for (int kc = 0; kc < 24; ++kc) {
        __syncthreads();
        shA[k4+0][rs] = pa.x; shA[k4+1][rs] = pa.y;
        shA[k4+2][rs] = pa.z; shA[k4+3][rs] = pa.w;
        *(float4*)&shB[bk][bc4]     = pb0;
        *(float4*)&shB[8 + bk][bc4] = pb1;
        if (kc + 1 < 24) MLP1_LOAD(kc + 1);
        __syncthreads();
        #pragma unroll
        for (int kk = 0; kk < 16; ++kk) {
            float4 a4 = *(const float4*)&shA[kk][r0];
            float4 b0 = *(const float4*)&shB[kk][cA];
            float4 b1 = *(const float4*)&shB[kk][cB];
            float av[4] = {a4.x, a4.y, a4.z, a4.w};
            #pragma unroll
            for (int i = 0; i < 4; ++i) {
                acc[i][0] += av[i]*b0.x; acc[i][1] += av[i]*b0.y;
                acc[i][2] += av[i]*b0.z; acc[i][3] += av[i]*b0.w;
                acc[i][4] += av[i]*b1.x; acc[i][5] += av[i]*b1.y;
                acc[i][6] += av[i]*b1.z; acc[i][7] += av[i]*b1.w;
            }
        }
    }
#undef MLP1_LOAD

    #pragma unroll
    for (int i = 0; i < 4; ++i) {
        int n = n0 + r0 + i;
        if (n < N) {
            float4 oA = make_float4(siluf(acc[i][0]), siluf(acc[i][1]), siluf(acc[i][2]), siluf(acc[i][3]));
            float4 oB = make_float4(siluf(acc[i][4]), siluf(acc[i][5]), siluf(acc[i][6]), siluf(acc[i][7]));
            *(float4*)&u1[(size_t)n * FDIM + cA] = oA;
            *(float4*)&u1[(size_t)n * FDIM + cB] = oB;
        }
    }
}

// ---------------------------------------------------------------- GEMM 2: upd = u1 @ uw2 + ub2, fused apply
__global__ __launch_bounds__(256) void k_mlp2(
    const float* __restrict__ u1, const float* __restrict__ uw2, const float* __restrict__ ub2,
    float* __restrict__ s, float* __restrict__ v, const __half* __restrict__ m_v_h,
    __half* __restrict__ s_h, __half* __restrict__ v_h, int N)
{
    __shared__ float shU[64][132];
    __shared__ float shB[16][132];

    const int tid = threadIdx.x;
    const int n0  = blockIdx.x * 64;
    const int tx  = tid & 15, ty = tid >> 4;
    const int cA  = tx * 4, cB = 64 + tx * 4;
    const int r0  = ty * 4;
    const int bk  = tid >> 5;
    const int bc4 = (tid & 31) * 4;

    #pragma unroll
    for (int it = 0; it < 8; ++it) {
        int idx = it * 256 + tid;
        int row = idx >> 5;
        int c4  = (idx & 31) * 4;
        int n = n0 + row;
        float4 a = make_float4(0.f,0.f,0.f,0.f);
        if (n < N) a = *(const float4*)&u1[(size_t)n * FDIM + c4];
        *(float4*)&shU[row][c4] = a;
    }

    float4 pb0, pb1;
#define MLP2_LOADB(g, kc) do { \
        pb0 = *(const float4*)&uw2[(size_t)((kc)*16 + bk) * (3*FDIM) + (g) * FDIM + bc4]; \
        pb1 = *(const float4*)&uw2[(size_t)((kc)*16 + 8 + bk) * (3*FDIM) + (g) * FDIM + bc4]; \
    } while (0)

    MLP2_LOADB(0, 0);
    float alpha[4][8];

    for (int g = 0; g < 3; ++g) {
        float acc2[4][8];
        {
            float4 bA = *(const float4*)&ub2[g * FDIM + cA];
            float4 bB = *(const float4*)&ub2[g * FDIM + cB];
            #pragma unroll
            for (int i = 0; i < 4; ++i) {
                acc2[i][0]=bA.x; acc2[i][1]=bA.y; acc2[i][2]=bA.z; acc2[i][3]=bA.w;
                acc2[i][4]=bB.x; acc2[i][5]=bB.y; acc2[i][6]=bB.z; acc2[i][7]=bB.w;
            }
        }
        for (int kc = 0; kc < 8; ++kc) {
            __syncthreads();
            *(float4*)&shB[bk][bc4]     = pb0;
            *(float4*)&shB[8 + bk][bc4] = pb1;
            if (kc + 1 < 8)      MLP2_LOADB(g, kc + 1);
            else if (g + 1 < 3)  MLP2_LOADB(g + 1, 0);
            __syncthreads();
            #pragma unroll
            for (int kk = 0; kk < 16; ++kk) {
                int col = kc * 16 + kk;
                float4 b0 = *(const float4*)&shB[kk][cA];
                float4 b1 = *(const float4*)&shB[kk][cB];
                #pragma unroll
                for (int i = 0; i < 4; ++i) {
                    float uv = shU[r0 + i][col];
                    acc2[i][0] += uv*b0.x; acc2[i][1] += uv*b0.y;
                    acc2[i][2] += uv*b0.z; acc2[i][3] += uv*b0.w;
                    acc2[i][4] += uv*b1.x; acc2[i][5] += uv*b1.y;
                    acc2[i][6] += uv*b1.z; acc2[i][7] += uv*b1.w;
                }
            }
        }

        if (g == 0) {
            #pragma unroll
            for (int i = 0; i < 4; ++i) {
                int n = n0 + r0 + i;
                if (n < N) {
                    float4 s0 = *(const float4*)&s[(size_t)n * FDIM + cA];
                    float4 s1 = *(const float4*)&s[(size_t)n * FDIM + cB];
                    s0.x += acc2[i][0]; s0.y += acc2[i][1]; s0.z += acc2[i][2]; s0.w += acc2[i][3];
                    s1.x += acc2[i][4]; s1.y += acc2[i][5]; s1.z += acc2[i][6]; s1.w += acc2[i][7];
                    *(float4*)&s[(size_t)n * FDIM + cA] = s0;
                    *(float4*)&s[(size_t)n * FDIM + cB] = s1;
                    store_h4(&s_h[(size_t)n * FDIM + cA], s0.x, s0.y, s0.z, s0.w);
                    store_h4(&s_h[(size_t)n * FDIM + cB], s1.x, s1.y, s1.z, s1.w);
                }
            }
        } else if (g == 1) {
            #pragma unroll
            for (int i = 0; i < 4; ++i)
                #pragma unroll
                for (int j = 0; j < 8; ++j) alpha[i][j] = acc2[i][j];
        } else {
            #pragma unroll
            for (int i = 0; i < 4; ++i) {
                int n = n0 + r0 + i;
                if (n < N) {
                    #pragma unroll
                    for (int k = 0; k < 3; ++k) {
                        float* vp = v + ((size_t)n * 3 + k) * FDIM;
                        const __half* mp = m_v_h + ((size_t)n * 3 + k) * FDIM;
                        __half* vhp = v_h + ((size_t)n * 3 + k) * FDIM;
                        __half mh[8];
                        *(uint2*)&mh[0] = *(const uint2*)&mp[cA];
                        *(uint2*)&mh[4] = *(const uint2*)&mp[cB];
                        float4 v0 = *(const float4*)&vp[cA];
                        float4 v1 = *(const float4*)&vp[cB];
                        v0.x = alpha[i][0]*v0.x + acc2[i][0]*__half2float(mh[0]);
                        v0.y = alpha[i][1]*v0.y + acc2[i][1]*__half2float(mh[1]);
                        v0.z = alpha[i][2]*v0.z + acc2[i][2]*__half2float(mh[2]);
                        v0.w = alpha[i][3]*v0.w + acc2[i][3]*__half2float(mh[3]);
                        v1.x = alpha[i][4]*v1.x + acc2[i][4]*__half2float(mh[4]);
                        v1.y = alpha[i][5]*v1.y + acc2[i][5]*__half2float(mh[5]);
                        v1.z = alpha[i][6]*v1.z + acc2[i][6]*__half2float(mh[6]);
                        v1.w = alpha[i][7]*v1.w + acc2[i][7]*__half2float(mh[7]);
                        *(float4*)&vp[cA] = v0;
                        *(float4*)&vp[cB] = v1;
                        store_h4(&vhp[cA], v0.x, v0.y, v0.z, v0.w);
                        store_h4(&vhp[cB], v1.x, v1.y, v1.z, v1.w);
                    }
                }
            }
        }
    }
#undef MLP2_LOADB
}

// ---------------------------------------------------------------- energy head GEMM (grid = NB x S)
__global__ __launch_bounds__(256) void k_energy2(
    const float* __restrict__ ew1, const float* __restrict__ eb1,
    const float* __restrict__ ew2, const float* __restrict__ eb2,
    const float* __restrict__ s, const int* __restrict__ batch,
    float* __restrict__ energies, int N, int S)
{
    __shared__ float shA[16][68];
    __shared__ float shB[16][132];

    const int tid = threadIdx.x;
    const int n0  = blockIdx.x * 64;
    const int st  = blockIdx.y;
    const int tx  = tid & 15, ty = tid >> 4;
    const int cA  = tx * 4, cB = 64 + tx * 4;
    const int r0  = ty * 4;
    const int rs  = tid >> 2;
    const int k4  = (tid & 3) * 4;

    float acc[4][8];
    {
        float4 bA = *(const float4*)&eb1[st * FDIM + cA];
        float4 bB = *(const float4*)&eb1[st * FDIM + cB];
        #pragma unroll
        for (int i = 0; i < 4; ++i) {
            acc[i][0]=bA.x; acc[i][1]=bA.y; acc[i][2]=bA.z; acc[i][3]=bA.w;
            acc[i][4]=bB.x; acc[i][5]=bB.y; acc[i][6]=bB.z; acc[i][7]=bB.w;
        }
    }

    for (int kc = 0; kc < 8; ++kc) {
        __syncthreads();
        {
            int kg = kc * 16 + k4;
            int n  = n0 + rs;
            float4 a = make_float4(0.f, 0.f, 0.f, 0.f);
            if (n < N) a = *(const float4*)&s[(size_t)n * FDIM + kg];
            shA[k4+0][rs] = a.x; shA[k4+1][rs] = a.y; shA[k4+2][rs] = a.z; shA[k4+3][rs] = a.w;
        }
        #pragma unroll
        for (int i = 0; i < 2; ++i) {
            int idx = tid + i * 256;
            int kk = idx >> 5;
            int c4 = (idx & 31) * 4;
            *(float4*)&shB[kk][c4] =
                *(const float4*)&ew1[(size_t)st * FDIM * FDIM + (size_t)(kc*16+kk) * FDIM + c4];
        }
        __syncthreads();
        #pragma unroll
        for (int kk = 0; kk < 16; ++kk) {
            float4 a4 = *(const float4*)&shA[kk][r0];
            float4 b0 = *(const float4*)&shB[kk][cA];
            float4 b1 = *(const float4*)&shB[kk][cB];
            float av[4] = {a4.x, a4.y, a4.z, a4.w};
            #pragma unroll
            for (int i = 0; i < 4; ++i) {
                acc[i][0] += av[i]*b0.x; acc[i][1] += av[i]*b0.y;
                acc[i][2] += av[i]*b0.z; acc[i][3] += av[i]*b0.w;
                acc[i][4] += av[i]*b1.x; acc[i][5] += av[i]*b1.y;
                acc[i][6] += av[i]*b1.z; acc[i][7] += av[i]*b1.w;
            }
        }
    }

    float4 wA = *(const float4*)&ew2[st * FDIM + cA];
    float4 wB = *(const float4*)&ew2[st * FDIM + cB];
    float p[4];
    #pragma unroll
    for (int i = 0; i < 4; ++i) {
        p[i]  = siluf(acc[i][0])*wA.x + siluf(acc[i][1])*wA.y
              + siluf(acc[i][2])*wA.z + siluf(acc[i][3])*wA.w;
        p[i] += siluf(acc[i][4])*wB.x + siluf(acc[i][5])*wB.y
              + siluf(acc[i][6])*wB.z + siluf(acc[i][7])*wB.w;
    }
    #pragma unroll
    for (int m = 1; m <= 8; m <<= 1) {
        #pragma unroll
        for (int i = 0; i < 4; ++i) p[i] += __shfl_xor(p[i], m, 64);
    }
    if (tx == 0) {
        float b2 = eb2[st];
        #pragma unroll
        for (int i = 0; i < 4; ++i) {
            int n = n0 + r0 + i;
            if (n < N) atomicAdd(&energies[batch[n] * S + st], p[i] + b2);
        }
    }
}

// ---------------------------------------------------------------- dipole / nac heads
__global__ void k_vec(const float* __restrict__ v, const float* __restrict__ dipole_w,
                      const float* __restrict__ nac_w, const int* __restrict__ batch,
                      float* __restrict__ dipoles, float* __restrict__ nac, int N)
{
    int n = blockIdx.x * 4 + (threadIdx.x >> 6);
    int lane = threadIdx.x & 63;
    if (n >= N) return;
    float pd[3] = {0.f, 0.f, 0.f};
    float pn[3][3] = {{0.f}};
    const float* vb = v + (size_t)n * 3 * FDIM;
    for (int f = lane; f < FDIM; f += 64) {
        float v0 = vb[f], v1 = vb[FDIM + f], v2 = vb[2*FDIM + f];
        float wd = dipole_w[f];
        pd[0] += wd * v0; pd[1] += wd * v1; pd[2] += wd * v2;
        #pragma unroll
        for (int p = 0; p < 3; ++p) {
            float wn = nac_w[p * FDIM + f];
            pn[p][0] += wn * v0; pn[p][1] += wn * v1; pn[p][2] += wn * v2;
        }
    }
    #pragma unroll
    for (int d = 32; d > 0; d >>= 1) {
        #pragma unroll
        for (int k = 0; k < 3; ++k) pd[k] += __shfl_down(pd[k], d, 64);
        #pragma unroll
        for (int p = 0; p < 3; ++p)
            #pragma unroll
            for (int k = 0; k < 3; ++k) pn[p][k] += __shfl_down(pn[p][k], d, 64);
    }
    if (lane == 0) {
        int m = batch[n];
        #pragma unroll
        for (int k = 0; k < 3; ++k) atomicAdd(&dipoles[m * 3 + k], pd[k]);
        #pragma unroll
        for (int p = 0; p < 3; ++p)
            #pragma unroll
            for (int k = 0; k < 3; ++k) atomicAdd(&nac[(m * 3 + p) * 3 + k], pn[p][k]);
    }
}

// ---------------------------------------------------------------- per-molecule heads
__global__ __launch_bounds__(128) void k_heads(
    const float* __restrict__ aw1, const float* __restrict__ ab1,
    const float* __restrict__ aw2, const float* __restrict__ ab2,
    const float* __restrict__ yw1, const float* __restrict__ yb1,
    const float* __restrict__ yw2, const float* __restrict__ yb2,
    const float* __restrict__ energies, const float* __restrict__ nac,
    float* __restrict__ lam, float* __restrict__ phi_y, int M, int S)
{
    __shared__ float sh_in[8];
    __shared__ float sh_red[2];
    int m = blockIdx.x;
    if (m >= M) return;
    int tid = threadIdx.x;
    if (tid == 0) {
        float e0 = energies[m * S];
        for (int j = 0; j < 3; ++j) sh_in[j] = energies[m * S + 1 + j] - e0;
        for (int p = 0; p < 3; ++p) {
            float a = nac[(m * 3 + p) * 3 + 0];
            float b = nac[(m * 3 + p) * 3 + 1];
            float c = nac[(m * 3 + p) * 3 + 2];
            sh_in[3 + p] = sqrtf(a*a + b*b + c*c + 1e-12f);
        }
    }
    __syncthreads();
    float pa = 0.f;
    if (tid < 64) {
        float h = ab1[tid];
        #pragma unroll
        for (int j = 0; j < 3; ++j) h += sh_in[j] * aw1[j * 64 + tid];
        pa = siluf(h) * aw2[tid];
    }
    float h2 = yb1[tid];
    #pragma unroll
    for (int j = 0; j < 6; ++j) h2 += sh_in[j] * yw1[j * 128 + tid];
    float py = siluf(h2) * yw2[tid];
    #pragma unroll
    for (int d = 32; d > 0; d >>= 1) {
        pa += __shfl_down(pa, d, 64);
        py += __shfl_down(py, d, 64);
    }
    int wid = tid >> 6, lane = tid & 63;
    if (lane == 0) sh_red[wid] = py;
    __syncthreads();
    if (tid == 0) {
        lam[m] = pa + ab2[0];
        float yt = sh_red[0] + sh_red[1] + yb2[0];
        phi_y[m] = 1.f / (1.f + __expf(-yt));
    }
}

// ---------------------------------------------------------------- launch
extern "C" void kernel_launch(void* const* d_in, const int* in_sizes, int n_in,
                              void* d_out, int out_size, void* d_ws, size_t ws_size,
                              hipStream_t stream)
{
    const int*   z        = (const int*)  d_in[0];
    const float* pos      = (const float*)d_in[1];
    const int*   eidx     = (const int*)  d_in[2];
    const int*   batch    = (const int*)  d_in[3];
    const float* emb      = (const float*)d_in[5];
    const float* centers  = (const float*)d_in[6];
    const float* gamma    = (const float*)d_in[7];
    const float* fw1      = (const float*)d_in[8];
    const float* fb1      = (const float*)d_in[9];
    const float* fw2      = (const float*)d_in[10];
    const float* fb2      = (const float*)d_in[11];
    const float* uw1      = (const float*)d_in[12];
    const float* ub1      = (const float*)d_in[13];
    const float* uw2      = (const float*)d_in[14];
    const float* ub2      = (const float*)d_in[15];
    const float* ew1      = (const float*)d_in[16];
    const float* eb1      = (const float*)d_in[17];
    const float* ew2      = (const float*)d_in[18];
    const float* eb2      = (const float*)d_in[19];
    const float* dipole_w = (const float*)d_in[20];
    const float* nac_w    = (const float*)d_in[21];
    const float* aw1      = (const float*)d_in[22];
    const float* ab1      = (const float*)d_in[23];
    const float* aw2      = (const float*)d_in[24];
    const float* ab2      = (const float*)d_in[25];
    const float* yw1      = (const float*)d_in[26];
    const float* yb1      = (const float*)d_in[27];
    const float* yw2      = (const float*)d_in[28];
    const float* yb2      = (const float*)d_in[29];

    const int N = in_sizes[0];
    const int E = in_sizes[2] / 2;
    const int S = in_sizes[19];
    const int P = in_sizes[21] / FDIM;
    const int L = in_sizes[9] / FDIM;
    const int M = out_size / (S + 3 + P * 3 + 2);

    const size_t NF = (size_t)N * FDIM;
    float*   s     = (float*)d_ws;                  // NF
    float*   v     = s + NF;                        // 3 NF
    float*   m_s   = v + 3 * NF;                    // NF   (aliased by u1)
    float*   vnorm = m_s + NF;                      // NF
    __half*  s_h   = (__half*)(vnorm + NF);         // NF halves
    __half*  v_h   = s_h + NF;                      // 3 NF halves
    __half*  m_v_h = v_h + 3 * NF;                  // 3 NF halves
    __half*  tab   = m_v_h + 3 * NF;                // L * (TAB_T+1) * 384 halves
    __half2* tab2  = (__half2*)(tab + (size_t)L * (TAB_T + 1) * 384);  // L * TAB_T * 384 half2
    float4*  geo_wd = (float4*)(tab2 + (size_t)L * TAB_T * 384);        // E float4
    int2*    geo_ci = (int2*)(geo_wd + E);                              // E int2
    int* rowstart = (int*)(geo_ci + E);
    int* cursor   = rowstart + (N + 1);
    int* esort    = cursor + N;
    int* bsum     = esort + E;
    float* u1 = m_s;   // safe alias: block-local row panels, m_s fully consumed before u1 written

    float* out      = (float*)d_out;
    float* energies = out;
    float* dipoles  = energies + (size_t)M * S;
    float* nac      = dipoles  + (size_t)M * 3;
    float* lam      = nac      + (size_t)M * P * 3;
    float* phi_y    = lam      + M;

    const int* erow = eidx;
    const int* ecol = eidx + E;

    const float step = TAB_RANGE / (float)TAB_T;
    const float inv_step = (float)TAB_T / TAB_RANGE;
    const int NB = (N + 63) / 64;
    const int NSB = (N + 255) / 256;

    hipMemsetAsync(d_out, 0, (size_t)out_size * sizeof(float), stream);
    hipMemsetAsync(cursor, 0, (size_t)N * sizeof(int), stream);
    k_hist<<<(E + 255) / 256, 256, 0, stream>>>(erow, cursor, E);
    k_scan1<<<NSB, 256, 0, stream>>>(cursor, rowstart, bsum, N);
    k_scan2<<<1, 256, 0, stream>>>(bsum, rowstart, NSB, N);
    k_scan3<<<NSB, 256, 0, stream>>>(rowstart, cursor, bsum, N);
    k_fill<<<(E + 255) / 256, 256, 0, stream>>>(erow, cursor, esort, E);
    k_geom<<<(E + 255) / 256, 256, 0, stream>>>(pos, erow, ecol, esort, geo_ci, geo_wd, inv_step, E);
    k_init<<<(N * FDIM + 255) / 256, 256, 0, stream>>>(z, emb, s, v, s_h, v_h, N);

    const int tab_blocks = (TAB_T + 1 + 31) / 32;
    k_table<<<dim3(tab_blocks, L), TH, 0, stream>>>(centers, gamma, fw1, fb1, fw2, fb2, tab, step);
    k_repack<<<dim3(TAB_T * 384 / 256, L), 256, 0, stream>>>(tab, tab2);

    for (int l = 0; l < L; ++l) {
        const __half2* tab2_l = tab2 + (size_t)l * TAB_T * 384;
        k_gather<<<N, 128, 0, stream>>>(
            rowstart, geo_ci, geo_wd, tab2_l, s_h, v_h,
            m_s, vnorm, m_v_h, (l > 0) ? 1 : 0, N);
        k_mlp1<<<NB, 256, 0, stream>>>(
            s, m_s, vnorm, uw1 + (size_t)l * 3 * FDIM * FDIM, ub1 + (size_t)l * FDIM, u1, N);
        k_mlp2<<<NB, 256, 0, stream>>>(
            u1, uw2 + (size_t)l * FDIM * 3 * FDIM, ub2 + (size_t)l * 3 * FDIM,
            s, v, m_v_h, s_h, v_h, N);
    }

    k_energy2<<<dim3(NB, S), 256, 0, stream>>>(ew1, eb1, ew2, eb2, s, batch, energies, N, S);
    k_vec<<<(N + 3) / 4, 256, 0, stream>>>(v, dipole_w, nac_w, batch, dipoles, nac, N);
    k_heads<<<M, 128, 0, stream>>>(aw1, ab1, aw2, ab2, yw1, yb1, yw2, yb2,
                                   energies, nac, lam, phi_y, M, S);
}

// Round 10
// 592.101 us; speedup vs baseline: 29.0340x; 1.0232x over previous
//
#include <hip/hip_runtime.h>
#include <hip/hip_fp16.h>

#define FDIM 128
#define RDIM 20

#define TAB_T 2048              // table cells; TAB_T+1 rows (scalar), TAB_T pair rows
#define TAB_RANGE 12.0f

constexpr int TH = 256;

__device__ __forceinline__ float siluf(float x) { return x / (1.f + __expf(-x)); }

__device__ __forceinline__ void store_h4(__half* p, float a, float b, float c, float d) {
    __half h[4] = {__float2half(a), __float2half(b), __float2half(c), __float2half(d)};
    *(uint2*)p = *(uint2*)h;
}

// ---------------------------------------------------------------- init: s = emb[z], v = 0
__global__ void k_init(const int* __restrict__ z, const float* __restrict__ emb,
                       float* __restrict__ s, float* __restrict__ v,
                       __half* __restrict__ s_h, __half* __restrict__ v_h, int N) {
    int i = blockIdx.x * blockDim.x + threadIdx.x;
    if (i >= N * FDIM) return;
    int n = i >> 7, f = i & 127;
    float val = emb[z[n] * FDIM + f];
    s[i] = val;
    s_h[i] = __float2half(val);
    size_t nf = (size_t)N * FDIM;
    v[i] = 0.f; v[i + nf] = 0.f; v[i + 2 * nf] = 0.f;
    __half hz = __float2half(0.f);
    v_h[i] = hz; v_h[i + nf] = hz; v_h[i + 2 * nf] = hz;
}

// ---------------------------------------------------------------- CSR build
__global__ void k_hist(const int* __restrict__ erow, int* __restrict__ cursor, int E) {
    int e = blockIdx.x * blockDim.x + threadIdx.x;
    if (e < E) atomicAdd(&cursor[erow[e]], 1);
}

__global__ __launch_bounds__(256) void k_scan1(const int* __restrict__ cursor,
                                               int* __restrict__ rowstart,
                                               int* __restrict__ bsum, int N) {
    __shared__ int sh[256];
    int tid = threadIdx.x;
    int idx = blockIdx.x * 256 + tid;
    int x = (idx < N) ? cursor[idx] : 0;
    sh[tid] = x;
    __syncthreads();
    #pragma unroll
    for (int off = 1; off < 256; off <<= 1) {
        int t = (tid >= off) ? sh[tid - off] : 0;
        __syncthreads();
        sh[tid] += t;
        __syncthreads();
    }
    if (idx < N) rowstart[idx] = sh[tid] - x;
    if (tid == 255) bsum[blockIdx.x] = sh[255];
}

__global__ __launch_bounds__(256) void k_scan2(int* __restrict__ bsum,
                                               int* __restrict__ rowstart, int nb, int N) {
    __shared__ int sh[256];
    __shared__ int carry;
    int tid = threadIdx.x;
    if (tid == 0) carry = 0;
    __syncthreads();
    for (int base = 0; base < nb; base += 256) {
        int idx = base + tid;
        int x = (idx < nb) ? bsum[idx] : 0;
        sh[tid] = x;
        __syncthreads();
        #pragma unroll
        for (int off = 1; off < 256; off <<= 1) {
            int t = (tid >= off) ? sh[tid - off] : 0;
            __syncthreads();
            sh[tid] += t;
            __syncthreads();
        }
        if (idx < nb) bsum[idx] = carry + sh[tid] - x;
        __syncthreads();
        if (tid == 0) carry += sh[255];
        __syncthreads();
    }
    if (tid == 0) rowstart[N] = carry;
}

__global__ __launch_bounds__(256) void k_scan3(int* __restrict__ rowstart,
                                               int* __restrict__ cursor,
                                               const int* __restrict__ bsum, int N) {
    int idx = blockIdx.x * 256 + threadIdx.x;
    if (idx < N) {
        int val = rowstart[idx] + bsum[blockIdx.x];
        rowstart[idx] = val;
        cursor[idx] = val;
    }
}

__global__ void k_fill(const int* __restrict__ erow, int* __restrict__ cursor,
                       int* __restrict__ esort, int E) {
    int e = blockIdx.x * blockDim.x + threadIdx.x;
    if (e < E) {
        int p = atomicAdd(&cursor[erow[e]], 1);
        esort[p] = e;
    }
}

// ---------------------------------------------------------------- per-slot edge geometry (once, reused 3 layers)
__global__ void k_geom(const float* __restrict__ pos, const int* __restrict__ erow,
                       const int* __restrict__ ecol, const int* __restrict__ esort,
                       int2* __restrict__ geo_ci, float4* __restrict__ geo_wd,
                       float inv_step, int E) {
    int i = blockIdx.x * blockDim.x + threadIdx.x;
    if (i >= E) return;
    int e  = esort[i];
    int rw = erow[e], cl = ecol[e];
    float dx = pos[cl*3+0] - pos[rw*3+0];
    float dy = pos[cl*3+1] - pos[rw*3+1];
    float dz = pos[cl*3+2] - pos[rw*3+2];
    float dist = sqrtf(dx*dx + dy*dy + dz*dz + 1e-12f);
    float inv = 1.f / (dist + 1e-8f);
    float u = fminf(dist * inv_step, (float)TAB_T);
    int t0 = min((int)u, TAB_T - 1);
    geo_ci[i] = make_int2(cl, t0);
    geo_wd[i] = make_float4(u - (float)t0, dx*inv, dy*inv, dz*inv);
}

// ---------------------------------------------------------------- filter-MLP table build (all layers, fp16 out)
__global__ __launch_bounds__(TH) void k_table(
    const float* __restrict__ centers, const float* __restrict__ gamma,
    const float* __restrict__ fw1b, const float* __restrict__ fb1b,
    const float* __restrict__ fw2b, const float* __restrict__ fb2b,
    __half* __restrict__ tabb, float step)
{
    __shared__ float sh_rbf[32][RDIM];
    __shared__ float sh_ht[FDIM][33];
    __shared__ float sh_w[32][3 * FDIM + 4];

    const int l   = blockIdx.y;
    const float* fw1 = fw1b + (size_t)l * RDIM * FDIM;
    const float* fb1 = fb1b + (size_t)l * FDIM;
    const float* fw2 = fw2b + (size_t)l * FDIM * 3 * FDIM;
    const float* fb2 = fb2b + (size_t)l * 3 * FDIM;
    __half* tab = tabb + (size_t)l * (TAB_T + 1) * 384;

    const int p0  = blockIdx.x * 32;
    const int tid = threadIdx.x;

    for (int i = tid; i < 32 * RDIM; i += TH) {
        int p = i / RDIM, r = i - p * RDIM;
        float d = (float)(p0 + p) * step - centers[r];
        sh_rbf[p][r] = __expf(-gamma[r] * d * d);
    }
    __syncthreads();
    for (int i = tid; i < 32 * FDIM; i += TH) {
        int p = i >> 7, f = i & 127;
        float acc = fb1[f];
        #pragma unroll
        for (int r = 0; r < RDIM; ++r) acc += sh_rbf[p][r] * fw1[r * FDIM + f];
        sh_ht[f][p] = siluf(acc);
    }

    const int eq = tid & 7;
    const int fq = tid >> 3;
    const int f0 = fq * 4;

    float pg[3][4][4];
    #pragma unroll
    for (int g3 = 0; g3 < 3; ++g3)
        #pragma unroll
        for (int ee = 0; ee < 4; ++ee)
            #pragma unroll
            for (int i = 0; i < 4; ++i) pg[g3][ee][i] = fb2[g3 * FDIM + f0 + i];

    const int kkr = tid >> 3;
    const int t8  = tid & 7;
    for (int kc = 0; kc < 4; ++kc) {
        __syncthreads();
        #pragma unroll
        for (int j = 0; j < 12; ++j) {
            int g = (t8 * 12 + j) * 4;
            float4 w4 = *(const float4*)&fw2[(size_t)(kc * 32 + kkr) * (3 * FDIM) + g];
            *(float4*)&sh_w[kkr][g] = w4;
        }
        __syncthreads();
        #pragma unroll 4
        for (int kk = 0; kk < 32; ++kk) {
            float hv[4];
            #pragma unroll
            for (int ee = 0; ee < 4; ++ee) hv[ee] = sh_ht[kc * 32 + kk][4 * eq + ee];
            #pragma unroll
            for (int g3 = 0; g3 < 3; ++g3) {
                float4 w4 = *(const float4*)&sh_w[kk][g3 * FDIM + f0];
                #pragma unroll
                for (int ee = 0; ee < 4; ++ee) {
                    pg[g3][ee][0] += hv[ee] * w4.x;
                    pg[g3][ee][1] += hv[ee] * w4.y;
                    pg[g3][ee][2] += hv[ee] * w4.z;
                    pg[g3][ee][3] += hv[ee] * w4.w;
                }
            }
        }
    }

    #pragma unroll
    for (int ee = 0; ee < 4; ++ee) {
        int pt = p0 + 4 * eq + ee;
        if (pt <= TAB_T) {
            #pragma unroll
            for (int g3 = 0; g3 < 3; ++g3)
                store_h4(&tab[(size_t)pt * 384 + g3 * FDIM + f0],
                         pg[g3][ee][0], pg[g3][ee][1], pg[g3][ee][2], pg[g3][ee][3]);
        }
    }
}

// ---------------------------------------------------------------- repack: tab2[t][j] = {tab[t][j], tab[t+1][j]}
__global__ __launch_bounds__(256) void k_repack(const __half* __restrict__ tab,
                                                __half2* __restrict__ tab2) {
    int l = blockIdx.y;
    const __half* t  = tab  + (size_t)l * (TAB_T + 1) * 384;
    __half2*      t2 = tab2 + (size_t)l * TAB_T * 384;
    int i = blockIdx.x * 256 + threadIdx.x;
    t2[i] = __halves2half2(t[i], t[i + 384]);
}

// ---------------------------------------------------------------- gather message kernel (fp16, precomputed geometry)
__global__ __launch_bounds__(128) void k_gather(
    const int* __restrict__ rowstart,
    const int2* __restrict__ geo_ci, const float4* __restrict__ geo_wd,
    const __half2* __restrict__ tab2, const __half* __restrict__ s_h,
    const __half* __restrict__ v_h,
    float* __restrict__ m_s, float* __restrict__ vnorm, __half* __restrict__ m_v_h,
    int withv, int N)
{
    __shared__ int   sh_col[32];
    __shared__ int   sh_t0[32];
    __shared__ float sh_w[32];
    __shared__ float sh_d0[32], sh_d1[32], sh_d2[32];

    const int n   = blockIdx.x;
    const int tid = threadIdx.x;
    const int lo  = rowstart[n], hi = rowstart[n + 1];

    float acc_s = 0.f, av0 = 0.f, av1 = 0.f, av2 = 0.f;

    for (int base = lo; base < hi; base += 32) {
        const int ne = min(32, hi - base);
        __syncthreads();
        if (tid < 32) {
            int idx = base + tid;
            if (tid < ne) {
                int2   ci = geo_ci[idx];
                float4 wd = geo_wd[idx];
                sh_col[tid] = ci.x; sh_t0[tid] = ci.y;
                sh_w[tid] = wd.x;
                sh_d0[tid] = wd.y; sh_d1[tid] = wd.z; sh_d2[tid] = wd.w;
            } else {
                sh_col[tid] = 0; sh_t0[tid] = 0; sh_w[tid] = 0.f;
                sh_d0[tid] = sh_d1[tid] = sh_d2[tid] = 0.f;
            }
        }
        __syncthreads();
        if (withv) {
            #pragma unroll 2
            for (int el = 0; el < ne; ++el) {
                int   cl = sh_col[el];
                int   t0 = sh_t0[el];
                float w  = sh_w[el];
                const __half2* t2 = tab2 + (size_t)t0 * 384 + tid;
                float2 pss2 = __half22float2(t2[0]);
                float2 pvv2 = __half22float2(t2[128]);
                float2 psv2 = __half22float2(t2[256]);
                float pss = pss2.x + w * (pss2.y - pss2.x);
                float pvv = pvv2.x + w * (pvv2.y - pvv2.x);
                float psv = psv2.x + w * (psv2.y - psv2.x);
                float sc = __half2float(s_h[(size_t)cl * FDIM + tid]);
                const __half* vp = v_h + (size_t)cl * 3 * FDIM + tid;
                float svs = psv * sc;
                acc_s += pss * sc;
                av0 += pvv * __half2float(vp[0])        + svs * sh_d0[el];
                av1 += pvv * __half2float(vp[FDIM])     + svs * sh_d1[el];
                av2 += pvv * __half2float(vp[2*FDIM])   + svs * sh_d2[el];
            }
        } else {
            #pragma unroll 2
            for (int el = 0; el < ne; ++el) {
                int   cl = sh_col[el];
                int   t0 = sh_t0[el];
                float w  = sh_w[el];
                const __half2* t2 = tab2 + (size_t)t0 * 384 + tid;
                float2 pss2 = __half22float2(t2[0]);
                float2 psv2 = __half22float2(t2[256]);
                float pss = pss2.x + w * (pss2.y - pss2.x);
                float psv = psv2.x + w * (psv2.y - psv2.x);
                float sc = __half2float(s_h[(size_t)cl * FDIM + tid]);
                float svs = psv * sc;
                acc_s += pss * sc;
                av0 += svs * sh_d0[el];
                av1 += svs * sh_d1[el];
                av2 += svs * sh_d2[el];
            }
        }
    }

    m_s[(size_t)n * FDIM + tid] = acc_s;
    vnorm[(size_t)n * FDIM + tid] = sqrtf(av0*av0 + av1*av1 + av2*av2 + 1e-12f);
    __half* mh = m_v_h + (size_t)n * 3 * FDIM + tid;
    mh[0]      = __float2half(av0);
    mh[FDIM]   = __float2half(av1);
    mh[2*FDIM] = __float2half(av2);
}

// ---------------------------------------------------------------- GEMM 1: u1 = silu(X @ uw1 + ub1)
// 32-row tiles (625 blocks), 256 thr, 2x8 micro, K=384, reg-pipelined.
__global__ __launch_bounds__(256) void k_mlp1(
    const float* __restrict__ s, const float* __restrict__ m_s, const float* __restrict__ vnorm,
    const float* __restrict__ uw1, const float* __restrict__ ub1,
    float* __restrict__ u1, int N)
{
    __shared__ float shA[16][36];    // [kk][row]
    __shared__ float shB[16][132];   // [kk][col]

    const int tid = threadIdx.x;
    const int n0  = blockIdx.x * 32;
    const int tx  = tid & 15, ty = tid >> 4;
    const int cA  = tx * 4, cB = 64 + tx * 4;
    const int r0  = ty * 2;
    const int rs  = (tid & 127) >> 2;   // 0..31 (A staging row; threads <128)
    const int k4  = (tid & 3) * 4;
    const int bk  = tid >> 5;
    const int bc4 = (tid & 31) * 4;

    float acc[2][8];
    {
        float4 bA = *(const float4*)&ub1[cA];
        float4 bB = *(const float4*)&ub1[cB];
        #pragma unroll
        for (int i = 0; i < 2; ++i) {
            acc[i][0]=bA.x; acc[i][1]=bA.y; acc[i][2]=bA.z; acc[i][3]=bA.w;
            acc[i][4]=bB.x; acc[i][5]=bB.y; acc[i][6]=bB.z; acc[i][7]=bB.w;
        }
    }

    float4 pa, pb0, pb1;

#define MLP1_LOAD(kc) do { \
        pa = make_float4(0.f,0.f,0.f,0.f); \
        if (tid < 128) { \
            int kg = (kc) * 16 + k4; int n = n0 + rs; \
            if (n < N) { \
                if (kg < 128)      pa = *(const float4*)&s[(size_t)n * FDIM + kg]; \
                else if (kg < 256) pa = *(const float4*)&m_s[(size_t)n * FDIM + kg - 128]; \
                else               pa = *(const float4*)&vnorm[(size_t)n * FDIM + kg - 256]; \
            } \
        } \
        pb0 = *(const float4*)&uw1[(size_t)((kc)*16 + bk) * FDIM + bc4]; \
        pb1 = *(const float4*)&uw1[(size_t)((kc)*16 + 8 + bk) * FDIM + bc4]; \
    } while (0)

    MLP1_LOAD(0);
    for (int kc = 0; kc < 24; ++kc) {
        __syncthreads();
        if (tid < 128) {
            shA[k4+0][rs] = pa.x; shA[k4+1][rs] = pa.y;
            shA[k4+2][rs] = pa.z; shA[k4+3][rs] = pa.w;
        }
        *(float4*)&shB[bk][bc4]     = pb0;
        *(float4*)&shB[8 + bk][bc4] = pb1;
        if (kc + 1 < 24) MLP1_LOAD(kc + 1);
        __syncthreads();
        #pragma unroll
        for (int kk = 0; kk < 16; ++kk) {
            float2 a2 = *(const float2*)&shA[kk][r0];
            float4 b0 = *(const float4*)&shB[kk][cA];
            float4 b1 = *(const float4*)&shB[kk][cB];
            float av[2] = {a2.x, a2.y};
            #pragma unroll
            for (int i = 0; i < 2; ++i) {
                acc[i][0] += av[i]*b0.x; acc[i][1] += av[i]*b0.y;
                acc[i][2] += av[i]*b0.z; acc[i][3] += av[i]*b0.w;
                acc[i][4] += av[i]*b1.x; acc[i][5] += av[i]*b1.y;
                acc[i][6] += av[i]*b1.z; acc[i][7] += av[i]*b1.w;
            }
        }
    }
#undef MLP1_LOAD

    #pragma unroll
    for (int i = 0; i < 2; ++i) {
        int n = n0 + r0 + i;
        if (n < N) {
            float4 oA = make_float4(siluf(acc[i][0]), siluf(acc[i][1]), siluf(acc[i][2]), siluf(acc[i][3]));
            float4 oB = make_float4(siluf(acc[i][4]), siluf(acc[i][5]), siluf(acc[i][6]), siluf(acc[i][7]));
            *(float4*)&u1[(size_t)n * FDIM + cA] = oA;
            *(float4*)&u1[(size_t)n * FDIM + cB] = oB;
        }
    }
}

// ---------------------------------------------------------------- GEMM 2: upd = u1 @ uw2 + ub2, fused apply
// 32-row tiles, 2x8 micro; wmirror=0 skips fp16 mirror writes (last layer).
__global__ __launch_bounds__(256) void k_mlp2(
    const float* __restrict__ u1, const float* __restrict__ uw2, const float* __restrict__ ub2,
    float* __restrict__ s, float* __restrict__ v, const __half* __restrict__ m_v_h,
    __half* __restrict__ s_h, __half* __restrict__ v_h, int wmirror, int N)
{
    __shared__ float shU[32][132];
    __shared__ float shB[16][132];

    const int tid = threadIdx.x;
    const int n0  = blockIdx.x * 32;
    const int tx  = tid & 15, ty = tid >> 4;
    const int cA  = tx * 4, cB = 64 + tx * 4;
    const int r0  = ty * 2;
    const int bk  = tid >> 5;
    const int bc4 = (tid & 31) * 4;

    // stage u1 tile (32 x 128) once
    #pragma unroll
    for (int it = 0; it < 4; ++it) {
        int idx = it * 256 + tid;
        int row = idx >> 5;
        int c4  = (idx & 31) * 4;
        int n = n0 + row;
        float4 a = make_float4(0.f,0.f,0.f,0.f);
        if (n < N) a = *(const float4*)&u1[(size_t)n * FDIM + c4];
        *(float4*)&shU[row][c4] = a;
    }

    float4 pb0, pb1;
#define MLP2_LOADB(g, kc) do { \
        pb0 = *(const float4*)&uw2[(size_t)((kc)*16 + bk) * (3*FDIM) + (g) * FDIM + bc4]; \
        pb1 = *(const float4*)&uw2[(size_t)((kc)*16 + 8 + bk) * (3*FDIM) + (g) * FDIM + bc4]; \
    } while (0)

    MLP2_LOADB(0, 0);
    float alpha[2][8];

    for (int g = 0; g < 3; ++g) {
        float acc2[2][8];
        {
            float4 bA = *(const float4*)&ub2[g * FDIM + cA];
            float4 bB = *(const float4*)&ub2[g * FDIM + cB];
            #pragma unroll
            for (int i = 0; i < 2; ++i) {
                acc2[i][0]=bA.x; acc2[i][1]=bA.y; acc2[i][2]=bA.z; acc2[i][3]=bA.w;
                acc2[i][4]=bB.x; acc2[i][5]=bB.y; acc2[i][6]=bB.z; acc2[i][7]=bB.w;
            }
        }
        for (int kc = 0; kc < 8; ++kc) {
            __syncthreads();
            *(float4*)&shB[bk][bc4]     = pb0;
            *(float4*)&shB[8 + bk][bc4] = pb1;
            if (kc + 1 < 8)      MLP2_LOADB(g, kc + 1);
            else if (g + 1 < 3)  MLP2_LOADB(g + 1, 0);
            __syncthreads();
            #pragma unroll
            for (int kk = 0; kk < 16; ++kk) {
                int col = kc * 16 + kk;
                float4 b0 = *(const float4*)&shB[kk][cA];
                float4 b1 = *(const float4*)&shB[kk][cB];
                #pragma unroll
                for (int i = 0; i < 2; ++i) {
                    float uv = shU[r0 + i][col];
                    acc2[i][0] += uv*b0.x; acc2[i][1] += uv*b0.y;
                    acc2[i][2] += uv*b0.z; acc2[i][3] += uv*b0.w;
                    acc2[i][4] += uv*b1.x; acc2[i][5] += uv*b1.y;
                    acc2[i][6] += uv*b1.z; acc2[i][7] += uv*b1.w;
                }
            }
        }

        if (g == 0) {
            #pragma unroll
            for (int i = 0; i < 2; ++i) {
                int n = n0 + r0 + i;
                if (n < N) {
                    float4 s0 = *(const float4*)&s[(size_t)n * FDIM + cA];
                    float4 s1 = *(const float4*)&s[(size_t)n * FDIM + cB];
                    s0.x += acc2[i][0]; s0.y += acc2[i][1]; s0.z += acc2[i][2]; s0.w += acc2[i][3];
                    s1.x += acc2[i][4]; s1.y += acc2[i][5]; s1.z += acc2[i][6]; s1.w += acc2[i][7];
                    *(float4*)&s[(size_t)n * FDIM + cA] = s0;
                    *(float4*)&s[(size_t)n * FDIM + cB] = s1;
                    if (wmirror) {
                        store_h4(&s_h[(size_t)n * FDIM + cA], s0.x, s0.y, s0.z, s0.w);
                        store_h4(&s_h[(size_t)n * FDIM + cB], s1.x, s1.y, s1.z, s1.w);
                    }
                }
            }
        } else if (g == 1) {
            #pragma unroll
            for (int i = 0; i < 2; ++i)
                #pragma unroll
                for (int j = 0; j < 8; ++j) alpha[i][j] = acc2[i][j];
        } else {
            #pragma unroll
            for (int i = 0; i < 2; ++i) {
                int n = n0 + r0 + i;
                if (n < N) {
                    #pragma unroll
                    for (int k = 0; k < 3; ++k) {
                        float* vp = v + ((size_t)n * 3 + k) * FDIM;
                        const __half* mp = m_v_h + ((size_t)n * 3 + k) * FDIM;
                        __half* vhp = v_h + ((size_t)n * 3 + k) * FDIM;
                        __half mh[8];
                        *(uint2*)&mh[0] = *(const uint2*)&mp[cA];
                        *(uint2*)&mh[4] = *(const uint2*)&mp[cB];
                        float4 v0 = *(const float4*)&vp[cA];
                        float4 v1 = *(const float4*)&vp[cB];
                        v0.x = alpha[i][0]*v0.x + acc2[i][0]*__half2float(mh[0]);
                        v0.y = alpha[i][1]*v0.y + acc2[i][1]*__half2float(mh[1]);
                        v0.z = alpha[i][2]*v0.z + acc2[i][2]*__half2float(mh[2]);
                        v0.w = alpha[i][3]*v0.w + acc2[i][3]*__half2float(mh[3]);
                        v1.x = alpha[i][4]*v1.x + acc2[i][4]*__half2float(mh[4]);
                        v1.y = alpha[i][5]*v1.y + acc2[i][5]*__half2float(mh[5]);
                        v1.z = alpha[i][6]*v1.z + acc2[i][6]*__half2float(mh[6]);
                        v1.w = alpha[i][7]*v1.w + acc2[i][7]*__half2float(mh[7]);
                        *(float4*)&vp[cA] = v0;
                        *(float4*)&vp[cB] = v1;
                        if (wmirror) {
                            store_h4(&vhp[cA], v0.x, v0.y, v0.z, v0.w);
                            store_h4(&vhp[cB], v1.x, v1.y, v1.z, v1.w);
                        }
                    }
                }
            }
        }
    }
#undef MLP2_LOADB
}

// ---------------------------------------------------------------- energy head GEMM (grid = NB x S)
__global__ __launch_bounds__(256) void k_energy2(
    const float* __restrict__ ew1, const float* __restrict__ eb1,
    const float* __restrict__ ew2, const float* __restrict__ eb2,
    const float* __restrict__ s, const int* __restrict__ batch,
    float* __restrict__ energies, int N, int S)
{
    __shared__ float shA[16][68];
    __shared__ float shB[16][132];

    const int tid = threadIdx.x;
    const int n0  = blockIdx.x * 64;
    const int st  = blockIdx.y;
    const int tx  = tid & 15, ty = tid >> 4;
    const int cA  = tx * 4, cB = 64 + tx * 4;
    const int r0  = ty * 4;
    const int rs  = tid >> 2;
    const int k4  = (tid & 3) * 4;

    float acc[4][8];
    {
        float4 bA = *(const float4*)&eb1[st * FDIM + cA];
        float4 bB = *(const float4*)&eb1[st * FDIM + cB];
        #pragma unroll
        for (int i = 0; i < 4; ++i) {
            acc[i][0]=bA.x; acc[i][1]=bA.y; acc[i][2]=bA.z; acc[i][3]=bA.w;
            acc[i][4]=bB.x; acc[i][5]=bB.y; acc[i][6]=bB.z; acc[i][7]=bB.w;
        }
    }

    for (int kc = 0; kc < 8; ++kc) {
        __syncthreads();
        {
            int kg = kc * 16 + k4;
            int n  = n0 + rs;
            float4 a = make_float4(0.f, 0.f, 0.f, 0.f);
            if (n < N) a = *(const float4*)&s[(size_t)n * FDIM + kg];
            shA[k4+0][rs] = a.x; shA[k4+1][rs] = a.y; shA[k4+2][rs] = a.z; shA[k4+3][rs] = a.w;
        }
        #pragma unroll
        for (int i = 0; i < 2; ++i) {
            int idx = tid + i * 256;
            int kk = idx >> 5;
            int c4 = (idx & 31) * 4;
            *(float4*)&shB[kk][c4] =
                *(const float4*)&ew1[(size_t)st * FDIM * FDIM + (size_t)(kc*16+kk) * FDIM + c4];
        }
        __syncthreads();
        #pragma unroll
        for (int kk = 0; kk < 16; ++kk) {
            float4 a4 = *(const float4*)&shA[kk][r0];
            float4 b0 = *(const float4*)&shB[kk][cA];
            float4 b1 = *(const float4*)&shB[kk][cB];
            float av[4] = {a4.x, a4.y, a4.z, a4.w};
            #pragma unroll
            for (int i = 0; i < 4; ++i) {
                acc[i][0] += av[i]*b0.x; acc[i][1] += av[i]*b0.y;
                acc[i][2] += av[i]*b0.z; acc[i][3] += av[i]*b0.w;
                acc[i][4] += av[i]*b1.x; acc[i][5] += av[i]*b1.y;
                acc[i][6] += av[i]*b1.z; acc[i][7] += av[i]*b1.w;
            }
        }
    }

    float4 wA = *(const float4*)&ew2[st * FDIM + cA];
    float4 wB = *(const float4*)&ew2[st * FDIM + cB];
    float p[4];
    #pragma unroll
    for (int i = 0; i < 4; ++i) {
        p[i]  = siluf(acc[i][0])*wA.x + siluf(acc[i][1])*wA.y
              + siluf(acc[i][2])*wA.z + siluf(acc[i][3])*wA.w;
        p[i] += siluf(acc[i][4])*wB.x + siluf(acc[i][5])*wB.y
              + siluf(acc[i][6])*wB.z + siluf(acc[i][7])*wB.w;
    }
    #pragma unroll
    for (int m = 1; m <= 8; m <<= 1) {
        #pragma unroll
        for (int i = 0; i < 4; ++i) p[i] += __shfl_xor(p[i], m, 64);
    }
    if (tx == 0) {
        float b2 = eb2[st];
        #pragma unroll
        for (int i = 0; i < 4; ++i) {
            int n = n0 + r0 + i;
            if (n < N) atomicAdd(&energies[batch[n] * S + st], p[i] + b2);
        }
    }
}

// ---------------------------------------------------------------- dipole / nac heads
__global__ void k_vec(const float* __restrict__ v, const float* __restrict__ dipole_w,
                      const float* __restrict__ nac_w, const int* __restrict__ batch,
                      float* __restrict__ dipoles, float* __restrict__ nac, int N)
{
    int n = blockIdx.x * 4 + (threadIdx.x >> 6);
    int lane = threadIdx.x & 63;
    if (n >= N) return;
    float pd[3] = {0.f, 0.f, 0.f};
    float pn[3][3] = {{0.f}};
    const float* vb = v + (size_t)n * 3 * FDIM;
    for (int f = lane; f < FDIM; f += 64) {
        float v0 = vb[f], v1 = vb[FDIM + f], v2 = vb[2*FDIM + f];
        float wd = dipole_w[f];
        pd[0] += wd * v0; pd[1] += wd * v1; pd[2] += wd * v2;
        #pragma unroll
        for (int p = 0; p < 3; ++p) {
            float wn = nac_w[p * FDIM + f];
            pn[p][0] += wn * v0; pn[p][1] += wn * v1; pn[p][2] += wn * v2;
        }
    }
    #pragma unroll
    for (int d = 32; d > 0; d >>= 1) {
        #pragma unroll
        for (int k = 0; k < 3; ++k) pd[k] += __shfl_down(pd[k], d, 64);
        #pragma unroll
        for (int p = 0; p < 3; ++p)
            #pragma unroll
            for (int k = 0; k < 3; ++k) pn[p][k] += __shfl_down(pn[p][k], d, 64);
    }
    if (lane == 0) {
        int m = batch[n];
        #pragma unroll
        for (int k = 0; k < 3; ++k) atomicAdd(&dipoles[m * 3 + k], pd[k]);
        #pragma unroll
        for (int p = 0; p < 3; ++p)
            #pragma unroll
            for (int k = 0; k < 3; ++k) atomicAdd(&nac[(m * 3 + p) * 3 + k], pn[p][k]);
    }
}

// ---------------------------------------------------------------- per-molecule heads
__global__ __launch_bounds__(128) void k_heads(
    const float* __restrict__ aw1, const float* __restrict__ ab1,
    const float* __restrict__ aw2, const float* __restrict__ ab2,
    const float* __restrict__ yw1, const float* __restrict__ yb1,
    const float* __restrict__ yw2, const float* __restrict__ yb2,
    const float* __restrict__ energies, const float* __restrict__ nac,
    float* __restrict__ lam, float* __restrict__ phi_y, int M, int S)
{
    __shared__ float sh_in[8];
    __shared__ float sh_red[2];
    int m = blockIdx.x;
    if (m >= M) return;
    int tid = threadIdx.x;
    if (tid == 0) {
        float e0 = energies[m * S];
        for (int j = 0; j < 3; ++j) sh_in[j] = energies[m * S + 1 + j] - e0;
        for (int p = 0; p < 3; ++p) {
            float a = nac[(m * 3 + p) * 3 + 0];
            float b = nac[(m * 3 + p) * 3 + 1];
            float c = nac[(m * 3 + p) * 3 + 2];
            sh_in[3 + p] = sqrtf(a*a + b*b + c*c + 1e-12f);
        }
    }
    __syncthreads();
    float pa = 0.f;
    if (tid < 64) {
        float h = ab1[tid];
        #pragma unroll
        for (int j = 0; j < 3; ++j) h += sh_in[j] * aw1[j * 64 + tid];
        pa = siluf(h) * aw2[tid];
    }
    float h2 = yb1[tid];
    #pragma unroll
    for (int j = 0; j < 6; ++j) h2 += sh_in[j] * yw1[j * 128 + tid];
    float py = siluf(h2) * yw2[tid];
    #pragma unroll
    for (int d = 32; d > 0; d >>= 1) {
        pa += __shfl_down(pa, d, 64);
        py += __shfl_down(py, d, 64);
    }
    int wid = tid >> 6, lane = tid & 63;
    if (lane == 0) sh_red[wid] = py;
    __syncthreads();
    if (tid == 0) {
        lam[m] = pa + ab2[0];
        float yt = sh_red[0] + sh_red[1] + yb2[0];
        phi_y[m] = 1.f / (1.f + __expf(-yt));
    }
}

// ---------------------------------------------------------------- launch
extern "C" void kernel_launch(void* const* d_in, const int* in_sizes, int n_in,
                              void* d_out, int out_size, void* d_ws, size_t ws_size,
                              hipStream_t stream)
{
    const int*   z        = (const int*)  d_in[0];
    const float* pos      = (const float*)d_in[1];
    const int*   eidx     = (const int*)  d_in[2];
    const int*   batch    = (const int*)  d_in[3];
    const float* emb      = (const float*)d_in[5];
    const float* centers  = (const float*)d_in[6];
    const float* gamma    = (const float*)d_in[7];
    const float* fw1      = (const float*)d_in[8];
    const float* fb1      = (const float*)d_in[9];
    const float* fw2      = (const float*)d_in[10];
    const float* fb2      = (const float*)d_in[11];
    const float* uw1      = (const float*)d_in[12];
    const float* ub1      = (const float*)d_in[13];
    const float* uw2      = (const float*)d_in[14];
    const float* ub2      = (const float*)d_in[15];
    const float* ew1      = (const float*)d_in[16];
    const float* eb1      = (const float*)d_in[17];
    const float* ew2      = (const float*)d_in[18];
    const float* eb2      = (const float*)d_in[19];
    const float* dipole_w = (const float*)d_in[20];
    const float* nac_w    = (const float*)d_in[21];
    const float* aw1      = (const float*)d_in[22];
    const float* ab1      = (const float*)d_in[23];
    const float* aw2      = (const float*)d_in[24];
    const float* ab2      = (const float*)d_in[25];
    const float* yw1      = (const float*)d_in[26];
    const float* yb1      = (const float*)d_in[27];
    const float* yw2      = (const float*)d_in[28];
    const float* yb2      = (const float*)d_in[29];

    const int N = in_sizes[0];
    const int E = in_sizes[2] / 2;
    const int S = in_sizes[19];
    const int P = in_sizes[21] / FDIM;
    const int L = in_sizes[9] / FDIM;
    const int M = out_size / (S + 3 + P * 3 + 2);

    const size_t NF = (size_t)N * FDIM;
    float*   s     = (float*)d_ws;                  // NF
    float*   v     = s + NF;                        // 3 NF
    float*   m_s   = v + 3 * NF;                    // NF   (aliased by u1)
    float*   vnorm = m_s + NF;                      // NF
    __half*  s_h   = (__half*)(vnorm + NF);         // NF halves
    __half*  v_h   = s_h + NF;                      // 3 NF halves
    __half*  m_v_h = v_h + 3 * NF;                  // 3 NF halves
    __half*  tab   = m_v_h + 3 * NF;                // L * (TAB_T+1) * 384 halves
    __half2* tab2  = (__half2*)(tab + (size_t)L * (TAB_T + 1) * 384);  // L * TAB_T * 384 half2
    float4*  geo_wd = (float4*)(tab2 + (size_t)L * TAB_T * 384);        // E float4
    int2*    geo_ci = (int2*)(geo_wd + E);                              // E int2
    int* rowstart = (int*)(geo_ci + E);
    int* cursor   = rowstart + (N + 1);
    int* esort    = cursor + N;
    int* bsum     = esort + E;
    float* u1 = m_s;   // safe alias: block-local row panels, m_s fully consumed before u1 written

    float* out      = (float*)d_out;
    float* energies = out;
    float* dipoles  = energies + (size_t)M * S;
    float* nac      = dipoles  + (size_t)M * 3;
    float* lam      = nac      + (size_t)M * P * 3;
    float* phi_y    = lam      + M;

    const int* erow = eidx;
    const int* ecol = eidx + E;

    const float step = TAB_RANGE / (float)TAB_T;
    const float inv_step = (float)TAB_T / TAB_RANGE;
    const int NB  = (N + 63) / 64;
    const int NB2 = (N + 31) / 32;
    const int NSB = (N + 255) / 256;

    hipMemsetAsync(d_out, 0, (size_t)out_size * sizeof(float), stream);
    hipMemsetAsync(cursor, 0, (size_t)N * sizeof(int), stream);
    k_hist<<<(E + 255) / 256, 256, 0, stream>>>(erow, cursor, E);
    k_scan1<<<NSB, 256, 0, stream>>>(cursor, rowstart, bsum, N);
    k_scan2<<<1, 256, 0, stream>>>(bsum, rowstart, NSB, N);
    k_scan3<<<NSB, 256, 0, stream>>>(rowstart, cursor, bsum, N);
    k_fill<<<(E + 255) / 256, 256, 0, stream>>>(erow, cursor, esort, E);
    k_geom<<<(E + 255) / 256, 256, 0, stream>>>(pos, erow, ecol, esort, geo_ci, geo_wd, inv_step, E);
    k_init<<<(N * FDIM + 255) / 256, 256, 0, stream>>>(z, emb, s, v, s_h, v_h, N);

    const int tab_blocks = (TAB_T + 1 + 31) / 32;
    k_table<<<dim3(tab_blocks, L), TH, 0, stream>>>(centers, gamma, fw1, fb1, fw2, fb2, tab, step);
    k_repack<<<dim3(TAB_T * 384 / 256, L), 256, 0, stream>>>(tab, tab2);

    for (int l = 0; l < L; ++l) {
        const __half2* tab2_l = tab2 + (size_t)l * TAB_T * 384;
        k_gather<<<N, 128, 0, stream>>>(
            rowstart, geo_ci, geo_wd, tab2_l, s_h, v_h,
            m_s, vnorm, m_v_h, (l > 0) ? 1 : 0, N);
        k_mlp1<<<NB2, 256, 0, stream>>>(
            s, m_s, vnorm, uw1 + (size_t)l * 3 * FDIM * FDIM, ub1 + (size_t)l * FDIM, u1, N);
        k_mlp2<<<NB2, 256, 0, stream>>>(
            u1, uw2 + (size_t)l * FDIM * 3 * FDIM, ub2 + (size_t)l * 3 * FDIM,
            s, v, m_v_h, s_h, v_h, (l + 1 < L) ? 1 : 0, N);
    }

    k_energy2<<<dim3(NB, S), 256, 0, stream>>>(ew1, eb1, ew2, eb2, s, batch, energies, N, S);
    k_vec<<<(N + 3) / 4, 256, 0, stream>>>(v, dipole_w, nac_w, batch, dipoles, nac, N);
    k_heads<<<M, 128, 0, stream>>>(aw1, ab1, aw2, ab2, yw1, yb1, yw2, yb2,
                                   energies, nac, lam, phi_y, M, S);
}